// Round 1
// baseline (2457.567 us; speedup 1.0000x reference)
//
#include <hip/hip_runtime.h>
#include <hip/hip_bf16.h>
#include <math.h>

// Problem constants
#define BATCH 16
#define NTOK 1024      // 32*32
#define HID 256
#define KMEM 4
#define DIN 272
#define DFF 1024
#define GRID_H 32
#define GRID_W 32
#define LN_EPS 1e-5f

// ---------------------------------------------------------------------------
// pos embed: pos[t][j] = j<128 ? col_embed[t%32][j] : row_embed[t/32][j-128]
// ---------------------------------------------------------------------------
__global__ __launch_bounds__(256) void pos_kernel(
    const float* __restrict__ row_e, const float* __restrict__ col_e,
    float* __restrict__ pos) {
  int t = blockIdx.x;
  int j = threadIdx.x;
  float v = (j < 128) ? col_e[(t & 31) * 128 + j]
                      : row_e[(t >> 5) * 128 + (j - 128)];
  pos[t * 256 + j] = v;
}

// ---------------------------------------------------------------------------
// Generic tiled GEMM: C[M,N] = A[M,K] @ W[K,N] + bias, optional ReLU.
// ALAYOUT 0: A row-major (lda=K).
// ALAYOUT 1: A "batched col-major": A[r,c] = A[(r/1024)*batchStrideA + c*1024 + (r%1024)]
// Tile 64x64, Kc=16, 256 threads, 4x4 microtile. K must be multiple of 16,
// M multiple of 64 (and of 1024 per batch for ALAYOUT 1). N guarded.
// ---------------------------------------------------------------------------
template <int ALAYOUT, bool RELU>
__global__ __launch_bounds__(256) void gemm_kernel(
    const float* __restrict__ A, const float* __restrict__ W,
    const float* __restrict__ bias, float* __restrict__ C,
    int M, int N, int K, long batchStrideA) {
  __shared__ float As[16][68];  // [cc][tt], padded
  __shared__ float Bs[16][68];  // [cc][jj], padded
  int tid = threadIdx.x;
  int tx = tid & 15, ty = tid >> 4;
  int row0 = blockIdx.y * 64;
  int col0 = blockIdx.x * 64;
  float acc[4][4] = {};
  const float* Abase;
  if (ALAYOUT == 1) {
    int b = row0 >> 10;
    Abase = A + (long)b * batchStrideA + (row0 & 1023);
  } else {
    Abase = A + (long)row0 * K;
  }
  for (int k0 = 0; k0 < K; k0 += 16) {
#pragma unroll
    for (int i = 0; i < 4; i++) {
      int idx = i * 256 + tid;
      if (ALAYOUT == 1) {
        int tt = idx & 63, cc = idx >> 6;
        As[cc][tt] = Abase[(long)(k0 + cc) * 1024 + tt];
      } else {
        int cc = idx & 15, tt = idx >> 4;
        As[cc][tt] = Abase[(long)tt * K + k0 + cc];
      }
    }
#pragma unroll
    for (int i = 0; i < 4; i++) {
      int idx = i * 256 + tid;
      int cc = idx >> 6, jj = idx & 63;
      int col = col0 + jj;
      Bs[cc][jj] = (col < N) ? W[(long)(k0 + cc) * N + col] : 0.0f;
    }
    __syncthreads();
#pragma unroll
    for (int cc = 0; cc < 16; cc++) {
      float4 av = *reinterpret_cast<const float4*>(&As[cc][ty * 4]);
      float4 bv = *reinterpret_cast<const float4*>(&Bs[cc][tx * 4]);
      float a_[4] = {av.x, av.y, av.z, av.w};
      float b_[4] = {bv.x, bv.y, bv.z, bv.w};
#pragma unroll
      for (int u = 0; u < 4; u++)
#pragma unroll
        for (int v = 0; v < 4; v++) acc[u][v] = fmaf(a_[u], b_[v], acc[u][v]);
    }
    __syncthreads();
  }
#pragma unroll
  for (int u = 0; u < 4; u++) {
    long r = row0 + ty * 4 + u;
#pragma unroll
    for (int v = 0; v < 4; v++) {
      int c = col0 + tx * 4 + v;
      if (c < N) {
        float val = acc[u][v] + bias[c];
        if (RELU) val = fmaxf(val, 0.0f);
        C[r * N + c] = val;
      }
    }
  }
}

// ---------------------------------------------------------------------------
// Windowed attention: one block per (t, b, k). Softmax support is the 7x7
// neighborhood (<=49 keys). o[b,t,k*256+j] = sum_m attn * kt[k,b,m,j]
// ---------------------------------------------------------------------------
__global__ __launch_bounds__(256) void attn_kernel(
    const float* __restrict__ x, const float* __restrict__ kt,
    const float* __restrict__ pos, float* __restrict__ o) {
  int t = blockIdx.x;
  int b = blockIdx.y;
  int k = blockIdx.z;
  int tid = threadIdx.x;
  __shared__ float qp_s[256];
  __shared__ float sc_s[64];
  const float scale = 0.0625f;  // 1/sqrt(256)
  const float* xrow = x + ((long)b * NTOK + t) * HID;
  qp_s[tid] = (xrow[tid] + pos[t * HID + tid]) * scale;
  int r = t >> 5, c = t & 31;
  int r0 = max(r - 3, 0), r1 = min(r + 3, 31);
  int c0 = max(c - 3, 0), c1 = min(c + 3, 31);
  int nc = c1 - c0 + 1;
  int nm = (r1 - r0 + 1) * nc;
  __syncthreads();
  const float* ktb = kt + ((long)(k * BATCH + b)) * NTOK * HID;
  int wave = tid >> 6, lane = tid & 63;
  for (int idx = wave; idx < nm; idx += 4) {
    int m = (r0 + idx / nc) * 32 + (c0 + idx % nc);
    const float* krow = ktb + (long)m * HID;
    const float* prow = pos + m * HID;
    float s = 0.f;
#pragma unroll
    for (int u = 0; u < 4; u++) {
      int j = lane + u * 64;
      s = fmaf(qp_s[j], krow[j] + prow[j], s);
    }
#pragma unroll
    for (int off = 32; off > 0; off >>= 1) s += __shfl_xor(s, off);
    if (lane == 0) sc_s[idx] = s;
  }
  __syncthreads();
  if (tid < 64) {
    float v = (tid < nm) ? sc_s[tid] : -INFINITY;
    float mx = v;
#pragma unroll
    for (int off = 32; off > 0; off >>= 1) mx = fmaxf(mx, __shfl_xor(mx, off));
    float p = (tid < nm) ? expf(v - mx) : 0.f;
    float sm = p;
#pragma unroll
    for (int off = 32; off > 0; off >>= 1) sm += __shfl_xor(sm, off);
    if (tid < nm) sc_s[tid] = p / sm;
  }
  __syncthreads();
  float acc = 0.f;
  for (int idx = 0; idx < nm; idx++) {
    int m = (r0 + idx / nc) * 32 + (c0 + idx % nc);
    acc = fmaf(sc_s[idx], ktb[(long)m * HID + tid], acc);
  }
  o[((long)b * NTOK + t) * (KMEM * HID) + k * HID + tid] = acc;
}

// ---------------------------------------------------------------------------
// x = LayerNorm(x + res) * g + b   (one block per token row, 256 threads)
// ---------------------------------------------------------------------------
__global__ __launch_bounds__(256) void add_ln_kernel(
    const float* __restrict__ x, const float* __restrict__ res,
    const float* __restrict__ g, const float* __restrict__ bta,
    float* __restrict__ out) {
  long row = blockIdx.x;
  int j = threadIdx.x;
  float v = x[row * HID + j] + res[row * HID + j];
  float s = v, s2 = v * v;
#pragma unroll
  for (int off = 32; off > 0; off >>= 1) {
    s += __shfl_xor(s, off);
    s2 += __shfl_xor(s2, off);
  }
  __shared__ float ss[4], ss2[4];
  int wave = j >> 6, lane = j & 63;
  if (lane == 0) {
    ss[wave] = s;
    ss2[wave] = s2;
  }
  __syncthreads();
  s = ss[0] + ss[1] + ss[2] + ss[3];
  s2 = ss2[0] + ss2[1] + ss2[2] + ss2[3];
  float mean = s * (1.f / 256.f);
  float var = s2 * (1.f / 256.f) - mean * mean;
  float inv = rsqrtf(var + LN_EPS);
  out[row * HID + j] = (v - mean) * inv * g[j] + bta[j];
}

// ---------------------------------------------------------------------------
// recon_tokens (b,t,272) -> recon (b,272,32,32) transpose write, plus
// pred_sq[b,t] = sum_c (recon - qf)^2 (no atomics: block owns 32 tokens)
// ---------------------------------------------------------------------------
__global__ __launch_bounds__(256) void recon_out_kernel(
    const float* __restrict__ rt, const float* __restrict__ qf,
    float* __restrict__ recon, float* __restrict__ pred_sq) {
  int b = blockIdx.y;
  int t0 = blockIdx.x * 32;
  __shared__ float tile[32][33];
  int lx = threadIdx.x & 31;
  int ly = threadIdx.x >> 5;  // 0..7
  float sq = 0.f;
  for (int c0 = 0; c0 < DIN; c0 += 32) {
    __syncthreads();
#pragma unroll
    for (int i = 0; i < 4; i++) {
      int tt = ly + i * 8;
      int c = c0 + lx;
      tile[tt][lx] = (c < DIN) ? rt[((long)b * NTOK + t0 + tt) * DIN + c] : 0.f;
    }
    __syncthreads();
#pragma unroll
    for (int i = 0; i < 4; i++) {
      int c = c0 + ly + i * 8;
      if (c < DIN) {
        float v = tile[lx][ly + i * 8];
        long gaddr = ((long)b * DIN + c) * NTOK + t0 + lx;
        float q = qf[gaddr];
        recon[gaddr] = v;
        float d = v - q;
        sq = fmaf(d, d, sq);
      }
    }
  }
  __shared__ float red[8][33];
  red[ly][lx] = sq;
  __syncthreads();
  if (ly == 0) {
    float s = 0.f;
#pragma unroll
    for (int u = 0; u < 8; u++) s += red[u][lx];
    pred_sq[b * NTOK + t0 + lx] = s;
  }
}

// ---------------------------------------------------------------------------
// global min/max of sqrt(pred_sq) over 16384 values, single block
// ---------------------------------------------------------------------------
__global__ __launch_bounds__(256) void minmax_kernel(
    const float* __restrict__ pred_sq, float* __restrict__ mnmx) {
  int tid = threadIdx.x;
  float mn = INFINITY, mx = -INFINITY;
  for (int i = tid; i < BATCH * NTOK; i += 256) {
    float v = sqrtf(pred_sq[i]);
    mn = fminf(mn, v);
    mx = fmaxf(mx, v);
  }
#pragma unroll
  for (int off = 32; off > 0; off >>= 1) {
    mn = fminf(mn, __shfl_xor(mn, off));
    mx = fmaxf(mx, __shfl_xor(mx, off));
  }
  __shared__ float smn[4], smx[4];
  int wave = tid >> 6, lane = tid & 63;
  if (lane == 0) {
    smn[wave] = mn;
    smx[wave] = mx;
  }
  __syncthreads();
  if (tid == 0) {
    mn = fminf(fminf(smn[0], smn[1]), fminf(smn[2], smn[3]));
    mx = fmaxf(fmaxf(smx[0], smx[1]), fmaxf(smx[2], smx[3]));
    mnmx[0] = mn;
    mnmx[1] = mx;
  }
}

// ---------------------------------------------------------------------------
// bilinear upsample (align_corners) 32x32 -> 256x256 with normalization
// ---------------------------------------------------------------------------
__global__ __launch_bounds__(256) void resize_kernel(
    const float* __restrict__ pred_sq, const float* __restrict__ mnmx,
    float* __restrict__ out) {
  long idx = (long)blockIdx.x * 256 + threadIdx.x;
  if (idx >= (long)BATCH * 256 * 256) return;
  int b = (int)(idx >> 16);
  int oy = (int)((idx >> 8) & 255), ox = (int)(idx & 255);
  float mn = mnmx[0], mx = mnmx[1];
  float inv = 1.0f / (mx - mn);
  float ys = oy * (31.0f / 255.0f);
  int y0 = (int)floorf(ys);
  int y1 = min(y0 + 1, 31);
  float fy = ys - (float)y0;
  float xs = ox * (31.0f / 255.0f);
  int x0 = (int)floorf(xs);
  int x1 = min(x0 + 1, 31);
  float fx = xs - (float)x0;
  const float* p = pred_sq + b * NTOK;
  float v00 = sqrtf(p[y0 * 32 + x0]), v01 = sqrtf(p[y0 * 32 + x1]);
  float v10 = sqrtf(p[y1 * 32 + x0]), v11 = sqrtf(p[y1 * 32 + x1]);
  float cA = v00 * (1.f - fy) + v10 * fy;
  float cB = v01 * (1.f - fy) + v11 * fy;
  float v = cA * (1.f - fx) + cB * fx;
  out[idx] = (v - mn) * inv;
}

// ---------------------------------------------------------------------------
extern "C" void kernel_launch(void* const* d_in, const int* in_sizes, int n_in,
                              void* d_out, int out_size, void* d_ws,
                              size_t ws_size, hipStream_t stream) {
  const float* qf = (const float*)d_in[0];     // (16,272,32,32)
  const float* mf = (const float*)d_in[1];     // (4,16,272,32,32)
  const float* qW = (const float*)d_in[2];     // (272,256)
  const float* qb = (const float*)d_in[3];     // (256)
  const float* kvW = (const float*)d_in[4];    // (272,256)
  const float* kvb = (const float*)d_in[5];    // (256)
  const float* row_e = (const float*)d_in[6];  // (32,128)
  const float* col_e = (const float*)d_in[7];  // (32,128)
  const float* aggW = (const float*)d_in[8];   // (2,1024,256)
  const float* aggb = (const float*)d_in[9];   // (2,256)
  const float* n1g = (const float*)d_in[10];   // (2,256)
  const float* n1b = (const float*)d_in[11];
  const float* l1W = (const float*)d_in[12];  // (2,256,1024)
  const float* l1b = (const float*)d_in[13];  // (2,1024)
  const float* l2W = (const float*)d_in[14];  // (2,1024,256)
  const float* l2b = (const float*)d_in[15];  // (2,256)
  const float* n2g = (const float*)d_in[16];
  const float* n2b = (const float*)d_in[17];
  const float* outW = (const float*)d_in[18];  // (256,272)
  const float* outb = (const float*)d_in[19];  // (272)

  float* out = (float*)d_out;
  float* recon = out;                            // 16*272*1024
  float* pred = out + (long)BATCH * DIN * NTOK;  // 16*256*256

  // workspace layout (floats)
  float* ws = (float*)d_ws;
  float* pos = ws;                    // 262144
  float* x = pos + 262144;            // 4194304
  float* kt = x + 4194304;            // 16777216
  float* buf1024 = kt + 16777216;     // 16777216 (attn o / ff hidden / recon_tokens)
  float* tmp256 = buf1024 + 16777216; // 4194304
  float* pred_sq = tmp256 + 4194304;  // 16384
  float* mnmx = pred_sq + 16384;      // 2

  const long BS_FEAT = (long)DIN * NTOK;  // 278528

  // pos embed
  pos_kernel<<<NTOK, 256, 0, stream>>>(row_e, col_e, pos);

  // q projection: (16384,272) @ (272,256) -> x
  {
    dim3 grid(256 / 64, (BATCH * NTOK) / 64);
    gemm_kernel<1, false><<<grid, 256, 0, stream>>>(qf, qW, qb, x,
                                                    BATCH * NTOK, HID, DIN,
                                                    BS_FEAT);
  }
  // kv projection: (65536,272) @ (272,256) -> kt
  {
    dim3 grid(256 / 64, (KMEM * BATCH * NTOK) / 64);
    gemm_kernel<1, false><<<grid, 256, 0, stream>>>(
        mf, kvW, kvb, kt, KMEM * BATCH * NTOK, HID, DIN, BS_FEAT);
  }

  for (int l = 0; l < 2; l++) {
    // attention -> buf1024 (b,n,k*256)
    {
      dim3 grid(NTOK, BATCH, KMEM);
      attn_kernel<<<grid, 256, 0, stream>>>(x, kt, pos, buf1024);
    }
    // agg: (16384,1024)@(1024,256) -> tmp256
    {
      dim3 grid(256 / 64, (BATCH * NTOK) / 64);
      gemm_kernel<0, false><<<grid, 256, 0, stream>>>(
          buf1024, aggW + (long)l * 1024 * 256, aggb + l * 256, tmp256,
          BATCH * NTOK, HID, KMEM * HID, 0);
    }
    add_ln_kernel<<<BATCH * NTOK, 256, 0, stream>>>(x, tmp256, n1g + l * 256,
                                                    n1b + l * 256, x);
    // ff1: (16384,256)@(256,1024) relu -> buf1024
    {
      dim3 grid(1024 / 64, (BATCH * NTOK) / 64);
      gemm_kernel<0, true><<<grid, 256, 0, stream>>>(
          x, l1W + (long)l * 256 * 1024, l1b + l * 1024, buf1024, BATCH * NTOK,
          DFF, HID, 0);
    }
    // ff2: (16384,1024)@(1024,256) -> tmp256
    {
      dim3 grid(256 / 64, (BATCH * NTOK) / 64);
      gemm_kernel<0, false><<<grid, 256, 0, stream>>>(
          buf1024, l2W + (long)l * 1024 * 256, l2b + l * 256, tmp256,
          BATCH * NTOK, HID, DFF, 0);
    }
    add_ln_kernel<<<BATCH * NTOK, 256, 0, stream>>>(x, tmp256, n2g + l * 256,
                                                    n2b + l * 256, x);
  }

  // out projection: (16384,256)@(256,272) -> recon_tokens (reuse buf1024)
  {
    dim3 grid((DIN + 63) / 64, (BATCH * NTOK) / 64);
    gemm_kernel<0, false><<<grid, 256, 0, stream>>>(x, outW, outb, buf1024,
                                                    BATCH * NTOK, DIN, HID, 0);
  }
  // transpose to recon + per-token squared error
  {
    dim3 grid(NTOK / 32, BATCH);
    recon_out_kernel<<<grid, 256, 0, stream>>>(buf1024, qf, recon, pred_sq);
  }
  minmax_kernel<<<1, 256, 0, stream>>>(pred_sq, mnmx);
  resize_kernel<<<(BATCH * 256 * 256) / 256, 256, 0, stream>>>(pred_sq, mnmx,
                                                               pred);
}

// Round 2
// 1658.829 us; speedup vs baseline: 1.4815x; 1.4815x over previous
//
#include <hip/hip_runtime.h>
#include <hip/hip_bf16.h>
#include <math.h>

// Problem constants
#define BATCH 16
#define NTOK 1024      // 32*32
#define HID 256
#define KMEM 4
#define DIN 272
#define DFF 1024
#define LN_EPS 1e-5f

// ---------------------------------------------------------------------------
// pos embed: pos[t][j] = j<128 ? col_embed[t%32][j] : row_embed[t/32][j-128]
// ---------------------------------------------------------------------------
__global__ __launch_bounds__(256) void pos_kernel(
    const float* __restrict__ row_e, const float* __restrict__ col_e,
    float* __restrict__ pos) {
  int t = blockIdx.x;
  int j = threadIdx.x;
  float v = (j < 128) ? col_e[(t & 31) * 128 + j]
                      : row_e[(t >> 5) * 128 + (j - 128)];
  pos[t * 256 + j] = v;
}

// ---------------------------------------------------------------------------
// Generic tiled GEMM: C[M,N] = A[M,K] @ W[K,N] + bias, optional ReLU.
// ALAYOUT 0: A row-major (lda=K).
// ALAYOUT 1: A "batched col-major": A[r,c] = A[(r/1024)*batchStrideA + c*1024 + (r%1024)]
// ---------------------------------------------------------------------------
template <int ALAYOUT, bool RELU>
__global__ __launch_bounds__(256) void gemm_kernel(
    const float* __restrict__ A, const float* __restrict__ W,
    const float* __restrict__ bias, float* __restrict__ C,
    int M, int N, int K, long batchStrideA) {
  __shared__ float As[16][68];  // [cc][tt], padded
  __shared__ float Bs[16][68];  // [cc][jj], padded
  int tid = threadIdx.x;
  int tx = tid & 15, ty = tid >> 4;
  int row0 = blockIdx.y * 64;
  int col0 = blockIdx.x * 64;
  float acc[4][4] = {};
  const float* Abase;
  if (ALAYOUT == 1) {
    int b = row0 >> 10;
    Abase = A + (long)b * batchStrideA + (row0 & 1023);
  } else {
    Abase = A + (long)row0 * K;
  }
  for (int k0 = 0; k0 < K; k0 += 16) {
#pragma unroll
    for (int i = 0; i < 4; i++) {
      int idx = i * 256 + tid;
      if (ALAYOUT == 1) {
        int tt = idx & 63, cc = idx >> 6;
        As[cc][tt] = Abase[(long)(k0 + cc) * 1024 + tt];
      } else {
        int cc = idx & 15, tt = idx >> 4;
        As[cc][tt] = Abase[(long)tt * K + k0 + cc];
      }
    }
#pragma unroll
    for (int i = 0; i < 4; i++) {
      int idx = i * 256 + tid;
      int cc = idx >> 6, jj = idx & 63;
      int col = col0 + jj;
      Bs[cc][jj] = (col < N) ? W[(long)(k0 + cc) * N + col] : 0.0f;
    }
    __syncthreads();
#pragma unroll
    for (int cc = 0; cc < 16; cc++) {
      float4 av = *reinterpret_cast<const float4*>(&As[cc][ty * 4]);
      float4 bv = *reinterpret_cast<const float4*>(&Bs[cc][tx * 4]);
      float a_[4] = {av.x, av.y, av.z, av.w};
      float b_[4] = {bv.x, bv.y, bv.z, bv.w};
#pragma unroll
      for (int u = 0; u < 4; u++)
#pragma unroll
        for (int v = 0; v < 4; v++) acc[u][v] = fmaf(a_[u], b_[v], acc[u][v]);
    }
    __syncthreads();
  }
#pragma unroll
  for (int u = 0; u < 4; u++) {
    long r = row0 + ty * 4 + u;
#pragma unroll
    for (int v = 0; v < 4; v++) {
      int c = col0 + tx * 4 + v;
      if (c < N) {
        float val = acc[u][v] + bias[c];
        if (RELU) val = fmaxf(val, 0.0f);
        C[r * N + c] = val;
      }
    }
  }
}

// ---------------------------------------------------------------------------
// Windowed attention, one block per (query row r, b, k): 32 queries.
// Keys = rows r-3..r+3 (<=7 rows x 32 cols). Two passes:
//   1) scores: stage (kt+pos) row-by-row in LDS; 224 threads (32 q x 7 dc)
//      each do one 256-length banded dot (float4 LDS reads).
//   2) softmax per query over <=49 entries (8 lanes per query, shfl_xor).
//   3) AV: thread = channel; coalesced kt loads from L2; fully-unrolled
//      (ck x d) accumulation into compile-time-indexed acc[32].
// LDS ~75 KB -> 2 blocks/CU.
// ---------------------------------------------------------------------------
__global__ __launch_bounds__(256) void attn_kernel(
    const float* __restrict__ x, const float* __restrict__ kt,
    const float* __restrict__ pos, float* __restrict__ o) {
  __shared__ float q_s[32][260];   // stride 260: float4-aligned, conflict-free
  __shared__ float kr_s[32][260];
  __shared__ float sc_s[32][68];
  int r = blockIdx.x;   // query row 0..31
  int b = blockIdx.y;
  int k = blockIdx.z;
  int tid = threadIdx.x;
  const float scale = 0.0625f;  // 1/sqrt(256)

  const float* xb = x + ((long)b * NTOK + r * 32) * HID;
  const float* pq = pos + (long)r * 32 * HID;
  // stage q+pos scaled: 2048 float4, one row per wave-pass (coalesced)
  for (int f = tid; f < 2048; f += 256) {
    int row = f >> 6;
    int c4 = (f & 63) << 2;
    float4 xv = *reinterpret_cast<const float4*>(&xb[row * HID + c4]);
    float4 pv = *reinterpret_cast<const float4*>(&pq[row * HID + c4]);
    float4 qv;
    qv.x = (xv.x + pv.x) * scale;
    qv.y = (xv.y + pv.y) * scale;
    qv.z = (xv.z + pv.z) * scale;
    qv.w = (xv.w + pv.w) * scale;
    *reinterpret_cast<float4*>(&q_s[row][c4]) = qv;
  }

  int r0 = max(r - 3, 0), r1 = min(r + 3, 31);
  int nkr = r1 - r0 + 1;  // 4..7
  const float* ktb = kt + ((long)(k * BATCH + b)) * NTOK * HID;

  int c_q = tid >> 3, slot = tid & 7;
  int c_k = c_q + slot - 3;
  bool valid = (slot < 7) && (c_k >= 0) && (c_k < 32);

  for (int i = 0; i < nkr; ++i) {
    int kr = r0 + i;
    const float* kb = ktb + (long)kr * 32 * HID;
    const float* pb = pos + (long)kr * 32 * HID;
    __syncthreads();  // also covers q_s staging on i==0
    for (int f = tid; f < 2048; f += 256) {
      int row = f >> 6;
      int c4 = (f & 63) << 2;
      float4 kv = *reinterpret_cast<const float4*>(&kb[row * HID + c4]);
      float4 pv = *reinterpret_cast<const float4*>(&pb[row * HID + c4]);
      float4 sv;
      sv.x = kv.x + pv.x;
      sv.y = kv.y + pv.y;
      sv.z = kv.z + pv.z;
      sv.w = kv.w + pv.w;
      *reinterpret_cast<float4*>(&kr_s[row][c4]) = sv;
    }
    __syncthreads();
    if (slot < 7) {
      if (valid) {
        const float* qp = q_s[c_q];
        const float* kp = kr_s[c_k];
        float a0 = 0.f, a1 = 0.f, a2 = 0.f, a3 = 0.f;
#pragma unroll 16
        for (int j = 0; j < 256; j += 4) {
          float4 qa = *reinterpret_cast<const float4*>(&qp[j]);
          float4 ka = *reinterpret_cast<const float4*>(&kp[j]);
          a0 = fmaf(qa.x, ka.x, a0);
          a1 = fmaf(qa.y, ka.y, a1);
          a2 = fmaf(qa.z, ka.z, a2);
          a3 = fmaf(qa.w, ka.w, a3);
        }
        sc_s[c_q][i * 8 + slot] = (a0 + a1) + (a2 + a3);
      } else {
        sc_s[c_q][i * 8 + slot] = -INFINITY;
      }
    }
  }
  __syncthreads();

  // softmax: 8 lanes per query; lane s8 owns slot s8 across key rows
  {
    int q = tid >> 3, s8 = tid & 7;
    float p[7];
    float mx = -INFINITY;
#pragma unroll
    for (int i = 0; i < 7; ++i) {
      float v = (i < nkr && s8 < 7) ? sc_s[q][i * 8 + s8] : -INFINITY;
      p[i] = v;
      mx = fmaxf(mx, v);
    }
    mx = fmaxf(mx, __shfl_xor(mx, 1));
    mx = fmaxf(mx, __shfl_xor(mx, 2));
    mx = fmaxf(mx, __shfl_xor(mx, 4));
    float sm = 0.f;
#pragma unroll
    for (int i = 0; i < 7; ++i) {
      float e = (i < nkr && s8 < 7) ? expf(p[i] - mx) : 0.f;
      p[i] = e;
      sm += e;
    }
    sm += __shfl_xor(sm, 1);
    sm += __shfl_xor(sm, 2);
    sm += __shfl_xor(sm, 4);
    float rinv = 1.0f / sm;
#pragma unroll
    for (int i = 0; i < 7; ++i) {
      if (i < nkr && s8 < 7) sc_s[q][i * 8 + s8] = p[i] * rinv;
    }
  }
  __syncthreads();

  // AV: thread = channel tid; acc over 32 queries (compile-time indexed)
  float acc[32];
#pragma unroll
  for (int qq = 0; qq < 32; ++qq) acc[qq] = 0.f;
  for (int i = 0; i < nkr; ++i) {
    const float* kb = ktb + (long)(r0 + i) * 32 * HID;
#pragma unroll
    for (int ck = 0; ck < 32; ++ck) {
      float v = kb[ck * HID + tid];
#pragma unroll
      for (int d = -3; d <= 3; ++d) {
        int qq = ck + d;
        if (qq >= 0 && qq < 32) {
          acc[qq] = fmaf(sc_s[qq][i * 8 + (3 - d)], v, acc[qq]);
        }
      }
    }
  }
  long obase = ((long)b * NTOK + (long)r * 32) * (KMEM * HID) + (long)k * HID + tid;
#pragma unroll
  for (int qq = 0; qq < 32; ++qq) {
    o[obase + (long)qq * (KMEM * HID)] = acc[qq];
  }
}

// ---------------------------------------------------------------------------
// x = LayerNorm(x + res) * g + b   (one block per token row, 256 threads)
// ---------------------------------------------------------------------------
__global__ __launch_bounds__(256) void add_ln_kernel(
    const float* __restrict__ x, const float* __restrict__ res,
    const float* __restrict__ g, const float* __restrict__ bta,
    float* __restrict__ out) {
  long row = blockIdx.x;
  int j = threadIdx.x;
  float v = x[row * HID + j] + res[row * HID + j];
  float s = v, s2 = v * v;
#pragma unroll
  for (int off = 32; off > 0; off >>= 1) {
    s += __shfl_xor(s, off);
    s2 += __shfl_xor(s2, off);
  }
  __shared__ float ss[4], ss2[4];
  int wave = j >> 6, lane = j & 63;
  if (lane == 0) {
    ss[wave] = s;
    ss2[wave] = s2;
  }
  __syncthreads();
  s = ss[0] + ss[1] + ss[2] + ss[3];
  s2 = ss2[0] + ss2[1] + ss2[2] + ss2[3];
  float mean = s * (1.f / 256.f);
  float var = s2 * (1.f / 256.f) - mean * mean;
  float inv = rsqrtf(var + LN_EPS);
  out[row * HID + j] = (v - mean) * inv * g[j] + bta[j];
}

// ---------------------------------------------------------------------------
// recon_tokens (b,t,272) -> recon (b,272,32,32) transpose write, plus
// pred_sq[b,t] = sum_c (recon - qf)^2 (no atomics: block owns 32 tokens)
// ---------------------------------------------------------------------------
__global__ __launch_bounds__(256) void recon_out_kernel(
    const float* __restrict__ rt, const float* __restrict__ qf,
    float* __restrict__ recon, float* __restrict__ pred_sq) {
  int b = blockIdx.y;
  int t0 = blockIdx.x * 32;
  __shared__ float tile[32][33];
  int lx = threadIdx.x & 31;
  int ly = threadIdx.x >> 5;  // 0..7
  float sq = 0.f;
  for (int c0 = 0; c0 < DIN; c0 += 32) {
    __syncthreads();
#pragma unroll
    for (int i = 0; i < 4; i++) {
      int tt = ly + i * 8;
      int c = c0 + lx;
      tile[tt][lx] = (c < DIN) ? rt[((long)b * NTOK + t0 + tt) * DIN + c] : 0.f;
    }
    __syncthreads();
#pragma unroll
    for (int i = 0; i < 4; i++) {
      int c = c0 + ly + i * 8;
      if (c < DIN) {
        float v = tile[lx][ly + i * 8];
        long gaddr = ((long)b * DIN + c) * NTOK + t0 + lx;
        float q = qf[gaddr];
        recon[gaddr] = v;
        float d = v - q;
        sq = fmaf(d, d, sq);
      }
    }
  }
  __shared__ float red[8][33];
  red[ly][lx] = sq;
  __syncthreads();
  if (ly == 0) {
    float s = 0.f;
#pragma unroll
    for (int u = 0; u < 8; u++) s += red[u][lx];
    pred_sq[b * NTOK + t0 + lx] = s;
  }
}

// ---------------------------------------------------------------------------
// global min/max of sqrt(pred_sq) over 16384 values, single block
// ---------------------------------------------------------------------------
__global__ __launch_bounds__(256) void minmax_kernel(
    const float* __restrict__ pred_sq, float* __restrict__ mnmx) {
  int tid = threadIdx.x;
  float mn = INFINITY, mx = -INFINITY;
  for (int i = tid; i < BATCH * NTOK; i += 256) {
    float v = sqrtf(pred_sq[i]);
    mn = fminf(mn, v);
    mx = fmaxf(mx, v);
  }
#pragma unroll
  for (int off = 32; off > 0; off >>= 1) {
    mn = fminf(mn, __shfl_xor(mn, off));
    mx = fmaxf(mx, __shfl_xor(mx, off));
  }
  __shared__ float smn[4], smx[4];
  int wave = tid >> 6, lane = tid & 63;
  if (lane == 0) {
    smn[wave] = mn;
    smx[wave] = mx;
  }
  __syncthreads();
  if (tid == 0) {
    mn = fminf(fminf(smn[0], smn[1]), fminf(smn[2], smn[3]));
    mx = fmaxf(fmaxf(smx[0], smx[1]), fmaxf(smx[2], smx[3]));
    mnmx[0] = mn;
    mnmx[1] = mx;
  }
}

// ---------------------------------------------------------------------------
// bilinear upsample (align_corners) 32x32 -> 256x256 with normalization
// ---------------------------------------------------------------------------
__global__ __launch_bounds__(256) void resize_kernel(
    const float* __restrict__ pred_sq, const float* __restrict__ mnmx,
    float* __restrict__ out) {
  long idx = (long)blockIdx.x * 256 + threadIdx.x;
  if (idx >= (long)BATCH * 256 * 256) return;
  int b = (int)(idx >> 16);
  int oy = (int)((idx >> 8) & 255), ox = (int)(idx & 255);
  float mn = mnmx[0], mx = mnmx[1];
  float inv = 1.0f / (mx - mn);
  float ys = oy * (31.0f / 255.0f);
  int y0 = (int)floorf(ys);
  int y1 = min(y0 + 1, 31);
  float fy = ys - (float)y0;
  float xs = ox * (31.0f / 255.0f);
  int x0 = (int)floorf(xs);
  int x1 = min(x0 + 1, 31);
  float fx = xs - (float)x0;
  const float* p = pred_sq + b * NTOK;
  float v00 = sqrtf(p[y0 * 32 + x0]), v01 = sqrtf(p[y0 * 32 + x1]);
  float v10 = sqrtf(p[y1 * 32 + x0]), v11 = sqrtf(p[y1 * 32 + x1]);
  float cA = v00 * (1.f - fy) + v10 * fy;
  float cB = v01 * (1.f - fy) + v11 * fy;
  float v = cA * (1.f - fx) + cB * fx;
  out[idx] = (v - mn) * inv;
}

// ---------------------------------------------------------------------------
extern "C" void kernel_launch(void* const* d_in, const int* in_sizes, int n_in,
                              void* d_out, int out_size, void* d_ws,
                              size_t ws_size, hipStream_t stream) {
  const float* qf = (const float*)d_in[0];     // (16,272,32,32)
  const float* mf = (const float*)d_in[1];     // (4,16,272,32,32)
  const float* qW = (const float*)d_in[2];     // (272,256)
  const float* qb = (const float*)d_in[3];     // (256)
  const float* kvW = (const float*)d_in[4];    // (272,256)
  const float* kvb = (const float*)d_in[5];    // (256)
  const float* row_e = (const float*)d_in[6];  // (32,128)
  const float* col_e = (const float*)d_in[7];  // (32,128)
  const float* aggW = (const float*)d_in[8];   // (2,1024,256)
  const float* aggb = (const float*)d_in[9];   // (2,256)
  const float* n1g = (const float*)d_in[10];   // (2,256)
  const float* n1b = (const float*)d_in[11];
  const float* l1W = (const float*)d_in[12];  // (2,256,1024)
  const float* l1b = (const float*)d_in[13];  // (2,1024)
  const float* l2W = (const float*)d_in[14];  // (2,1024,256)
  const float* l2b = (const float*)d_in[15];  // (2,256)
  const float* n2g = (const float*)d_in[16];
  const float* n2b = (const float*)d_in[17];
  const float* outW = (const float*)d_in[18];  // (256,272)
  const float* outb = (const float*)d_in[19];  // (272)

  float* out = (float*)d_out;
  float* recon = out;                            // 16*272*1024
  float* pred = out + (long)BATCH * DIN * NTOK;  // 16*256*256

  // workspace layout (floats)
  float* ws = (float*)d_ws;
  float* pos = ws;                    // 262144
  float* x = pos + 262144;            // 4194304
  float* kt = x + 4194304;            // 16777216
  float* buf1024 = kt + 16777216;     // 16777216 (attn o / ff hidden / recon_tokens)
  float* tmp256 = buf1024 + 16777216; // 4194304
  float* pred_sq = tmp256 + 4194304;  // 16384
  float* mnmx = pred_sq + 16384;      // 2

  const long BS_FEAT = (long)DIN * NTOK;  // 278528

  // pos embed
  pos_kernel<<<NTOK, 256, 0, stream>>>(row_e, col_e, pos);

  // q projection: (16384,272) @ (272,256) -> x
  {
    dim3 grid(256 / 64, (BATCH * NTOK) / 64);
    gemm_kernel<1, false><<<grid, 256, 0, stream>>>(qf, qW, qb, x,
                                                    BATCH * NTOK, HID, DIN,
                                                    BS_FEAT);
  }
  // kv projection: (65536,272) @ (272,256) -> kt
  {
    dim3 grid(256 / 64, (KMEM * BATCH * NTOK) / 64);
    gemm_kernel<1, false><<<grid, 256, 0, stream>>>(
        mf, kvW, kvb, kt, KMEM * BATCH * NTOK, HID, DIN, BS_FEAT);
  }

  for (int l = 0; l < 2; l++) {
    // attention -> buf1024 (b,n,k*256)
    {
      dim3 grid(32, BATCH, KMEM);
      attn_kernel<<<grid, 256, 0, stream>>>(x, kt, pos, buf1024);
    }
    // agg: (16384,1024)@(1024,256) -> tmp256
    {
      dim3 grid(256 / 64, (BATCH * NTOK) / 64);
      gemm_kernel<0, false><<<grid, 256, 0, stream>>>(
          buf1024, aggW + (long)l * 1024 * 256, aggb + l * 256, tmp256,
          BATCH * NTOK, HID, KMEM * HID, 0);
    }
    add_ln_kernel<<<BATCH * NTOK, 256, 0, stream>>>(x, tmp256, n1g + l * 256,
                                                    n1b + l * 256, x);
    // ff1: (16384,256)@(256,1024) relu -> buf1024
    {
      dim3 grid(1024 / 64, (BATCH * NTOK) / 64);
      gemm_kernel<0, true><<<grid, 256, 0, stream>>>(
          x, l1W + (long)l * 256 * 1024, l1b + l * 1024, buf1024, BATCH * NTOK,
          DFF, HID, 0);
    }
    // ff2: (16384,1024)@(1024,256) -> tmp256
    {
      dim3 grid(256 / 64, (BATCH * NTOK) / 64);
      gemm_kernel<0, false><<<grid, 256, 0, stream>>>(
          buf1024, l2W + (long)l * 1024 * 256, l2b + l * 256, tmp256,
          BATCH * NTOK, HID, DFF, 0);
    }
    add_ln_kernel<<<BATCH * NTOK, 256, 0, stream>>>(x, tmp256, n2g + l * 256,
                                                    n2b + l * 256, x);
  }

  // out projection: (16384,256)@(256,272) -> recon_tokens (reuse buf1024)
  {
    dim3 grid((DIN + 63) / 64, (BATCH * NTOK) / 64);
    gemm_kernel<0, false><<<grid, 256, 0, stream>>>(x, outW, outb, buf1024,
                                                    BATCH * NTOK, DIN, HID, 0);
  }
  // transpose to recon + per-token squared error
  {
    dim3 grid(NTOK / 32, BATCH);
    recon_out_kernel<<<grid, 256, 0, stream>>>(buf1024, qf, recon, pred_sq);
  }
  minmax_kernel<<<1, 256, 0, stream>>>(pred_sq, mnmx);
  resize_kernel<<<(BATCH * 256 * 256) / 256, 256, 0, stream>>>(pred_sq, mnmx,
                                                               pred);
}

// Round 3
// 1112.185 us; speedup vs baseline: 2.2097x; 1.4915x over previous
//
#include <hip/hip_runtime.h>
#include <hip/hip_bf16.h>
#include <math.h>

// Problem constants
#define BATCH 16
#define NTOK 1024      // 32*32
#define HID 256
#define KMEM 4
#define DIN 272
#define DFF 1024
#define LN_EPS 1e-5f

using short8 = __attribute__((ext_vector_type(8))) short;
using short4v = __attribute__((ext_vector_type(4))) short;
using floatx4 = __attribute__((ext_vector_type(4))) float;

__device__ inline short f2bf(float f) {
  unsigned u = __builtin_bit_cast(unsigned, f);
  u += 0x7fff + ((u >> 16) & 1);  // RNE
  return (short)(u >> 16);
}

// ---------------------------------------------------------------------------
// pos embed: pos[t][j] = j<128 ? col_embed[t%32][j] : row_embed[t/32][j-128]
// ---------------------------------------------------------------------------
__global__ __launch_bounds__(256) void pos_kernel(
    const float* __restrict__ row_e, const float* __restrict__ col_e,
    float* __restrict__ pos) {
  int t = blockIdx.x;
  int j = threadIdx.x;
  float v = (j < 128) ? col_e[(t & 31) * 128 + j]
                      : row_e[(t >> 5) * 128 + (j - 128)];
  pos[t * 256 + j] = v;
}

// ---------------------------------------------------------------------------
// Weight transpose + cvt: W[K][N] fp32 -> Wt[N][K] bf16
// ---------------------------------------------------------------------------
__global__ __launch_bounds__(256) void wt_cvt_kernel(
    const float* __restrict__ W, short* __restrict__ Wt, int K, int N) {
  __shared__ short tile[32][33];
  int n0 = blockIdx.x * 32, k0 = blockIdx.y * 32;
  int tx = threadIdx.x & 31, ty8 = threadIdx.x >> 5;
#pragma unroll
  for (int i = 0; i < 4; i++) {
    int k = k0 + ty8 + i * 8;
    int n = n0 + tx;
    float v = (k < K && n < N) ? W[(long)k * N + n] : 0.f;
    tile[ty8 + i * 8][tx] = f2bf(v);
  }
  __syncthreads();
#pragma unroll
  for (int i = 0; i < 4; i++) {
    int n = n0 + ty8 + i * 8;
    int k = k0 + tx;
    if (n < N && k < K) Wt[(long)n * K + k] = tile[tx][ty8 + i * 8];
  }
}

// ---------------------------------------------------------------------------
// MFMA bf16 GEMM: C[M,N] = A[M,K](fp32,row-major, cvt on stage) @ Wt[N,K](bf16)
//                 + bias, optional ReLU.  Tile 128x128, BK=32, 4 waves (2x2),
//                 each wave 64x64 = 4x4 frags of 16x16x32.
// M%128==0, K%32==0; N guarded.
// ---------------------------------------------------------------------------
template <bool RELU>
__global__ __launch_bounds__(256) void mfma_gemm_kernel(
    const float* __restrict__ A, const short* __restrict__ Wt,
    const float* __restrict__ bias, float* __restrict__ C,
    int M, int N, int K) {
  __shared__ short As[128][40];  // [m][k] bf16, +8 pad
  __shared__ short Bs[128][40];  // [n][k] bf16, +8 pad
  int tid = threadIdx.x;
  int row0 = blockIdx.y * 128, col0 = blockIdx.x * 128;
  int wid = tid >> 6, lane = tid & 63;
  int wr = (wid >> 1) * 64, wc = (wid & 1) * 64;
  int lcol = lane & 15, kg = lane >> 4;

  floatx4 acc[4][4];
#pragma unroll
  for (int m = 0; m < 4; ++m)
#pragma unroll
    for (int n = 0; n < 4; ++n) acc[m][n] = (floatx4){0.f, 0.f, 0.f, 0.f};

  for (int k0 = 0; k0 < K; k0 += 32) {
    // stage A: 128x32 fp32 -> bf16 (1024 chunks of 4)
#pragma unroll
    for (int p = 0; p < 4; ++p) {
      int chunk = p * 256 + tid;
      int m = chunk >> 3, kc4 = (chunk & 7) * 4;
      floatx4 v = *reinterpret_cast<const floatx4*>(
          &A[(long)(row0 + m) * K + k0 + kc4]);
      short4v s;
      s[0] = f2bf(v[0]);
      s[1] = f2bf(v[1]);
      s[2] = f2bf(v[2]);
      s[3] = f2bf(v[3]);
      *reinterpret_cast<short4v*>(&As[m][kc4]) = s;
    }
    // stage B: 128x32 bf16 direct copy (512 chunks of 8)
#pragma unroll
    for (int p = 0; p < 2; ++p) {
      int chunk = p * 256 + tid;
      int n = chunk >> 2, kc8 = (chunk & 3) * 8;
      short8 v;
      if (col0 + n < N) {
        v = *reinterpret_cast<const short8*>(&Wt[(long)(col0 + n) * K + k0 + kc8]);
      } else {
        v = (short8){0, 0, 0, 0, 0, 0, 0, 0};
      }
      *reinterpret_cast<short8*>(&Bs[n][kc8]) = v;
    }
    __syncthreads();
    short8 af[4], bfr[4];
#pragma unroll
    for (int m = 0; m < 4; ++m)
      af[m] = *reinterpret_cast<const short8*>(&As[wr + m * 16 + lcol][kg * 8]);
#pragma unroll
    for (int n = 0; n < 4; ++n)
      bfr[n] = *reinterpret_cast<const short8*>(&Bs[wc + n * 16 + lcol][kg * 8]);
#pragma unroll
    for (int m = 0; m < 4; ++m)
#pragma unroll
      for (int n = 0; n < 4; ++n)
        acc[m][n] = __builtin_amdgcn_mfma_f32_16x16x32_bf16(af[m], bfr[n],
                                                            acc[m][n], 0, 0, 0);
    __syncthreads();
  }
  // epilogue: C/D layout col=lane&15, row=(lane>>4)*4+reg
#pragma unroll
  for (int n = 0; n < 4; ++n) {
    int c = col0 + wc + n * 16 + lcol;
    if (c >= N) continue;
    float bv = bias[c];
#pragma unroll
    for (int m = 0; m < 4; ++m) {
      int rbase = row0 + wr + m * 16 + kg * 4;
#pragma unroll
      for (int q = 0; q < 4; ++q) {
        float val = acc[m][n][q] + bv;
        if (RELU) val = fmaxf(val, 0.f);
        C[(long)(rbase + q) * N + c] = val;
      }
    }
  }
}

// ---------------------------------------------------------------------------
// Generic tiled fp32 GEMM (kept for batched-col-major A: q/kv projections)
// ---------------------------------------------------------------------------
template <int ALAYOUT, bool RELU>
__global__ __launch_bounds__(256) void gemm_kernel(
    const float* __restrict__ A, const float* __restrict__ W,
    const float* __restrict__ bias, float* __restrict__ C,
    int M, int N, int K, long batchStrideA) {
  __shared__ float As[16][68];
  __shared__ float Bs[16][68];
  int tid = threadIdx.x;
  int tx = tid & 15, ty = tid >> 4;
  int row0 = blockIdx.y * 64;
  int col0 = blockIdx.x * 64;
  float acc[4][4] = {};
  const float* Abase;
  if (ALAYOUT == 1) {
    int b = row0 >> 10;
    Abase = A + (long)b * batchStrideA + (row0 & 1023);
  } else {
    Abase = A + (long)row0 * K;
  }
  for (int k0 = 0; k0 < K; k0 += 16) {
#pragma unroll
    for (int i = 0; i < 4; i++) {
      int idx = i * 256 + tid;
      if (ALAYOUT == 1) {
        int tt = idx & 63, cc = idx >> 6;
        As[cc][tt] = Abase[(long)(k0 + cc) * 1024 + tt];
      } else {
        int cc = idx & 15, tt = idx >> 4;
        As[cc][tt] = Abase[(long)tt * K + k0 + cc];
      }
    }
#pragma unroll
    for (int i = 0; i < 4; i++) {
      int idx = i * 256 + tid;
      int cc = idx >> 6, jj = idx & 63;
      int col = col0 + jj;
      Bs[cc][jj] = (col < N) ? W[(long)(k0 + cc) * N + col] : 0.0f;
    }
    __syncthreads();
#pragma unroll
    for (int cc = 0; cc < 16; cc++) {
      float4 av = *reinterpret_cast<const float4*>(&As[cc][ty * 4]);
      float4 bv = *reinterpret_cast<const float4*>(&Bs[cc][tx * 4]);
      float a_[4] = {av.x, av.y, av.z, av.w};
      float b_[4] = {bv.x, bv.y, bv.z, bv.w};
#pragma unroll
      for (int u = 0; u < 4; u++)
#pragma unroll
        for (int v = 0; v < 4; v++) acc[u][v] = fmaf(a_[u], b_[v], acc[u][v]);
    }
    __syncthreads();
  }
#pragma unroll
  for (int u = 0; u < 4; u++) {
    long r = row0 + ty * 4 + u;
#pragma unroll
    for (int v = 0; v < 4; v++) {
      int c = col0 + tx * 4 + v;
      if (c < N) {
        float val = acc[u][v] + bias[c];
        if (RELU) val = fmaxf(val, 0.0f);
        C[r * N + c] = val;
      }
    }
  }
}

// ---------------------------------------------------------------------------
// Windowed attention, one block per (query row r, b, k), XCD-swizzled so all
// 32 r-blocks of a (b,k) kt-slice land on the same XCD (L2 locality).
// ---------------------------------------------------------------------------
__global__ __launch_bounds__(256) void attn_kernel(
    const float* __restrict__ x, const float* __restrict__ kt,
    const float* __restrict__ pos, float* __restrict__ o) {
  __shared__ float q_s[32][260];
  __shared__ float kr_s[32][260];
  __shared__ float sc_s[32][68];
  // bijective XCD swizzle: 2048 blocks, 8 XCDs, 8 (b,k)-slices per XCD
  int h = blockIdx.x + 32 * (blockIdx.y + 16 * blockIdx.z);
  int xcd = h & 7, j = h >> 3;
  int s = xcd * 8 + (j >> 5);
  int r = j & 31;
  int b = s & 15, k = s >> 4;
  int tid = threadIdx.x;
  const float scale = 0.0625f;  // 1/sqrt(256)

  const float* xb = x + ((long)b * NTOK + r * 32) * HID;
  const float* pq = pos + (long)r * 32 * HID;
  for (int f = tid; f < 2048; f += 256) {
    int row = f >> 6;
    int c4 = (f & 63) << 2;
    float4 xv = *reinterpret_cast<const float4*>(&xb[row * HID + c4]);
    float4 pv = *reinterpret_cast<const float4*>(&pq[row * HID + c4]);
    float4 qv;
    qv.x = (xv.x + pv.x) * scale;
    qv.y = (xv.y + pv.y) * scale;
    qv.z = (xv.z + pv.z) * scale;
    qv.w = (xv.w + pv.w) * scale;
    *reinterpret_cast<float4*>(&q_s[row][c4]) = qv;
  }

  int r0 = max(r - 3, 0), r1 = min(r + 3, 31);
  int nkr = r1 - r0 + 1;  // 4..7
  const float* ktb = kt + ((long)(k * BATCH + b)) * NTOK * HID;

  int c_q = tid >> 3, slot = tid & 7;
  int c_k = c_q + slot - 3;
  bool valid = (slot < 7) && (c_k >= 0) && (c_k < 32);

  for (int i = 0; i < nkr; ++i) {
    int kr = r0 + i;
    const float* kb = ktb + (long)kr * 32 * HID;
    const float* pb = pos + (long)kr * 32 * HID;
    __syncthreads();
    for (int f = tid; f < 2048; f += 256) {
      int row = f >> 6;
      int c4 = (f & 63) << 2;
      float4 kv = *reinterpret_cast<const float4*>(&kb[row * HID + c4]);
      float4 pv = *reinterpret_cast<const float4*>(&pb[row * HID + c4]);
      float4 sv;
      sv.x = kv.x + pv.x;
      sv.y = kv.y + pv.y;
      sv.z = kv.z + pv.z;
      sv.w = kv.w + pv.w;
      *reinterpret_cast<float4*>(&kr_s[row][c4]) = sv;
    }
    __syncthreads();
    if (slot < 7) {
      if (valid) {
        const float* qp = q_s[c_q];
        const float* kp = kr_s[c_k];
        float a0 = 0.f, a1 = 0.f, a2 = 0.f, a3 = 0.f;
#pragma unroll 16
        for (int jj = 0; jj < 256; jj += 4) {
          float4 qa = *reinterpret_cast<const float4*>(&qp[jj]);
          float4 ka = *reinterpret_cast<const float4*>(&kp[jj]);
          a0 = fmaf(qa.x, ka.x, a0);
          a1 = fmaf(qa.y, ka.y, a1);
          a2 = fmaf(qa.z, ka.z, a2);
          a3 = fmaf(qa.w, ka.w, a3);
        }
        sc_s[c_q][i * 8 + slot] = (a0 + a1) + (a2 + a3);
      } else {
        sc_s[c_q][i * 8 + slot] = -INFINITY;
      }
    }
  }
  __syncthreads();

  {
    int q = tid >> 3, s8 = tid & 7;
    float p[7];
    float mx = -INFINITY;
#pragma unroll
    for (int i = 0; i < 7; ++i) {
      float v = (i < nkr && s8 < 7) ? sc_s[q][i * 8 + s8] : -INFINITY;
      p[i] = v;
      mx = fmaxf(mx, v);
    }
    mx = fmaxf(mx, __shfl_xor(mx, 1));
    mx = fmaxf(mx, __shfl_xor(mx, 2));
    mx = fmaxf(mx, __shfl_xor(mx, 4));
    float sm = 0.f;
#pragma unroll
    for (int i = 0; i < 7; ++i) {
      float e = (i < nkr && s8 < 7) ? expf(p[i] - mx) : 0.f;
      p[i] = e;
      sm += e;
    }
    sm += __shfl_xor(sm, 1);
    sm += __shfl_xor(sm, 2);
    sm += __shfl_xor(sm, 4);
    float rinv = 1.0f / sm;
#pragma unroll
    for (int i = 0; i < 7; ++i) {
      if (i < nkr && s8 < 7) sc_s[q][i * 8 + s8] = p[i] * rinv;
    }
  }
  __syncthreads();

  float acc[32];
#pragma unroll
  for (int qq = 0; qq < 32; ++qq) acc[qq] = 0.f;
  for (int i = 0; i < nkr; ++i) {
    const float* kb = ktb + (long)(r0 + i) * 32 * HID;
#pragma unroll
    for (int ck = 0; ck < 32; ++ck) {
      float v = kb[ck * HID + tid];
#pragma unroll
      for (int d = -3; d <= 3; ++d) {
        int qq = ck + d;
        if (qq >= 0 && qq < 32) {
          acc[qq] = fmaf(sc_s[qq][i * 8 + (3 - d)], v, acc[qq]);
        }
      }
    }
  }
  long obase = ((long)b * NTOK + (long)r * 32) * (KMEM * HID) + (long)k * HID + tid;
#pragma unroll
  for (int qq = 0; qq < 32; ++qq) {
    o[obase + (long)qq * (KMEM * HID)] = acc[qq];
  }
}

// ---------------------------------------------------------------------------
// x = LayerNorm(x + res) * g + b
// ---------------------------------------------------------------------------
__global__ __launch_bounds__(256) void add_ln_kernel(
    const float* __restrict__ x, const float* __restrict__ res,
    const float* __restrict__ g, const float* __restrict__ bta,
    float* __restrict__ out) {
  long row = blockIdx.x;
  int j = threadIdx.x;
  float v = x[row * HID + j] + res[row * HID + j];
  float s = v, s2 = v * v;
#pragma unroll
  for (int off = 32; off > 0; off >>= 1) {
    s += __shfl_xor(s, off);
    s2 += __shfl_xor(s2, off);
  }
  __shared__ float ss[4], ss2[4];
  int wave = j >> 6, lane = j & 63;
  if (lane == 0) {
    ss[wave] = s;
    ss2[wave] = s2;
  }
  __syncthreads();
  s = ss[0] + ss[1] + ss[2] + ss[3];
  s2 = ss2[0] + ss2[1] + ss2[2] + ss2[3];
  float mean = s * (1.f / 256.f);
  float var = s2 * (1.f / 256.f) - mean * mean;
  float inv = rsqrtf(var + LN_EPS);
  out[row * HID + j] = (v - mean) * inv * g[j] + bta[j];
}

// ---------------------------------------------------------------------------
// recon_tokens (b,t,272) -> recon (b,272,32,32) + pred_sq
// ---------------------------------------------------------------------------
__global__ __launch_bounds__(256) void recon_out_kernel(
    const float* __restrict__ rt, const float* __restrict__ qf,
    float* __restrict__ recon, float* __restrict__ pred_sq) {
  int b = blockIdx.y;
  int t0 = blockIdx.x * 32;
  __shared__ float tile[32][33];
  int lx = threadIdx.x & 31;
  int ly = threadIdx.x >> 5;
  float sq = 0.f;
  for (int c0 = 0; c0 < DIN; c0 += 32) {
    __syncthreads();
#pragma unroll
    for (int i = 0; i < 4; i++) {
      int tt = ly + i * 8;
      int c = c0 + lx;
      tile[tt][lx] = (c < DIN) ? rt[((long)b * NTOK + t0 + tt) * DIN + c] : 0.f;
    }
    __syncthreads();
#pragma unroll
    for (int i = 0; i < 4; i++) {
      int c = c0 + ly + i * 8;
      if (c < DIN) {
        float v = tile[lx][ly + i * 8];
        long gaddr = ((long)b * DIN + c) * NTOK + t0 + lx;
        float q = qf[gaddr];
        recon[gaddr] = v;
        float d = v - q;
        sq = fmaf(d, d, sq);
      }
    }
  }
  __shared__ float red[8][33];
  red[ly][lx] = sq;
  __syncthreads();
  if (ly == 0) {
    float s = 0.f;
#pragma unroll
    for (int u = 0; u < 8; u++) s += red[u][lx];
    pred_sq[b * NTOK + t0 + lx] = s;
  }
}

__global__ __launch_bounds__(256) void minmax_kernel(
    const float* __restrict__ pred_sq, float* __restrict__ mnmx) {
  int tid = threadIdx.x;
  float mn = INFINITY, mx = -INFINITY;
  for (int i = tid; i < BATCH * NTOK; i += 256) {
    float v = sqrtf(pred_sq[i]);
    mn = fminf(mn, v);
    mx = fmaxf(mx, v);
  }
#pragma unroll
  for (int off = 32; off > 0; off >>= 1) {
    mn = fminf(mn, __shfl_xor(mn, off));
    mx = fmaxf(mx, __shfl_xor(mx, off));
  }
  __shared__ float smn[4], smx[4];
  int wave = tid >> 6, lane = tid & 63;
  if (lane == 0) {
    smn[wave] = mn;
    smx[wave] = mx;
  }
  __syncthreads();
  if (tid == 0) {
    mn = fminf(fminf(smn[0], smn[1]), fminf(smn[2], smn[3]));
    mx = fmaxf(fmaxf(smx[0], smx[1]), fmaxf(smx[2], smx[3]));
    mnmx[0] = mn;
    mnmx[1] = mx;
  }
}

__global__ __launch_bounds__(256) void resize_kernel(
    const float* __restrict__ pred_sq, const float* __restrict__ mnmx,
    float* __restrict__ out) {
  long idx = (long)blockIdx.x * 256 + threadIdx.x;
  if (idx >= (long)BATCH * 256 * 256) return;
  int b = (int)(idx >> 16);
  int oy = (int)((idx >> 8) & 255), ox = (int)(idx & 255);
  float mn = mnmx[0], mx = mnmx[1];
  float inv = 1.0f / (mx - mn);
  float ys = oy * (31.0f / 255.0f);
  int y0 = (int)floorf(ys);
  int y1 = min(y0 + 1, 31);
  float fy = ys - (float)y0;
  float xs = ox * (31.0f / 255.0f);
  int x0 = (int)floorf(xs);
  int x1 = min(x0 + 1, 31);
  float fx = xs - (float)x0;
  const float* p = pred_sq + b * NTOK;
  float v00 = sqrtf(p[y0 * 32 + x0]), v01 = sqrtf(p[y0 * 32 + x1]);
  float v10 = sqrtf(p[y1 * 32 + x0]), v11 = sqrtf(p[y1 * 32 + x1]);
  float cA = v00 * (1.f - fy) + v10 * fy;
  float cB = v01 * (1.f - fy) + v11 * fy;
  float v = cA * (1.f - fx) + cB * fx;
  out[idx] = (v - mn) * inv;
}

// ---------------------------------------------------------------------------
extern "C" void kernel_launch(void* const* d_in, const int* in_sizes, int n_in,
                              void* d_out, int out_size, void* d_ws,
                              size_t ws_size, hipStream_t stream) {
  const float* qf = (const float*)d_in[0];
  const float* mf = (const float*)d_in[1];
  const float* qW = (const float*)d_in[2];
  const float* qb = (const float*)d_in[3];
  const float* kvW = (const float*)d_in[4];
  const float* kvb = (const float*)d_in[5];
  const float* row_e = (const float*)d_in[6];
  const float* col_e = (const float*)d_in[7];
  const float* aggW = (const float*)d_in[8];
  const float* aggb = (const float*)d_in[9];
  const float* n1g = (const float*)d_in[10];
  const float* n1b = (const float*)d_in[11];
  const float* l1W = (const float*)d_in[12];
  const float* l1b = (const float*)d_in[13];
  const float* l2W = (const float*)d_in[14];
  const float* l2b = (const float*)d_in[15];
  const float* n2g = (const float*)d_in[16];
  const float* n2b = (const float*)d_in[17];
  const float* outW = (const float*)d_in[18];
  const float* outb = (const float*)d_in[19];

  float* out = (float*)d_out;
  float* recon = out;                            // 16*272*1024
  float* pred = out + (long)BATCH * DIN * NTOK;  // 16*256*256

  // bf16 transposed weights stashed in recon region of d_out (3.3MB < 17.8MB),
  // fully consumed before recon_out_kernel overwrites it at the end.
  short* wt = (short*)d_out;
  short* wt_agg0 = wt;                   // [256][1024]
  short* wt_agg1 = wt_agg0 + 262144;     // [256][1024]
  short* wt_l1_0 = wt_agg1 + 262144;     // [1024][256]
  short* wt_l1_1 = wt_l1_0 + 262144;     // [1024][256]
  short* wt_l2_0 = wt_l1_1 + 262144;     // [256][1024]
  short* wt_l2_1 = wt_l2_0 + 262144;     // [256][1024]
  short* wt_out = wt_l2_1 + 262144;      // [272][256]

  // workspace layout (floats)
  float* ws = (float*)d_ws;
  float* pos = ws;                     // 262144
  float* x = pos + 262144;             // 4194304
  float* kt = x + 4194304;             // 16777216
  float* buf1024 = kt + 16777216;      // 16777216
  float* tmp256 = buf1024 + 16777216;  // 4194304
  float* pred_sq = tmp256 + 4194304;   // 16384
  float* mnmx = pred_sq + 16384;       // 2

  const long BS_FEAT = (long)DIN * NTOK;

  pos_kernel<<<NTOK, 256, 0, stream>>>(row_e, col_e, pos);

  // weight cvt+transpose (into d_out scratch)
  wt_cvt_kernel<<<dim3(8, 32), 256, 0, stream>>>(aggW, wt_agg0, 1024, 256);
  wt_cvt_kernel<<<dim3(8, 32), 256, 0, stream>>>(aggW + 262144, wt_agg1, 1024, 256);
  wt_cvt_kernel<<<dim3(32, 8), 256, 0, stream>>>(l1W, wt_l1_0, 256, 1024);
  wt_cvt_kernel<<<dim3(32, 8), 256, 0, stream>>>(l1W + 262144, wt_l1_1, 256, 1024);
  wt_cvt_kernel<<<dim3(8, 32), 256, 0, stream>>>(l2W, wt_l2_0, 1024, 256);
  wt_cvt_kernel<<<dim3(8, 32), 256, 0, stream>>>(l2W + 262144, wt_l2_1, 1024, 256);
  wt_cvt_kernel<<<dim3(9, 8), 256, 0, stream>>>(outW, wt_out, 256, 272);

  // q projection (fp32 path, batched col-major A)
  {
    dim3 grid(256 / 64, (BATCH * NTOK) / 64);
    gemm_kernel<1, false><<<grid, 256, 0, stream>>>(qf, qW, qb, x,
                                                    BATCH * NTOK, HID, DIN,
                                                    BS_FEAT);
  }
  // kv projection
  {
    dim3 grid(256 / 64, (KMEM * BATCH * NTOK) / 64);
    gemm_kernel<1, false><<<grid, 256, 0, stream>>>(
        mf, kvW, kvb, kt, KMEM * BATCH * NTOK, HID, DIN, BS_FEAT);
  }

  for (int l = 0; l < 2; l++) {
    {
      dim3 grid(32, BATCH, KMEM);
      attn_kernel<<<grid, 256, 0, stream>>>(x, kt, pos, buf1024);
    }
    // agg: (16384,1024)@Wt[256][1024] -> tmp256
    {
      dim3 grid(2, 128);
      mfma_gemm_kernel<false><<<grid, 256, 0, stream>>>(
          buf1024, l ? wt_agg1 : wt_agg0, aggb + l * 256, tmp256,
          BATCH * NTOK, HID, KMEM * HID);
    }
    add_ln_kernel<<<BATCH * NTOK, 256, 0, stream>>>(x, tmp256, n1g + l * 256,
                                                    n1b + l * 256, x);
    // ff1: (16384,256)@Wt[1024][256] relu -> buf1024
    {
      dim3 grid(8, 128);
      mfma_gemm_kernel<true><<<grid, 256, 0, stream>>>(
          x, l ? wt_l1_1 : wt_l1_0, l1b + l * 1024, buf1024, BATCH * NTOK,
          DFF, HID);
    }
    // ff2: (16384,1024)@Wt[256][1024] -> tmp256
    {
      dim3 grid(2, 128);
      mfma_gemm_kernel<false><<<grid, 256, 0, stream>>>(
          buf1024, l ? wt_l2_1 : wt_l2_0, l2b + l * 256, tmp256, BATCH * NTOK,
          HID, DFF);
    }
    add_ln_kernel<<<BATCH * NTOK, 256, 0, stream>>>(x, tmp256, n2g + l * 256,
                                                    n2b + l * 256, x);
  }

  // out projection: (16384,256)@Wt[272][256] -> recon_tokens (buf1024)
  {
    dim3 grid(3, 128);
    mfma_gemm_kernel<false><<<grid, 256, 0, stream>>>(
        x, wt_out, outb, buf1024, BATCH * NTOK, DIN, HID);
  }
  {
    dim3 grid(NTOK / 32, BATCH);
    recon_out_kernel<<<grid, 256, 0, stream>>>(buf1024, qf, recon, pred_sq);
  }
  minmax_kernel<<<1, 256, 0, stream>>>(pred_sq, mnmx);
  resize_kernel<<<(BATCH * 256 * 256) / 256, 256, 0, stream>>>(pred_sq, mnmx,
                                                               pred);
}

// Round 4
// 866.617 us; speedup vs baseline: 2.8358x; 1.2834x over previous
//
#include <hip/hip_runtime.h>
#include <hip/hip_bf16.h>
#include <math.h>

// Problem constants
#define BATCH 16
#define NTOK 1024      // 32*32
#define HID 256
#define KMEM 4
#define DIN 272
#define DFF 1024
#define LN_EPS 1e-5f

using short8 = __attribute__((ext_vector_type(8))) short;
using short4v = __attribute__((ext_vector_type(4))) short;
using floatx4 = __attribute__((ext_vector_type(4))) float;

__device__ inline short f2bf(float f) {
  unsigned u = __builtin_bit_cast(unsigned, f);
  u += 0x7fff + ((u >> 16) & 1);  // RNE
  return (short)(u >> 16);
}
__device__ inline float bf2f(short s) {
  unsigned u = ((unsigned)(unsigned short)s) << 16;
  return __builtin_bit_cast(float, u);
}

// ---------------------------------------------------------------------------
// pos embed: pos[t][j] = j<128 ? col_embed[t%32][j] : row_embed[t/32][j-128]
// ---------------------------------------------------------------------------
__global__ __launch_bounds__(256) void pos_kernel(
    const float* __restrict__ row_e, const float* __restrict__ col_e,
    float* __restrict__ pos) {
  int t = blockIdx.x;
  int j = threadIdx.x;
  float v = (j < 128) ? col_e[(t & 31) * 128 + j]
                      : row_e[(t >> 5) * 128 + (j - 128)];
  pos[t * 256 + j] = v;
}

// ---------------------------------------------------------------------------
// ktp = bf16(float(ktb16) + pos)  (16.78M elems, 4 per thread)
// ---------------------------------------------------------------------------
__global__ __launch_bounds__(256) void ktp_kernel(
    const short* __restrict__ ktb, const float* __restrict__ pos,
    short* __restrict__ ktp) {
  long i4 = ((long)blockIdx.x * 256 + threadIdx.x) * 4;
  short4v kv = *reinterpret_cast<const short4v*>(&ktb[i4]);
  int t = (int)((i4 >> 8) & 1023);
  int ch = (int)(i4 & 255);
  float4 pv = *reinterpret_cast<const float4*>(&pos[t * 256 + ch]);
  short4v o;
  o[0] = f2bf(bf2f(kv[0]) + pv.x);
  o[1] = f2bf(bf2f(kv[1]) + pv.y);
  o[2] = f2bf(bf2f(kv[2]) + pv.z);
  o[3] = f2bf(bf2f(kv[3]) + pv.w);
  *reinterpret_cast<short4v*>(&ktp[i4]) = o;
}

// ---------------------------------------------------------------------------
// Weight transpose + cvt: W[K][N] fp32 -> Wt[N][K] bf16
// ---------------------------------------------------------------------------
__global__ __launch_bounds__(256) void wt_cvt_kernel(
    const float* __restrict__ W, short* __restrict__ Wt, int K, int N) {
  __shared__ short tile[32][33];
  int n0 = blockIdx.x * 32, k0 = blockIdx.y * 32;
  int tx = threadIdx.x & 31, ty8 = threadIdx.x >> 5;
#pragma unroll
  for (int i = 0; i < 4; i++) {
    int k = k0 + ty8 + i * 8;
    int n = n0 + tx;
    float v = (k < K && n < N) ? W[(long)k * N + n] : 0.f;
    tile[ty8 + i * 8][tx] = f2bf(v);
  }
  __syncthreads();
#pragma unroll
  for (int i = 0; i < 4; i++) {
    int n = n0 + ty8 + i * 8;
    int k = k0 + tx;
    if (n < N && k < K) Wt[(long)n * K + k] = tile[tx][ty8 + i * 8];
  }
}

// ---------------------------------------------------------------------------
// MFMA bf16 GEMM: C[M,N] = A[M,K](fp32, cvt on stage) @ Wt[N,K](bf16) + bias
// Tile 128x128, BK=32, 4 waves (2x2), wave 64x64 = 4x4 frags of 16x16x32.
// ---------------------------------------------------------------------------
template <bool RELU>
__global__ __launch_bounds__(256) void mfma_gemm_kernel(
    const float* __restrict__ A, const short* __restrict__ Wt,
    const float* __restrict__ bias, float* __restrict__ C,
    int M, int N, int K) {
  __shared__ short As[128][40];
  __shared__ short Bs[128][40];
  int tid = threadIdx.x;
  int row0 = blockIdx.y * 128, col0 = blockIdx.x * 128;
  int wid = tid >> 6, lane = tid & 63;
  int wr = (wid >> 1) * 64, wc = (wid & 1) * 64;
  int lcol = lane & 15, kg = lane >> 4;

  floatx4 acc[4][4];
#pragma unroll
  for (int m = 0; m < 4; ++m)
#pragma unroll
    for (int n = 0; n < 4; ++n) acc[m][n] = (floatx4){0.f, 0.f, 0.f, 0.f};

  for (int k0 = 0; k0 < K; k0 += 32) {
#pragma unroll
    for (int p = 0; p < 4; ++p) {
      int chunk = p * 256 + tid;
      int m = chunk >> 3, kc4 = (chunk & 7) * 4;
      floatx4 v = *reinterpret_cast<const floatx4*>(
          &A[(long)(row0 + m) * K + k0 + kc4]);
      short4v s;
      s[0] = f2bf(v[0]);
      s[1] = f2bf(v[1]);
      s[2] = f2bf(v[2]);
      s[3] = f2bf(v[3]);
      *reinterpret_cast<short4v*>(&As[m][kc4]) = s;
    }
#pragma unroll
    for (int p = 0; p < 2; ++p) {
      int chunk = p * 256 + tid;
      int n = chunk >> 2, kc8 = (chunk & 3) * 8;
      short8 v;
      if (col0 + n < N) {
        v = *reinterpret_cast<const short8*>(&Wt[(long)(col0 + n) * K + k0 + kc8]);
      } else {
        v = (short8){0, 0, 0, 0, 0, 0, 0, 0};
      }
      *reinterpret_cast<short8*>(&Bs[n][kc8]) = v;
    }
    __syncthreads();
    short8 af[4], bfr[4];
#pragma unroll
    for (int m = 0; m < 4; ++m)
      af[m] = *reinterpret_cast<const short8*>(&As[wr + m * 16 + lcol][kg * 8]);
#pragma unroll
    for (int n = 0; n < 4; ++n)
      bfr[n] = *reinterpret_cast<const short8*>(&Bs[wc + n * 16 + lcol][kg * 8]);
#pragma unroll
    for (int m = 0; m < 4; ++m)
#pragma unroll
      for (int n = 0; n < 4; ++n)
        acc[m][n] = __builtin_amdgcn_mfma_f32_16x16x32_bf16(af[m], bfr[n],
                                                            acc[m][n], 0, 0, 0);
    __syncthreads();
  }
#pragma unroll
  for (int n = 0; n < 4; ++n) {
    int c = col0 + wc + n * 16 + lcol;
    if (c >= N) continue;
    float bv = bias[c];
#pragma unroll
    for (int m = 0; m < 4; ++m) {
      int rbase = row0 + wr + m * 16 + kg * 4;
#pragma unroll
      for (int q = 0; q < 4; ++q) {
        float val = acc[m][n][q] + bv;
        if (RELU) val = fmaxf(val, 0.f);
        C[(long)(rbase + q) * N + c] = val;
      }
    }
  }
}

// ---------------------------------------------------------------------------
// Generic tiled fp32 GEMM (batched-col-major A: q/kv projections).
// OUTBF: emit bf16 (rounded) into (short*)C instead of fp32.
// ---------------------------------------------------------------------------
template <int ALAYOUT, bool RELU, bool OUTBF>
__global__ __launch_bounds__(256) void gemm_kernel(
    const float* __restrict__ A, const float* __restrict__ W,
    const float* __restrict__ bias, float* __restrict__ C,
    int M, int N, int K, long batchStrideA) {
  __shared__ float As[16][68];
  __shared__ float Bs[16][68];
  int tid = threadIdx.x;
  int tx = tid & 15, ty = tid >> 4;
  int row0 = blockIdx.y * 64;
  int col0 = blockIdx.x * 64;
  float acc[4][4] = {};
  const float* Abase;
  if (ALAYOUT == 1) {
    int b = row0 >> 10;
    Abase = A + (long)b * batchStrideA + (row0 & 1023);
  } else {
    Abase = A + (long)row0 * K;
  }
  for (int k0 = 0; k0 < K; k0 += 16) {
#pragma unroll
    for (int i = 0; i < 4; i++) {
      int idx = i * 256 + tid;
      if (ALAYOUT == 1) {
        int tt = idx & 63, cc = idx >> 6;
        As[cc][tt] = Abase[(long)(k0 + cc) * 1024 + tt];
      } else {
        int cc = idx & 15, tt = idx >> 4;
        As[cc][tt] = Abase[(long)tt * K + k0 + cc];
      }
    }
#pragma unroll
    for (int i = 0; i < 4; i++) {
      int idx = i * 256 + tid;
      int cc = idx >> 6, jj = idx & 63;
      int col = col0 + jj;
      Bs[cc][jj] = (col < N) ? W[(long)(k0 + cc) * N + col] : 0.0f;
    }
    __syncthreads();
#pragma unroll
    for (int cc = 0; cc < 16; cc++) {
      float4 av = *reinterpret_cast<const float4*>(&As[cc][ty * 4]);
      float4 bv = *reinterpret_cast<const float4*>(&Bs[cc][tx * 4]);
      float a_[4] = {av.x, av.y, av.z, av.w};
      float b_[4] = {bv.x, bv.y, bv.z, bv.w};
#pragma unroll
      for (int u = 0; u < 4; u++)
#pragma unroll
        for (int v = 0; v < 4; v++) acc[u][v] = fmaf(a_[u], b_[v], acc[u][v]);
    }
    __syncthreads();
  }
#pragma unroll
  for (int u = 0; u < 4; u++) {
    long r = row0 + ty * 4 + u;
#pragma unroll
    for (int v = 0; v < 4; v++) {
      int c = col0 + tx * 4 + v;
      if (c < N) {
        float val = acc[u][v] + bias[c];
        if (RELU) val = fmaxf(val, 0.0f);
        if (OUTBF) {
          ((short*)C)[r * N + c] = f2bf(val);
        } else {
          C[r * N + c] = val;
        }
      }
    }
  }
}

// ---------------------------------------------------------------------------
// MFMA windowed attention. One block per (b,k,r) (grid 2048, XCD-swizzled).
// S[32q x 256key] = Q @ K'^T   (K'-frags b128 direct from global ktp)
// cross-wave softmax (stats in LDS), P transposed into LDS (bf16),
// O[32q x 256ch] = P @ V       (V-frags gathered from global ktb16, raw kt)
// Wave w owns key-quarter in S, ch-quarter in PV. No barriers in hot loops.
// ---------------------------------------------------------------------------
__global__ __launch_bounds__(256) void attn_kernel(
    const float* __restrict__ x, const short* __restrict__ ktp,
    const short* __restrict__ ktb, const float* __restrict__ pos,
    float* __restrict__ o) {
  __shared__ short Q_s[32][264];
  __shared__ short P_s[32][264];
  __shared__ float st_mx[32][4];
  __shared__ float st_sm[32][4];
  // bijective XCD swizzle: 2048 blocks, 8 XCDs
  int h = blockIdx.x;
  int xcd = h & 7, jj = h >> 3;
  int sidx = xcd * 8 + (jj >> 5);
  int r = jj & 31;
  int b = sidx & 15, k = sidx >> 4;
  int tid = threadIdx.x;
  int w = tid >> 6, lane = tid & 63, lcol = lane & 15, kg = lane >> 4;
  const float scale = 0.0625f;  // 1/sqrt(256)

  // ---- stage Q = bf16((x + pos) * scale) ----
  const float* xb = x + ((long)b * NTOK + r * 32) * HID;
  const float* pq = pos + (long)r * 32 * HID;
#pragma unroll
  for (int p = 0; p < 8; ++p) {
    int f = p * 256 + tid;
    int row = f >> 6, c4 = (f & 63) << 2;
    float4 xv = *reinterpret_cast<const float4*>(&xb[row * HID + c4]);
    float4 pv = *reinterpret_cast<const float4*>(&pq[row * HID + c4]);
    short4v s;
    s[0] = f2bf((xv.x + pv.x) * scale);
    s[1] = f2bf((xv.y + pv.y) * scale);
    s[2] = f2bf((xv.z + pv.z) * scale);
    s[3] = f2bf((xv.w + pv.w) * scale);
    *reinterpret_cast<short4v*>(&Q_s[row][c4]) = s;
  }
  __syncthreads();

  int r0 = max(r - 3, 0), r1 = min(r + 3, 31);
  int nkr = r1 - r0 + 1, nm = nkr * 32;
  const short* ktpb = ktp + ((long)(k * BATCH + b)) * NTOK * HID;
  const short* ktbb = ktb + ((long)(k * BATCH + b)) * NTOK * HID;

  // ---- S phase: acc[m][n] = S frags (cols w*64 + n*16 + lcol) ----
  floatx4 acc[2][4];
#pragma unroll
  for (int m = 0; m < 2; ++m)
#pragma unroll
    for (int n = 0; n < 4; ++n) acc[m][n] = (floatx4){0.f, 0.f, 0.f, 0.f};

  int tokn[4];
#pragma unroll
  for (int n = 0; n < 4; ++n) {
    int nf = w * 4 + n;
    int krow = min(r0 + (nf >> 1), 31);  // clamp keeps addresses in-bounds
    tokn[n] = krow * 32 + ((nf & 1) << 4) + lcol;
  }
#pragma unroll
  for (int s = 0; s < 8; ++s) {
    short8 af0 = *reinterpret_cast<const short8*>(&Q_s[lcol][s * 32 + kg * 8]);
    short8 af1 =
        *reinterpret_cast<const short8*>(&Q_s[16 + lcol][s * 32 + kg * 8]);
#pragma unroll
    for (int n = 0; n < 4; ++n) {
      short8 bfr = *reinterpret_cast<const short8*>(
          &ktpb[(long)tokn[n] * HID + s * 32 + kg * 8]);
      acc[0][n] =
          __builtin_amdgcn_mfma_f32_16x16x32_bf16(af0, bfr, acc[0][n], 0, 0, 0);
      acc[1][n] =
          __builtin_amdgcn_mfma_f32_16x16x32_bf16(af1, bfr, acc[1][n], 0, 0, 0);
    }
  }

  // ---- softmax over rows (queries), cols distributed across waves ----
  const float NEG = -3.0e38f;
  float mx[2][4];
#pragma unroll
  for (int m = 0; m < 2; ++m)
#pragma unroll
    for (int q = 0; q < 4; ++q) {
      int rr = m * 16 + kg * 4 + q;
      float vmax = NEG;
#pragma unroll
      for (int n = 0; n < 4; ++n) {
        int col = (w * 4 + n) * 16 + lcol;
        int ck = col & 31;
        bool ok = (col < nm) && (ck - rr <= 3) && (rr - ck <= 3);
        float v = ok ? acc[m][n][q] : NEG;
        acc[m][n][q] = v;
        vmax = fmaxf(vmax, v);
      }
      vmax = fmaxf(vmax, __shfl_xor(vmax, 1));
      vmax = fmaxf(vmax, __shfl_xor(vmax, 2));
      vmax = fmaxf(vmax, __shfl_xor(vmax, 4));
      vmax = fmaxf(vmax, __shfl_xor(vmax, 8));
      mx[m][q] = vmax;
    }
  if (lcol == 0) {
#pragma unroll
    for (int m = 0; m < 2; ++m)
#pragma unroll
      for (int q = 0; q < 4; ++q) st_mx[m * 16 + kg * 4 + q][w] = mx[m][q];
  }
  __syncthreads();
  float sm[2][4];
#pragma unroll
  for (int m = 0; m < 2; ++m)
#pragma unroll
    for (int q = 0; q < 4; ++q) {
      int rr = m * 16 + kg * 4 + q;
      float4 v4 = *reinterpret_cast<const float4*>(&st_mx[rr][0]);
      float g = fmaxf(fmaxf(v4.x, v4.y), fmaxf(v4.z, v4.w));
      float ss = 0.f;
#pragma unroll
      for (int n = 0; n < 4; ++n) {
        float v = acc[m][n][q];
        float pv = (v > -1.0e30f) ? exp2f((v - g) * 1.4426950408889634f) : 0.f;
        acc[m][n][q] = pv;
        ss += pv;
      }
      ss += __shfl_xor(ss, 1);
      ss += __shfl_xor(ss, 2);
      ss += __shfl_xor(ss, 4);
      ss += __shfl_xor(ss, 8);
      sm[m][q] = ss;
    }
  if (lcol == 0) {
#pragma unroll
    for (int m = 0; m < 2; ++m)
#pragma unroll
      for (int q = 0; q < 4; ++q) st_sm[m * 16 + kg * 4 + q][w] = sm[m][q];
  }
  __syncthreads();
#pragma unroll
  for (int m = 0; m < 2; ++m)
#pragma unroll
    for (int q = 0; q < 4; ++q) {
      int rr = m * 16 + kg * 4 + q;
      float4 v4 = *reinterpret_cast<const float4*>(&st_sm[rr][0]);
      float rinv = 1.0f / (v4.x + v4.y + v4.z + v4.w);
#pragma unroll
      for (int n = 0; n < 4; ++n) {
        P_s[rr][(w * 4 + n) * 16 + lcol] = f2bf(acc[m][n][q] * rinv);
      }
    }
  __syncthreads();

  // ---- PV: O[32q][256ch], wave w owns chs w*64..w*64+63 ----
  floatx4 oacc[2][4];
#pragma unroll
  for (int m = 0; m < 2; ++m)
#pragma unroll
    for (int n = 0; n < 4; ++n) oacc[m][n] = (floatx4){0.f, 0.f, 0.f, 0.f};

  for (int kb = 0; kb < nkr; ++kb) {
    short8 ap0 = *reinterpret_cast<const short8*>(&P_s[lcol][kb * 32 + kg * 8]);
    short8 ap1 =
        *reinterpret_cast<const short8*>(&P_s[16 + lcol][kb * 32 + kg * 8]);
    int tokb = (r0 + kb) * 32;
#pragma unroll
    for (int n = 0; n < 4; ++n) {
      int ch = w * 64 + n * 16 + lcol;
      const short* vp = &ktbb[(long)(tokb + kg * 8) * HID + ch];
      short8 bv;
#pragma unroll
      for (int j = 0; j < 8; ++j) bv[j] = vp[(long)j * HID];
      oacc[0][n] =
          __builtin_amdgcn_mfma_f32_16x16x32_bf16(ap0, bv, oacc[0][n], 0, 0, 0);
      oacc[1][n] =
          __builtin_amdgcn_mfma_f32_16x16x32_bf16(ap1, bv, oacc[1][n], 0, 0, 0);
    }
  }
  // ---- write O: o[b, r*32+rr, k*256+ch] ----
#pragma unroll
  for (int m = 0; m < 2; ++m)
#pragma unroll
    for (int n = 0; n < 4; ++n) {
      int ch = w * 64 + n * 16 + lcol;
#pragma unroll
      for (int q = 0; q < 4; ++q) {
        int rr = m * 16 + kg * 4 + q;
        o[((long)b * NTOK + r * 32 + rr) * (KMEM * HID) + k * HID + ch] =
            oacc[m][n][q];
      }
    }
}

// ---------------------------------------------------------------------------
// x = LayerNorm(x + res) * g + b
// ---------------------------------------------------------------------------
__global__ __launch_bounds__(256) void add_ln_kernel(
    const float* __restrict__ x, const float* __restrict__ res,
    const float* __restrict__ g, const float* __restrict__ bta,
    float* __restrict__ out) {
  long row = blockIdx.x;
  int j = threadIdx.x;
  float v = x[row * HID + j] + res[row * HID + j];
  float s = v, s2 = v * v;
#pragma unroll
  for (int off = 32; off > 0; off >>= 1) {
    s += __shfl_xor(s, off);
    s2 += __shfl_xor(s2, off);
  }
  __shared__ float ss[4], ss2[4];
  int wave = j >> 6, lane = j & 63;
  if (lane == 0) {
    ss[wave] = s;
    ss2[wave] = s2;
  }
  __syncthreads();
  s = ss[0] + ss[1] + ss[2] + ss[3];
  s2 = ss2[0] + ss2[1] + ss2[2] + ss2[3];
  float mean = s * (1.f / 256.f);
  float var = s2 * (1.f / 256.f) - mean * mean;
  float inv = rsqrtf(var + LN_EPS);
  out[row * HID + j] = (v - mean) * inv * g[j] + bta[j];
}

// ---------------------------------------------------------------------------
// recon_tokens (b,t,272) -> recon (b,272,32,32) + pred_sq
// ---------------------------------------------------------------------------
__global__ __launch_bounds__(256) void recon_out_kernel(
    const float* __restrict__ rt, const float* __restrict__ qf,
    float* __restrict__ recon, float* __restrict__ pred_sq) {
  int b = blockIdx.y;
  int t0 = blockIdx.x * 32;
  __shared__ float tile[32][33];
  int lx = threadIdx.x & 31;
  int ly = threadIdx.x >> 5;
  float sq = 0.f;
  for (int c0 = 0; c0 < DIN; c0 += 32) {
    __syncthreads();
#pragma unroll
    for (int i = 0; i < 4; i++) {
      int tt = ly + i * 8;
      int c = c0 + lx;
      tile[tt][lx] = (c < DIN) ? rt[((long)b * NTOK + t0 + tt) * DIN + c] : 0.f;
    }
    __syncthreads();
#pragma unroll
    for (int i = 0; i < 4; i++) {
      int c = c0 + ly + i * 8;
      if (c < DIN) {
        float v = tile[lx][ly + i * 8];
        long gaddr = ((long)b * DIN + c) * NTOK + t0 + lx;
        float q = qf[gaddr];
        recon[gaddr] = v;
        float d = v - q;
        sq = fmaf(d, d, sq);
      }
    }
  }
  __shared__ float red[8][33];
  red[ly][lx] = sq;
  __syncthreads();
  if (ly == 0) {
    float s = 0.f;
#pragma unroll
    for (int u = 0; u < 8; u++) s += red[u][lx];
    pred_sq[b * NTOK + t0 + lx] = s;
  }
}

__global__ __launch_bounds__(256) void minmax_kernel(
    const float* __restrict__ pred_sq, float* __restrict__ mnmx) {
  int tid = threadIdx.x;
  float mn = INFINITY, mx = -INFINITY;
  for (int i = tid; i < BATCH * NTOK; i += 256) {
    float v = sqrtf(pred_sq[i]);
    mn = fminf(mn, v);
    mx = fmaxf(mx, v);
  }
#pragma unroll
  for (int off = 32; off > 0; off >>= 1) {
    mn = fminf(mn, __shfl_xor(mn, off));
    mx = fmaxf(mx, __shfl_xor(mx, off));
  }
  __shared__ float smn[4], smx[4];
  int wave = tid >> 6, lane = tid & 63;
  if (lane == 0) {
    smn[wave] = mn;
    smx[wave] = mx;
  }
  __syncthreads();
  if (tid == 0) {
    mn = fminf(fminf(smn[0], smn[1]), fminf(smn[2], smn[3]));
    mx = fmaxf(fmaxf(smx[0], smx[1]), fmaxf(smx[2], smx[3]));
    mnmx[0] = mn;
    mnmx[1] = mx;
  }
}

__global__ __launch_bounds__(256) void resize_kernel(
    const float* __restrict__ pred_sq, const float* __restrict__ mnmx,
    float* __restrict__ out) {
  long idx = (long)blockIdx.x * 256 + threadIdx.x;
  if (idx >= (long)BATCH * 256 * 256) return;
  int b = (int)(idx >> 16);
  int oy = (int)((idx >> 8) & 255), ox = (int)(idx & 255);
  float mn = mnmx[0], mx = mnmx[1];
  float inv = 1.0f / (mx - mn);
  float ys = oy * (31.0f / 255.0f);
  int y0 = (int)floorf(ys);
  int y1 = min(y0 + 1, 31);
  float fy = ys - (float)y0;
  float xs = ox * (31.0f / 255.0f);
  int x0 = (int)floorf(xs);
  int x1 = min(x0 + 1, 31);
  float fx = xs - (float)x0;
  const float* p = pred_sq + b * NTOK;
  float v00 = sqrtf(p[y0 * 32 + x0]), v01 = sqrtf(p[y0 * 32 + x1]);
  float v10 = sqrtf(p[y1 * 32 + x0]), v11 = sqrtf(p[y1 * 32 + x1]);
  float cA = v00 * (1.f - fy) + v10 * fy;
  float cB = v01 * (1.f - fy) + v11 * fy;
  float v = cA * (1.f - fx) + cB * fx;
  out[idx] = (v - mn) * inv;
}

// ---------------------------------------------------------------------------
extern "C" void kernel_launch(void* const* d_in, const int* in_sizes, int n_in,
                              void* d_out, int out_size, void* d_ws,
                              size_t ws_size, hipStream_t stream) {
  const float* qf = (const float*)d_in[0];
  const float* mf = (const float*)d_in[1];
  const float* qW = (const float*)d_in[2];
  const float* qb = (const float*)d_in[3];
  const float* kvW = (const float*)d_in[4];
  const float* kvb = (const float*)d_in[5];
  const float* row_e = (const float*)d_in[6];
  const float* col_e = (const float*)d_in[7];
  const float* aggW = (const float*)d_in[8];
  const float* aggb = (const float*)d_in[9];
  const float* n1g = (const float*)d_in[10];
  const float* n1b = (const float*)d_in[11];
  const float* l1W = (const float*)d_in[12];
  const float* l1b = (const float*)d_in[13];
  const float* l2W = (const float*)d_in[14];
  const float* l2b = (const float*)d_in[15];
  const float* n2g = (const float*)d_in[16];
  const float* n2b = (const float*)d_in[17];
  const float* outW = (const float*)d_in[18];
  const float* outb = (const float*)d_in[19];

  float* out = (float*)d_out;
  float* recon = out;                            // 16*272*1024
  float* pred = out + (long)BATCH * DIN * NTOK;  // 16*256*256

  // bf16 transposed weights stashed in recon region of d_out (6.9MB < 17.8MB),
  // fully consumed before recon_out_kernel overwrites it at the end.
  short* wt = (short*)d_out;
  short* wt_agg0 = wt;
  short* wt_agg1 = wt_agg0 + 262144;
  short* wt_l1_0 = wt_agg1 + 262144;
  short* wt_l1_1 = wt_l1_0 + 262144;
  short* wt_l2_0 = wt_l1_1 + 262144;
  short* wt_l2_1 = wt_l2_0 + 262144;
  short* wt_out = wt_l2_1 + 262144;

  // workspace layout
  float* ws = (float*)d_ws;
  float* pos = ws;                          // 262144 f
  float* x = pos + 262144;                  // 4194304 f
  short* ktb16 = (short*)(x + 4194304);     // 16777216 s
  short* ktp = ktb16 + 16777216;            // 16777216 s
  float* buf1024 = (float*)(ktp + 16777216);  // 16777216 f
  float* tmp256 = buf1024 + 16777216;       // 4194304 f
  float* pred_sq = tmp256 + 4194304;        // 16384 f
  float* mnmx = pred_sq + 16384;            // 2 f

  const long BS_FEAT = (long)DIN * NTOK;

  pos_kernel<<<NTOK, 256, 0, stream>>>(row_e, col_e, pos);

  wt_cvt_kernel<<<dim3(8, 32), 256, 0, stream>>>(aggW, wt_agg0, 1024, 256);
  wt_cvt_kernel<<<dim3(8, 32), 256, 0, stream>>>(aggW + 262144, wt_agg1, 1024, 256);
  wt_cvt_kernel<<<dim3(32, 8), 256, 0, stream>>>(l1W, wt_l1_0, 256, 1024);
  wt_cvt_kernel<<<dim3(32, 8), 256, 0, stream>>>(l1W + 262144, wt_l1_1, 256, 1024);
  wt_cvt_kernel<<<dim3(8, 32), 256, 0, stream>>>(l2W, wt_l2_0, 1024, 256);
  wt_cvt_kernel<<<dim3(8, 32), 256, 0, stream>>>(l2W + 262144, wt_l2_1, 1024, 256);
  wt_cvt_kernel<<<dim3(9, 8), 256, 0, stream>>>(outW, wt_out, 256, 272);

  // q projection (fp32 out -> x)
  {
    dim3 grid(256 / 64, (BATCH * NTOK) / 64);
    gemm_kernel<1, false, false><<<grid, 256, 0, stream>>>(
        qf, qW, qb, x, BATCH * NTOK, HID, DIN, BS_FEAT);
  }
  // kv projection (bf16 out -> ktb16)
  {
    dim3 grid(256 / 64, (KMEM * BATCH * NTOK) / 64);
    gemm_kernel<1, false, true><<<grid, 256, 0, stream>>>(
        mf, kvW, kvb, (float*)ktb16, KMEM * BATCH * NTOK, HID, DIN, BS_FEAT);
  }
  // ktp = bf16(kt + pos)
  ktp_kernel<<<16384, 256, 0, stream>>>(ktb16, pos, ktp);

  for (int l = 0; l < 2; l++) {
    attn_kernel<<<2048, 256, 0, stream>>>(x, ktp, ktb16, pos, buf1024);
    // agg
    {
      dim3 grid(2, 128);
      mfma_gemm_kernel<false><<<grid, 256, 0, stream>>>(
          buf1024, l ? wt_agg1 : wt_agg0, aggb + l * 256, tmp256, BATCH * NTOK,
          HID, KMEM * HID);
    }
    add_ln_kernel<<<BATCH * NTOK, 256, 0, stream>>>(x, tmp256, n1g + l * 256,
                                                    n1b + l * 256, x);
    // ff1
    {
      dim3 grid(8, 128);
      mfma_gemm_kernel<true><<<grid, 256, 0, stream>>>(
          x, l ? wt_l1_1 : wt_l1_0, l1b + l * 1024, buf1024, BATCH * NTOK, DFF,
          HID);
    }
    // ff2
    {
      dim3 grid(2, 128);
      mfma_gemm_kernel<false><<<grid, 256, 0, stream>>>(
          buf1024, l ? wt_l2_1 : wt_l2_0, l2b + l * 256, tmp256, BATCH * NTOK,
          HID, DFF);
    }
    add_ln_kernel<<<BATCH * NTOK, 256, 0, stream>>>(x, tmp256, n2g + l * 256,
                                                    n2b + l * 256, x);
  }

  // out projection -> recon_tokens (buf1024)
  {
    dim3 grid(3, 128);
    mfma_gemm_kernel<false><<<grid, 256, 0, stream>>>(x, wt_out, outb, buf1024,
                                                      BATCH * NTOK, DIN, HID);
  }
  {
    dim3 grid(NTOK / 32, BATCH);
    recon_out_kernel<<<grid, 256, 0, stream>>>(buf1024, qf, recon, pred_sq);
  }
  minmax_kernel<<<1, 256, 0, stream>>>(pred_sq, mnmx);
  resize_kernel<<<(BATCH * 256 * 256) / 256, 256, 0, stream>>>(pred_sq, mnmx,
                                                               pred);
}

// Round 5
// 805.420 us; speedup vs baseline: 3.0513x; 1.0760x over previous
//
#include <hip/hip_runtime.h>
#include <hip/hip_bf16.h>
#include <math.h>

// Problem constants
#define BATCH 16
#define NTOK 1024      // 32*32
#define HID 256
#define KMEM 4
#define DIN 272
#define DINP 288       // DIN zero-padded to /32
#define DFF 1024
#define LN_EPS 1e-5f

using short8 = __attribute__((ext_vector_type(8))) short;
using short4v = __attribute__((ext_vector_type(4))) short;
using floatx4 = __attribute__((ext_vector_type(4))) float;

__device__ inline short f2bf(float f) {
  unsigned u = __builtin_bit_cast(unsigned, f);
  u += 0x7fff + ((u >> 16) & 1);  // RNE
  return (short)(u >> 16);
}

// ---------------------------------------------------------------------------
// pos embed: pos[t][j] = j<128 ? col_embed[t%32][j] : row_embed[t/32][j-128]
// ---------------------------------------------------------------------------
__global__ __launch_bounds__(256) void pos_kernel(
    const float* __restrict__ row_e, const float* __restrict__ col_e,
    float* __restrict__ pos) {
  int t = blockIdx.x;
  int j = threadIdx.x;
  float v = (j < 128) ? col_e[(t & 31) * 128 + j]
                      : row_e[(t >> 5) * 128 + (j - 128)];
  pos[t * 256 + j] = v;
}

// ---------------------------------------------------------------------------
// Activation transpose+cvt: src fp32 [slices][272][1024] -> dst bf16
// [slices*1024][288], channels 272..287 zeroed.  One 32x32 tile per block.
// ---------------------------------------------------------------------------
__global__ __launch_bounds__(256) void tcvt_kernel(
    const float* __restrict__ src, short* __restrict__ dst) {
  __shared__ short tile[32][33];
  int slice = blockIdx.x >> 5;
  int t0 = (blockIdx.x & 31) * 32;
  int c0 = blockIdx.y * 32;
  int tx = threadIdx.x & 31, ty = threadIdx.x >> 5;
  const float* s = src + (long)slice * DIN * NTOK;
#pragma unroll
  for (int i = 0; i < 4; i++) {
    int c = c0 + ty + i * 8;
    float v = (c < DIN) ? s[(long)c * NTOK + t0 + tx] : 0.f;
    tile[ty + i * 8][tx] = f2bf(v);
  }
  __syncthreads();
  short* d = dst + ((long)slice * NTOK + t0) * DINP + c0;
#pragma unroll
  for (int i = 0; i < 4; i++) {
    int tl = ty + i * 8;
    d[(long)tl * DINP + tx] = tile[tx][tl];
  }
}

// ---------------------------------------------------------------------------
// Weight transpose + cvt: W[K][N] fp32 -> Wt[N][Kd] bf16, rows K..Kd zeroed
// ---------------------------------------------------------------------------
__global__ __launch_bounds__(256) void wt_cvt_kernel(
    const float* __restrict__ W, short* __restrict__ Wt, int K, int Kd,
    int N) {
  __shared__ short tile[32][33];
  int n0 = blockIdx.x * 32, k0 = blockIdx.y * 32;
  int tx = threadIdx.x & 31, ty8 = threadIdx.x >> 5;
#pragma unroll
  for (int i = 0; i < 4; i++) {
    int k = k0 + ty8 + i * 8;
    int n = n0 + tx;
    float v = (k < K && n < N) ? W[(long)k * N + n] : 0.f;
    tile[ty8 + i * 8][tx] = f2bf(v);
  }
  __syncthreads();
#pragma unroll
  for (int i = 0; i < 4; i++) {
    int n = n0 + ty8 + i * 8;
    int k = k0 + tx;
    if (n < N && k < Kd) Wt[(long)n * Kd + k] = tile[tx][ty8 + i * 8];
  }
}

// ---------------------------------------------------------------------------
// MFMA bf16 GEMM, fp32 A (cvt on stage): C = A[M,K] @ Wt[N,K] + bias
// Tile 128x128, BK=32, 4 waves (2x2), wave 64x64 = 4x4 frags of 16x16x32.
// ---------------------------------------------------------------------------
template <bool RELU>
__global__ __launch_bounds__(256) void mfma_gemm_kernel(
    const float* __restrict__ A, const short* __restrict__ Wt,
    const float* __restrict__ bias, float* __restrict__ C,
    int M, int N, int K) {
  __shared__ short As[128][40];
  __shared__ short Bs[128][40];
  int tid = threadIdx.x;
  int row0 = blockIdx.y * 128, col0 = blockIdx.x * 128;
  int wid = tid >> 6, lane = tid & 63;
  int wr = (wid >> 1) * 64, wc = (wid & 1) * 64;
  int lcol = lane & 15, kg = lane >> 4;

  floatx4 acc[4][4];
#pragma unroll
  for (int m = 0; m < 4; ++m)
#pragma unroll
    for (int n = 0; n < 4; ++n) acc[m][n] = (floatx4){0.f, 0.f, 0.f, 0.f};

  for (int k0 = 0; k0 < K; k0 += 32) {
#pragma unroll
    for (int p = 0; p < 4; ++p) {
      int chunk = p * 256 + tid;
      int m = chunk >> 3, kc4 = (chunk & 7) * 4;
      floatx4 v = *reinterpret_cast<const floatx4*>(
          &A[(long)(row0 + m) * K + k0 + kc4]);
      short4v s;
      s[0] = f2bf(v[0]);
      s[1] = f2bf(v[1]);
      s[2] = f2bf(v[2]);
      s[3] = f2bf(v[3]);
      *reinterpret_cast<short4v*>(&As[m][kc4]) = s;
    }
#pragma unroll
    for (int p = 0; p < 2; ++p) {
      int chunk = p * 256 + tid;
      int n = chunk >> 2, kc8 = (chunk & 3) * 8;
      short8 v;
      if (col0 + n < N) {
        v = *reinterpret_cast<const short8*>(&Wt[(long)(col0 + n) * K + k0 + kc8]);
      } else {
        v = (short8){0, 0, 0, 0, 0, 0, 0, 0};
      }
      *reinterpret_cast<short8*>(&Bs[n][kc8]) = v;
    }
    __syncthreads();
    short8 af[4], bfr[4];
#pragma unroll
    for (int m = 0; m < 4; ++m)
      af[m] = *reinterpret_cast<const short8*>(&As[wr + m * 16 + lcol][kg * 8]);
#pragma unroll
    for (int n = 0; n < 4; ++n)
      bfr[n] = *reinterpret_cast<const short8*>(&Bs[wc + n * 16 + lcol][kg * 8]);
#pragma unroll
    for (int m = 0; m < 4; ++m)
#pragma unroll
      for (int n = 0; n < 4; ++n)
        acc[m][n] = __builtin_amdgcn_mfma_f32_16x16x32_bf16(af[m], bfr[n],
                                                            acc[m][n], 0, 0, 0);
    __syncthreads();
  }
#pragma unroll
  for (int n = 0; n < 4; ++n) {
    int c = col0 + wc + n * 16 + lcol;
    if (c >= N) continue;
    float bv = bias[c];
#pragma unroll
    for (int m = 0; m < 4; ++m) {
      int rbase = row0 + wr + m * 16 + kg * 4;
#pragma unroll
      for (int q = 0; q < 4; ++q) {
        float val = acc[m][n][q] + bv;
        if (RELU) val = fmaxf(val, 0.f);
        C[(long)(rbase + q) * N + c] = val;
      }
    }
  }
}

// ---------------------------------------------------------------------------
// MFMA bf16 GEMM, bf16 A (direct stage). OUTMODE 0: fp32 C.
// OUTMODE 2 (kv projection, N==256): no C; writes
//   ktp[r*256+c] = bf16(val + pos[(r&1023)*256+c])   (scores operand)
//   ktv[(r>>10)*262144 + c*1024 + (r&1023)] = bf16(val)  (V^T operand)
// ---------------------------------------------------------------------------
template <int OUTMODE>
__global__ __launch_bounds__(256) void mfma_gemm_bf16a_kernel(
    const short* __restrict__ A, const short* __restrict__ Wt,
    const float* __restrict__ bias, float* __restrict__ C, int M, int N,
    int K, short* __restrict__ ktp, short* __restrict__ ktv,
    const float* __restrict__ pos) {
  __shared__ short As[128][40];
  __shared__ short Bs[128][40];
  int tid = threadIdx.x;
  int row0 = blockIdx.y * 128, col0 = blockIdx.x * 128;
  int wid = tid >> 6, lane = tid & 63;
  int wr = (wid >> 1) * 64, wc = (wid & 1) * 64;
  int lcol = lane & 15, kg = lane >> 4;

  floatx4 acc[4][4];
#pragma unroll
  for (int m = 0; m < 4; ++m)
#pragma unroll
    for (int n = 0; n < 4; ++n) acc[m][n] = (floatx4){0.f, 0.f, 0.f, 0.f};

  for (int k0 = 0; k0 < K; k0 += 32) {
#pragma unroll
    for (int p = 0; p < 2; ++p) {
      int chunk = p * 256 + tid;
      int m = chunk >> 2, kc8 = (chunk & 3) * 8;
      short8 v = *reinterpret_cast<const short8*>(&A[(long)(row0 + m) * K + k0 + kc8]);
      *reinterpret_cast<short8*>(&As[m][kc8]) = v;
    }
#pragma unroll
    for (int p = 0; p < 2; ++p) {
      int chunk = p * 256 + tid;
      int n = chunk >> 2, kc8 = (chunk & 3) * 8;
      short8 v = *reinterpret_cast<const short8*>(&Wt[(long)(col0 + n) * K + k0 + kc8]);
      *reinterpret_cast<short8*>(&Bs[n][kc8]) = v;
    }
    __syncthreads();
    short8 af[4], bfr[4];
#pragma unroll
    for (int m = 0; m < 4; ++m)
      af[m] = *reinterpret_cast<const short8*>(&As[wr + m * 16 + lcol][kg * 8]);
#pragma unroll
    for (int n = 0; n < 4; ++n)
      bfr[n] = *reinterpret_cast<const short8*>(&Bs[wc + n * 16 + lcol][kg * 8]);
#pragma unroll
    for (int m = 0; m < 4; ++m)
#pragma unroll
      for (int n = 0; n < 4; ++n)
        acc[m][n] = __builtin_amdgcn_mfma_f32_16x16x32_bf16(af[m], bfr[n],
                                                            acc[m][n], 0, 0, 0);
    __syncthreads();
  }
#pragma unroll
  for (int n = 0; n < 4; ++n) {
    int c = col0 + wc + n * 16 + lcol;
    float bv = bias[c];
#pragma unroll
    for (int m = 0; m < 4; ++m) {
      int rbase = row0 + wr + m * 16 + kg * 4;
      if (OUTMODE == 0) {
#pragma unroll
        for (int q = 0; q < 4; ++q) {
          C[(long)(rbase + q) * N + c] = acc[m][n][q] + bv;
        }
      } else {
        int slice = rbase >> 10, tbase = rbase & 1023;
        short4v vt;
#pragma unroll
        for (int q = 0; q < 4; ++q) {
          float val = acc[m][n][q] + bv;
          vt[q] = f2bf(val);
          ktp[(long)(rbase + q) * 256 + c] =
              f2bf(val + pos[(tbase + q) * 256 + c]);
        }
        *reinterpret_cast<short4v*>(
            &ktv[(long)slice * (256 * 1024) + (long)c * 1024 + tbase]) = vt;
      }
    }
  }
}

// ---------------------------------------------------------------------------
// MFMA windowed attention. One block per (b,k,r) (grid 2048, XCD-swizzled).
// S[32q x 256key] = Q @ K'^T   (K'-frags b128 direct from global ktp)
// cross-wave softmax (stats in LDS), P transposed into LDS (bf16),
// O[32q x 256ch] = P @ V       (V-frags b128 from global ktv = V^T)
// ---------------------------------------------------------------------------
__global__ __launch_bounds__(256) void attn_kernel(
    const float* __restrict__ x, const short* __restrict__ ktp,
    const short* __restrict__ ktv, const float* __restrict__ pos,
    float* __restrict__ o) {
  __shared__ short Q_s[32][264];
  __shared__ short P_s[32][264];
  __shared__ float st_mx[32][4];
  __shared__ float st_sm[32][4];
  // bijective XCD swizzle: 2048 blocks, 8 XCDs
  int h = blockIdx.x;
  int xcd = h & 7, jj = h >> 3;
  int sidx = xcd * 8 + (jj >> 5);
  int r = jj & 31;
  int b = sidx & 15, k = sidx >> 4;
  int tid = threadIdx.x;
  int w = tid >> 6, lane = tid & 63, lcol = lane & 15, kg = lane >> 4;
  const float scale = 0.0625f;  // 1/sqrt(256)

  // ---- stage Q = bf16((x + pos) * scale) ----
  const float* xb = x + ((long)b * NTOK + r * 32) * HID;
  const float* pq = pos + (long)r * 32 * HID;
#pragma unroll
  for (int p = 0; p < 8; ++p) {
    int f = p * 256 + tid;
    int row = f >> 6, c4 = (f & 63) << 2;
    float4 xv = *reinterpret_cast<const float4*>(&xb[row * HID + c4]);
    float4 pv = *reinterpret_cast<const float4*>(&pq[row * HID + c4]);
    short4v s;
    s[0] = f2bf((xv.x + pv.x) * scale);
    s[1] = f2bf((xv.y + pv.y) * scale);
    s[2] = f2bf((xv.z + pv.z) * scale);
    s[3] = f2bf((xv.w + pv.w) * scale);
    *reinterpret_cast<short4v*>(&Q_s[row][c4]) = s;
  }
  __syncthreads();

  int r0 = max(r - 3, 0), r1 = min(r + 3, 31);
  int nkr = r1 - r0 + 1, nm = nkr * 32;
  const short* ktpb = ktp + ((long)(k * BATCH + b)) * NTOK * HID;
  const short* ktvb = ktv + ((long)(k * BATCH + b)) * NTOK * HID;

  // ---- S phase ----
  floatx4 acc[2][4];
#pragma unroll
  for (int m = 0; m < 2; ++m)
#pragma unroll
    for (int n = 0; n < 4; ++n) acc[m][n] = (floatx4){0.f, 0.f, 0.f, 0.f};

  int tokn[4];
#pragma unroll
  for (int n = 0; n < 4; ++n) {
    int nf = w * 4 + n;
    int krow = min(r0 + (nf >> 1), 31);  // clamp keeps addresses in-bounds
    tokn[n] = krow * 32 + ((nf & 1) << 4) + lcol;
  }
#pragma unroll
  for (int s = 0; s < 8; ++s) {
    short8 af0 = *reinterpret_cast<const short8*>(&Q_s[lcol][s * 32 + kg * 8]);
    short8 af1 =
        *reinterpret_cast<const short8*>(&Q_s[16 + lcol][s * 32 + kg * 8]);
#pragma unroll
    for (int n = 0; n < 4; ++n) {
      short8 bfr = *reinterpret_cast<const short8*>(
          &ktpb[(long)tokn[n] * HID + s * 32 + kg * 8]);
      acc[0][n] =
          __builtin_amdgcn_mfma_f32_16x16x32_bf16(af0, bfr, acc[0][n], 0, 0, 0);
      acc[1][n] =
          __builtin_amdgcn_mfma_f32_16x16x32_bf16(af1, bfr, acc[1][n], 0, 0, 0);
    }
  }

  // ---- softmax ----
  const float NEG = -3.0e38f;
  float mx[2][4];
#pragma unroll
  for (int m = 0; m < 2; ++m)
#pragma unroll
    for (int q = 0; q < 4; ++q) {
      int rr = m * 16 + kg * 4 + q;
      float vmax = NEG;
#pragma unroll
      for (int n = 0; n < 4; ++n) {
        int col = (w * 4 + n) * 16 + lcol;
        int ck = col & 31;
        bool ok = (col < nm) && (ck - rr <= 3) && (rr - ck <= 3);
        float v = ok ? acc[m][n][q] : NEG;
        acc[m][n][q] = v;
        vmax = fmaxf(vmax, v);
      }
      vmax = fmaxf(vmax, __shfl_xor(vmax, 1));
      vmax = fmaxf(vmax, __shfl_xor(vmax, 2));
      vmax = fmaxf(vmax, __shfl_xor(vmax, 4));
      vmax = fmaxf(vmax, __shfl_xor(vmax, 8));
      mx[m][q] = vmax;
    }
  if (lcol == 0) {
#pragma unroll
    for (int m = 0; m < 2; ++m)
#pragma unroll
      for (int q = 0; q < 4; ++q) st_mx[m * 16 + kg * 4 + q][w] = mx[m][q];
  }
  __syncthreads();
  float sm[2][4];
#pragma unroll
  for (int m = 0; m < 2; ++m)
#pragma unroll
    for (int q = 0; q < 4; ++q) {
      int rr = m * 16 + kg * 4 + q;
      float4 v4 = *reinterpret_cast<const float4*>(&st_mx[rr][0]);
      float g = fmaxf(fmaxf(v4.x, v4.y), fmaxf(v4.z, v4.w));
      float ss = 0.f;
#pragma unroll
      for (int n = 0; n < 4; ++n) {
        float v = acc[m][n][q];
        float pv = (v > -1.0e30f) ? exp2f((v - g) * 1.4426950408889634f) : 0.f;
        acc[m][n][q] = pv;
        ss += pv;
      }
      ss += __shfl_xor(ss, 1);
      ss += __shfl_xor(ss, 2);
      ss += __shfl_xor(ss, 4);
      ss += __shfl_xor(ss, 8);
      sm[m][q] = ss;
    }
  if (lcol == 0) {
#pragma unroll
    for (int m = 0; m < 2; ++m)
#pragma unroll
      for (int q = 0; q < 4; ++q) st_sm[m * 16 + kg * 4 + q][w] = sm[m][q];
  }
  __syncthreads();
#pragma unroll
  for (int m = 0; m < 2; ++m)
#pragma unroll
    for (int q = 0; q < 4; ++q) {
      int rr = m * 16 + kg * 4 + q;
      float4 v4 = *reinterpret_cast<const float4*>(&st_sm[rr][0]);
      float rinv = 1.0f / (v4.x + v4.y + v4.z + v4.w);
#pragma unroll
      for (int n = 0; n < 4; ++n) {
        P_s[rr][(w * 4 + n) * 16 + lcol] = f2bf(acc[m][n][q] * rinv);
      }
    }
  __syncthreads();

  // ---- PV: O[32q][256ch], wave w owns chs w*64..w*64+63 ----
  floatx4 oacc[2][4];
#pragma unroll
  for (int m = 0; m < 2; ++m)
#pragma unroll
    for (int n = 0; n < 4; ++n) oacc[m][n] = (floatx4){0.f, 0.f, 0.f, 0.f};

  for (int kb = 0; kb < nkr; ++kb) {
    short8 ap0 = *reinterpret_cast<const short8*>(&P_s[lcol][kb * 32 + kg * 8]);
    short8 ap1 =
        *reinterpret_cast<const short8*>(&P_s[16 + lcol][kb * 32 + kg * 8]);
    int tokb = (r0 + kb) * 32;
#pragma unroll
    for (int n = 0; n < 4; ++n) {
      int ch = w * 64 + n * 16 + lcol;
      short8 bv = *reinterpret_cast<const short8*>(
          &ktvb[(long)ch * NTOK + tokb + kg * 8]);
      oacc[0][n] =
          __builtin_amdgcn_mfma_f32_16x16x32_bf16(ap0, bv, oacc[0][n], 0, 0, 0);
      oacc[1][n] =
          __builtin_amdgcn_mfma_f32_16x16x32_bf16(ap1, bv, oacc[1][n], 0, 0, 0);
    }
  }
  // ---- write O ----
#pragma unroll
  for (int m = 0; m < 2; ++m)
#pragma unroll
    for (int n = 0; n < 4; ++n) {
      int ch = w * 64 + n * 16 + lcol;
#pragma unroll
      for (int q = 0; q < 4; ++q) {
        int rr = m * 16 + kg * 4 + q;
        o[((long)b * NTOK + r * 32 + rr) * (KMEM * HID) + k * HID + ch] =
            oacc[m][n][q];
      }
    }
}

// ---------------------------------------------------------------------------
// x = LayerNorm(x + res) * g + b
// ---------------------------------------------------------------------------
__global__ __launch_bounds__(256) void add_ln_kernel(
    const float* __restrict__ x, const float* __restrict__ res,
    const float* __restrict__ g, const float* __restrict__ bta,
    float* __restrict__ out) {
  long row = blockIdx.x;
  int j = threadIdx.x;
  float v = x[row * HID + j] + res[row * HID + j];
  float s = v, s2 = v * v;
#pragma unroll
  for (int off = 32; off > 0; off >>= 1) {
    s += __shfl_xor(s, off);
    s2 += __shfl_xor(s2, off);
  }
  __shared__ float ss[4], ss2[4];
  int wave = j >> 6, lane = j & 63;
  if (lane == 0) {
    ss[wave] = s;
    ss2[wave] = s2;
  }
  __syncthreads();
  s = ss[0] + ss[1] + ss[2] + ss[3];
  s2 = ss2[0] + ss2[1] + ss2[2] + ss2[3];
  float mean = s * (1.f / 256.f);
  float var = s2 * (1.f / 256.f) - mean * mean;
  float inv = rsqrtf(var + LN_EPS);
  out[row * HID + j] = (v - mean) * inv * g[j] + bta[j];
}

// ---------------------------------------------------------------------------
// recon_tokens (b,t,272) -> recon (b,272,32,32) + pred_sq
// ---------------------------------------------------------------------------
__global__ __launch_bounds__(256) void recon_out_kernel(
    const float* __restrict__ rt, const float* __restrict__ qf,
    float* __restrict__ recon, float* __restrict__ pred_sq) {
  int b = blockIdx.y;
  int t0 = blockIdx.x * 32;
  __shared__ float tile[32][33];
  int lx = threadIdx.x & 31;
  int ly = threadIdx.x >> 5;
  float sq = 0.f;
  for (int c0 = 0; c0 < DIN; c0 += 32) {
    __syncthreads();
#pragma unroll
    for (int i = 0; i < 4; i++) {
      int tt = ly + i * 8;
      int c = c0 + lx;
      tile[tt][lx] = (c < DIN) ? rt[((long)b * NTOK + t0 + tt) * DIN + c] : 0.f;
    }
    __syncthreads();
#pragma unroll
    for (int i = 0; i < 4; i++) {
      int c = c0 + ly + i * 8;
      if (c < DIN) {
        float v = tile[lx][ly + i * 8];
        long gaddr = ((long)b * DIN + c) * NTOK + t0 + lx;
        float q = qf[gaddr];
        recon[gaddr] = v;
        float d = v - q;
        sq = fmaf(d, d, sq);
      }
    }
  }
  __shared__ float red[8][33];
  red[ly][lx] = sq;
  __syncthreads();
  if (ly == 0) {
    float s = 0.f;
#pragma unroll
    for (int u = 0; u < 8; u++) s += red[u][lx];
    pred_sq[b * NTOK + t0 + lx] = s;
  }
}

__global__ __launch_bounds__(256) void minmax_kernel(
    const float* __restrict__ pred_sq, float* __restrict__ mnmx) {
  int tid = threadIdx.x;
  float mn = INFINITY, mx = -INFINITY;
  for (int i = tid; i < BATCH * NTOK; i += 256) {
    float v = sqrtf(pred_sq[i]);
    mn = fminf(mn, v);
    mx = fmaxf(mx, v);
  }
#pragma unroll
  for (int off = 32; off > 0; off >>= 1) {
    mn = fminf(mn, __shfl_xor(mn, off));
    mx = fmaxf(mx, __shfl_xor(mx, off));
  }
  __shared__ float smn[4], smx[4];
  int wave = tid >> 6, lane = tid & 63;
  if (lane == 0) {
    smn[wave] = mn;
    smx[wave] = mx;
  }
  __syncthreads();
  if (tid == 0) {
    mn = fminf(fminf(smn[0], smn[1]), fminf(smn[2], smn[3]));
    mx = fmaxf(fmaxf(smx[0], smx[1]), fmaxf(smx[2], smx[3]));
    mnmx[0] = mn;
    mnmx[1] = mx;
  }
}

__global__ __launch_bounds__(256) void resize_kernel(
    const float* __restrict__ pred_sq, const float* __restrict__ mnmx,
    float* __restrict__ out) {
  long idx = (long)blockIdx.x * 256 + threadIdx.x;
  if (idx >= (long)BATCH * 256 * 256) return;
  int b = (int)(idx >> 16);
  int oy = (int)((idx >> 8) & 255), ox = (int)(idx & 255);
  float mn = mnmx[0], mx = mnmx[1];
  float inv = 1.0f / (mx - mn);
  float ys = oy * (31.0f / 255.0f);
  int y0 = (int)floorf(ys);
  int y1 = min(y0 + 1, 31);
  float fy = ys - (float)y0;
  float xs = ox * (31.0f / 255.0f);
  int x0 = (int)floorf(xs);
  int x1 = min(x0 + 1, 31);
  float fx = xs - (float)x0;
  const float* p = pred_sq + b * NTOK;
  float v00 = sqrtf(p[y0 * 32 + x0]), v01 = sqrtf(p[y0 * 32 + x1]);
  float v10 = sqrtf(p[y1 * 32 + x0]), v11 = sqrtf(p[y1 * 32 + x1]);
  float cA = v00 * (1.f - fy) + v10 * fy;
  float cB = v01 * (1.f - fy) + v11 * fy;
  float v = cA * (1.f - fx) + cB * fx;
  out[idx] = (v - mn) * inv;
}

// ---------------------------------------------------------------------------
extern "C" void kernel_launch(void* const* d_in, const int* in_sizes, int n_in,
                              void* d_out, int out_size, void* d_ws,
                              size_t ws_size, hipStream_t stream) {
  const float* qf = (const float*)d_in[0];
  const float* mf = (const float*)d_in[1];
  const float* qW = (const float*)d_in[2];
  const float* qb = (const float*)d_in[3];
  const float* kvW = (const float*)d_in[4];
  const float* kvb = (const float*)d_in[5];
  const float* row_e = (const float*)d_in[6];
  const float* col_e = (const float*)d_in[7];
  const float* aggW = (const float*)d_in[8];
  const float* aggb = (const float*)d_in[9];
  const float* n1g = (const float*)d_in[10];
  const float* n1b = (const float*)d_in[11];
  const float* l1W = (const float*)d_in[12];
  const float* l1b = (const float*)d_in[13];
  const float* l2W = (const float*)d_in[14];
  const float* l2b = (const float*)d_in[15];
  const float* n2g = (const float*)d_in[16];
  const float* n2b = (const float*)d_in[17];
  const float* outW = (const float*)d_in[18];
  const float* outb = (const float*)d_in[19];

  float* out = (float*)d_out;
  float* recon = out;                            // 16*272*1024
  float* pred = out + (long)BATCH * DIN * NTOK;  // 16*256*256

  // bf16 transposed weights stashed in d_out (≈3.6MB < 17.8MB recon region),
  // fully consumed before recon_out_kernel overwrites it at the end.
  short* wt = (short*)d_out;
  short* wt_agg0 = wt;                  // [256][1024]
  short* wt_agg1 = wt_agg0 + 262144;    // [256][1024]
  short* wt_l1_0 = wt_agg1 + 262144;    // [1024][256]
  short* wt_l1_1 = wt_l1_0 + 262144;    // [1024][256]
  short* wt_l2_0 = wt_l1_1 + 262144;    // [256][1024]
  short* wt_l2_1 = wt_l2_0 + 262144;    // [256][1024]
  short* wt_out = wt_l2_1 + 262144;     // [272][256]
  short* wt_q = wt_out + 69632;         // [256][288]
  short* wt_kv = wt_q + 73728;          // [256][288]

  // workspace layout
  float* ws = (float*)d_ws;
  float* pos = ws;                            // 262144 f
  float* x = pos + 262144;                    // 4194304 f
  short* ktp = (short*)(x + 4194304);         // 16777216 s
  short* ktv = ktp + 16777216;                // 16777216 s
  float* buf1024 = (float*)(ktv + 16777216);  // 16777216 f
  float* tmp256 = buf1024 + 16777216;         // 4194304 f
  float* pred_sq = tmp256 + 4194304;          // 16384 f
  float* mnmx = pred_sq + 16384;              // 2 f
  // transient aliases (consumed before their hosts are first written):
  short* mf_t = (short*)buf1024;  // [65536][288] bf16 (36MB <= 64MB)
  short* qf_t = (short*)tmp256;   // [16384][288] bf16 (9MB <= 16MB)

  pos_kernel<<<NTOK, 256, 0, stream>>>(row_e, col_e, pos);

  wt_cvt_kernel<<<dim3(8, 32), 256, 0, stream>>>(aggW, wt_agg0, 1024, 1024, 256);
  wt_cvt_kernel<<<dim3(8, 32), 256, 0, stream>>>(aggW + 262144, wt_agg1, 1024, 1024, 256);
  wt_cvt_kernel<<<dim3(32, 8), 256, 0, stream>>>(l1W, wt_l1_0, 256, 256, 1024);
  wt_cvt_kernel<<<dim3(32, 8), 256, 0, stream>>>(l1W + 262144, wt_l1_1, 256, 256, 1024);
  wt_cvt_kernel<<<dim3(8, 32), 256, 0, stream>>>(l2W, wt_l2_0, 1024, 1024, 256);
  wt_cvt_kernel<<<dim3(8, 32), 256, 0, stream>>>(l2W + 262144, wt_l2_1, 1024, 1024, 256);
  wt_cvt_kernel<<<dim3(9, 8), 256, 0, stream>>>(outW, wt_out, 256, 256, 272);
  wt_cvt_kernel<<<dim3(8, 9), 256, 0, stream>>>(qW, wt_q, 272, 288, 256);
  wt_cvt_kernel<<<dim3(8, 9), 256, 0, stream>>>(kvW, wt_kv, 272, 288, 256);

  // activation transposes (into transient aliases)
  tcvt_kernel<<<dim3(2048, 9), 256, 0, stream>>>(mf, mf_t);
  tcvt_kernel<<<dim3(512, 9), 256, 0, stream>>>(qf, qf_t);

  // q projection: qf_t[16384][288] @ wt_q -> x (fp32)
  mfma_gemm_bf16a_kernel<0><<<dim3(2, 128), 256, 0, stream>>>(
      qf_t, wt_q, qb, x, BATCH * NTOK, HID, DINP, nullptr, nullptr, nullptr);
  // kv projection: mf_t[65536][288] @ wt_kv -> ktp (+pos) and ktv (V^T)
  mfma_gemm_bf16a_kernel<2><<<dim3(2, 512), 256, 0, stream>>>(
      mf_t, wt_kv, kvb, nullptr, KMEM * BATCH * NTOK, HID, DINP, ktp, ktv,
      pos);

  for (int l = 0; l < 2; l++) {
    attn_kernel<<<2048, 256, 0, stream>>>(x, ktp, ktv, pos, buf1024);
    // agg
    mfma_gemm_kernel<false><<<dim3(2, 128), 256, 0, stream>>>(
        buf1024, l ? wt_agg1 : wt_agg0, aggb + l * 256, tmp256, BATCH * NTOK,
        HID, KMEM * HID);
    add_ln_kernel<<<BATCH * NTOK, 256, 0, stream>>>(x, tmp256, n1g + l * 256,
                                                    n1b + l * 256, x);
    // ff1
    mfma_gemm_kernel<true><<<dim3(8, 128), 256, 0, stream>>>(
        x, l ? wt_l1_1 : wt_l1_0, l1b + l * 1024, buf1024, BATCH * NTOK, DFF,
        HID);
    // ff2
    mfma_gemm_kernel<false><<<dim3(2, 128), 256, 0, stream>>>(
        buf1024, l ? wt_l2_1 : wt_l2_0, l2b + l * 256, tmp256, BATCH * NTOK,
        HID, DFF);
    add_ln_kernel<<<BATCH * NTOK, 256, 0, stream>>>(x, tmp256, n2g + l * 256,
                                                    n2b + l * 256, x);
  }

  // out projection -> recon_tokens (buf1024)
  mfma_gemm_kernel<false><<<dim3(3, 128), 256, 0, stream>>>(
      x, wt_out, outb, buf1024, BATCH * NTOK, DIN, HID);
  {
    dim3 grid(NTOK / 32, BATCH);
    recon_out_kernel<<<grid, 256, 0, stream>>>(buf1024, qf, recon, pred_sq);
  }
  minmax_kernel<<<1, 256, 0, stream>>>(pred_sq, mnmx);
  resize_kernel<<<(BATCH * 256 * 256) / 256, 256, 0, stream>>>(pred_sq, mnmx,
                                                               pred);
}

// Round 6
// 503.697 us; speedup vs baseline: 4.8791x; 1.5990x over previous
//
#include <hip/hip_runtime.h>
#include <hip/hip_bf16.h>
#include <math.h>

// Problem constants
#define BATCH 16
#define NTOK 1024      // 32*32
#define HID 256
#define KMEM 4
#define DIN 272
#define DINP 288       // DIN zero-padded to /32
#define DFF 1024
#define LN_EPS 1e-5f

using short8 = __attribute__((ext_vector_type(8))) short;
using short4v = __attribute__((ext_vector_type(4))) short;
using floatx4 = __attribute__((ext_vector_type(4))) float;

__device__ inline short f2bf(float f) {
  unsigned u = __builtin_bit_cast(unsigned, f);
  u += 0x7fff + ((u >> 16) & 1);  // RNE
  return (short)(u >> 16);
}

// ---------------------------------------------------------------------------
// pos embed: pos[t][j] = j<128 ? col_embed[t%32][j] : row_embed[t/32][j-128]
// ---------------------------------------------------------------------------
__global__ __launch_bounds__(256) void pos_kernel(
    const float* __restrict__ row_e, const float* __restrict__ col_e,
    float* __restrict__ pos) {
  int t = blockIdx.x;
  int j = threadIdx.x;
  float v = (j < 128) ? col_e[(t & 31) * 128 + j]
                      : row_e[(t >> 5) * 128 + (j - 128)];
  pos[t * 256 + j] = v;
}

// ---------------------------------------------------------------------------
// Activation transpose+cvt: src fp32 [slices][272][1024] -> dst bf16
// [slices*1024][288], channels 272..287 zeroed.  One 32x32 tile per block.
// ---------------------------------------------------------------------------
__global__ __launch_bounds__(256) void tcvt_kernel(
    const float* __restrict__ src, short* __restrict__ dst) {
  __shared__ short tile[32][33];
  int slice = blockIdx.x >> 5;
  int t0 = (blockIdx.x & 31) * 32;
  int c0 = blockIdx.y * 32;
  int tx = threadIdx.x & 31, ty = threadIdx.x >> 5;
  const float* s = src + (long)slice * DIN * NTOK;
#pragma unroll
  for (int i = 0; i < 4; i++) {
    int c = c0 + ty + i * 8;
    float v = (c < DIN) ? s[(long)c * NTOK + t0 + tx] : 0.f;
    tile[ty + i * 8][tx] = f2bf(v);
  }
  __syncthreads();
  short* d = dst + ((long)slice * NTOK + t0) * DINP + c0;
#pragma unroll
  for (int i = 0; i < 4; i++) {
    int tl = ty + i * 8;
    d[(long)tl * DINP + tx] = tile[tx][tl];
  }
}

// ---------------------------------------------------------------------------
// Weight transpose + cvt: W[K][N] fp32 -> Wt[N][Kd] bf16, rows K..Kd zeroed
// ---------------------------------------------------------------------------
__global__ __launch_bounds__(256) void wt_cvt_kernel(
    const float* __restrict__ W, short* __restrict__ Wt, int K, int Kd,
    int N) {
  __shared__ short tile[32][33];
  int n0 = blockIdx.x * 32, k0 = blockIdx.y * 32;
  int tx = threadIdx.x & 31, ty8 = threadIdx.x >> 5;
#pragma unroll
  for (int i = 0; i < 4; i++) {
    int k = k0 + ty8 + i * 8;
    int n = n0 + tx;
    float v = (k < K && n < N) ? W[(long)k * N + n] : 0.f;
    tile[ty8 + i * 8][tx] = f2bf(v);
  }
  __syncthreads();
#pragma unroll
  for (int i = 0; i < 4; i++) {
    int n = n0 + ty8 + i * 8;
    int k = k0 + tx;
    if (n < N && k < Kd) Wt[(long)n * Kd + k] = tile[tx][ty8 + i * 8];
  }
}

// ---------------------------------------------------------------------------
// Unified MFMA bf16 GEMM with 2-phase prefetch pipeline.
// A bf16 [M][K] row-major, Wt bf16 [N][K].  Tile 64x128, BK=32, 4 waves
// (2x2 -> each wave 32x64 = 2x4 frags of 16x16x32).  Double-buffered LDS,
// register prefetch of tile t+1 issued BEFORE the MFMA of tile t, one
// barrier/iter.  1D grid, bijective XCD chunk swizzle (col tile fastest so
// col-tiles sharing A rows land on the same XCD).  nwg % 8 == 0 required.
// OUTMODE 0: Cf = fp32 (+bias).  OUTMODE 1: Cs = bf16 relu (+bias).
// OUTMODE 2: kv projection (N==256):
//   ktp[r*256+c] = bf16(val + pos[(r&1023)*256+c]),
//   ktv[(r>>10)*262144 + c*1024 + (r&1023)] = bf16(val)   (V^T)
// ---------------------------------------------------------------------------
template <int OUTMODE>
__global__ __launch_bounds__(256) void gemm2_kernel(
    const short* __restrict__ A, const short* __restrict__ Wt,
    const float* __restrict__ bias, float* __restrict__ Cf,
    short* __restrict__ Cs, int M, int N, int K, int gxn,
    short* __restrict__ ktp, short* __restrict__ ktv,
    const float* __restrict__ pos) {
  __shared__ short As[2][64][40];
  __shared__ short Bs[2][128][40];
  int nwg = gridDim.x;
  int cpx = nwg >> 3;
  int bid = blockIdx.x;
  int h = (bid & 7) * cpx + (bid >> 3);  // logical id: contiguous chunk/XCD
  int cx = h % gxn;
  int ry = h / gxn;
  int row0 = ry * 64, col0 = cx * 128;
  int tid = threadIdx.x;
  int w = tid >> 6, lane = tid & 63;
  int wrow = (w >> 1) * 32, wcol = (w & 1) * 64;
  int lcol = lane & 15, kg = lane >> 4;

  // staging indices: A 64x32 (1 short8/thr), B 128x32 (2 short8/thr)
  int arow = tid >> 2, ak = (tid & 3) * 8;
  int brow = tid >> 2, bk = (tid & 3) * 8;  // rows brow and brow+64
  const short* Ab = A + (long)row0 * K;
  const short* Bb = Wt + (long)col0 * K;
  bool bv0 = (col0 + brow) < N;
  bool bv1 = (col0 + brow + 64) < N;

  const short8 z8 = (short8){0, 0, 0, 0, 0, 0, 0, 0};
  short8 ra, rb0, rb1;
  // prologue: tile 0 -> buf 0
  ra = *reinterpret_cast<const short8*>(&Ab[(long)arow * K + ak]);
  rb0 = bv0 ? *reinterpret_cast<const short8*>(&Bb[(long)brow * K + bk]) : z8;
  rb1 = bv1 ? *reinterpret_cast<const short8*>(&Bb[(long)(brow + 64) * K + bk])
            : z8;
  *reinterpret_cast<short8*>(&As[0][arow][ak]) = ra;
  *reinterpret_cast<short8*>(&Bs[0][brow][bk]) = rb0;
  *reinterpret_cast<short8*>(&Bs[0][brow + 64][bk]) = rb1;
  __syncthreads();

  floatx4 acc[2][4];
#pragma unroll
  for (int m = 0; m < 2; ++m)
#pragma unroll
    for (int n = 0; n < 4; ++n) acc[m][n] = (floatx4){0.f, 0.f, 0.f, 0.f};

  int NT = K >> 5;
  for (int t = 0; t < NT; ++t) {
    int cur = t & 1;
    if (t + 1 < NT) {  // issue prefetch loads (consumed after MFMA)
      int ko = (t + 1) << 5;
      ra = *reinterpret_cast<const short8*>(&Ab[(long)arow * K + ko + ak]);
      rb0 = bv0 ? *reinterpret_cast<const short8*>(&Bb[(long)brow * K + ko + bk])
                : z8;
      rb1 = bv1 ? *reinterpret_cast<const short8*>(
                      &Bb[(long)(brow + 64) * K + ko + bk])
                : z8;
    }
    short8 af[2], bf[4];
#pragma unroll
    for (int m = 0; m < 2; ++m)
      af[m] = *reinterpret_cast<const short8*>(
          &As[cur][wrow + m * 16 + lcol][kg * 8]);
#pragma unroll
    for (int n = 0; n < 4; ++n)
      bf[n] = *reinterpret_cast<const short8*>(
          &Bs[cur][wcol + n * 16 + lcol][kg * 8]);
#pragma unroll
    for (int m = 0; m < 2; ++m)
#pragma unroll
      for (int n = 0; n < 4; ++n)
        acc[m][n] = __builtin_amdgcn_mfma_f32_16x16x32_bf16(af[m], bf[n],
                                                            acc[m][n], 0, 0, 0);
    if (t + 1 < NT) {
      int nxt = cur ^ 1;
      *reinterpret_cast<short8*>(&As[nxt][arow][ak]) = ra;
      *reinterpret_cast<short8*>(&Bs[nxt][brow][bk]) = rb0;
      *reinterpret_cast<short8*>(&Bs[nxt][brow + 64][bk]) = rb1;
    }
    __syncthreads();
  }

#pragma unroll
  for (int n = 0; n < 4; ++n) {
    int c = col0 + wcol + n * 16 + lcol;
    if (c >= N) continue;
    float bv = bias[c];
#pragma unroll
    for (int m = 0; m < 2; ++m) {
      int rbase = row0 + wrow + m * 16 + kg * 4;
      if (OUTMODE == 0) {
#pragma unroll
        for (int q = 0; q < 4; ++q)
          Cf[(long)(rbase + q) * N + c] = acc[m][n][q] + bv;
      } else if (OUTMODE == 1) {
#pragma unroll
        for (int q = 0; q < 4; ++q)
          Cs[(long)(rbase + q) * N + c] = f2bf(fmaxf(acc[m][n][q] + bv, 0.f));
      } else {
        int slice = rbase >> 10, tbase = rbase & 1023;
        short4v vt;
#pragma unroll
        for (int q = 0; q < 4; ++q) {
          float val = acc[m][n][q] + bv;
          vt[q] = f2bf(val);
          ktp[(long)(rbase + q) * 256 + c] =
              f2bf(val + pos[(tbase + q) * 256 + c]);
        }
        *reinterpret_cast<short4v*>(
            &ktv[(long)slice * (256 * 1024) + (long)c * 1024 + tbase]) = vt;
      }
    }
  }
}

// ---------------------------------------------------------------------------
// MFMA windowed attention. One block per (b,k,r) (grid 2048, XCD-swizzled).
// S[32q x 256key] = Q @ K'^T   (K'-frags b128 direct from global ktp)
// cross-wave softmax (stats in LDS), P transposed into LDS (bf16),
// O[32q x 256ch] = P @ V       (V-frags b128 from global ktv = V^T)
// Output o written bf16.
// ---------------------------------------------------------------------------
__global__ __launch_bounds__(256) void attn_kernel(
    const float* __restrict__ x, const short* __restrict__ ktp,
    const short* __restrict__ ktv, const float* __restrict__ pos,
    short* __restrict__ o) {
  __shared__ short Q_s[32][264];
  __shared__ short P_s[32][264];
  __shared__ float st_mx[32][4];
  __shared__ float st_sm[32][4];
  int h = blockIdx.x;
  int xcd = h & 7, jj = h >> 3;
  int sidx = xcd * 8 + (jj >> 5);
  int r = jj & 31;
  int b = sidx & 15, k = sidx >> 4;
  int tid = threadIdx.x;
  int w = tid >> 6, lane = tid & 63, lcol = lane & 15, kg = lane >> 4;
  const float scale = 0.0625f;  // 1/sqrt(256)

  // ---- stage Q = bf16((x + pos) * scale) ----
  const float* xb = x + ((long)b * NTOK + r * 32) * HID;
  const float* pq = pos + (long)r * 32 * HID;
#pragma unroll
  for (int p = 0; p < 8; ++p) {
    int f = p * 256 + tid;
    int row = f >> 6, c4 = (f & 63) << 2;
    float4 xv = *reinterpret_cast<const float4*>(&xb[row * HID + c4]);
    float4 pv = *reinterpret_cast<const float4*>(&pq[row * HID + c4]);
    short4v s;
    s[0] = f2bf((xv.x + pv.x) * scale);
    s[1] = f2bf((xv.y + pv.y) * scale);
    s[2] = f2bf((xv.z + pv.z) * scale);
    s[3] = f2bf((xv.w + pv.w) * scale);
    *reinterpret_cast<short4v*>(&Q_s[row][c4]) = s;
  }
  __syncthreads();

  int r0 = max(r - 3, 0), r1 = min(r + 3, 31);
  int nkr = r1 - r0 + 1, nm = nkr * 32;
  const short* ktpb = ktp + ((long)(k * BATCH + b)) * NTOK * HID;
  const short* ktvb = ktv + ((long)(k * BATCH + b)) * NTOK * HID;

  // ---- S phase ----
  floatx4 acc[2][4];
#pragma unroll
  for (int m = 0; m < 2; ++m)
#pragma unroll
    for (int n = 0; n < 4; ++n) acc[m][n] = (floatx4){0.f, 0.f, 0.f, 0.f};

  int tokn[4];
#pragma unroll
  for (int n = 0; n < 4; ++n) {
    int nf = w * 4 + n;
    int krow = min(r0 + (nf >> 1), 31);
    tokn[n] = krow * 32 + ((nf & 1) << 4) + lcol;
  }
#pragma unroll
  for (int s = 0; s < 8; ++s) {
    short8 af0 = *reinterpret_cast<const short8*>(&Q_s[lcol][s * 32 + kg * 8]);
    short8 af1 =
        *reinterpret_cast<const short8*>(&Q_s[16 + lcol][s * 32 + kg * 8]);
#pragma unroll
    for (int n = 0; n < 4; ++n) {
      short8 bfr = *reinterpret_cast<const short8*>(
          &ktpb[(long)tokn[n] * HID + s * 32 + kg * 8]);
      acc[0][n] =
          __builtin_amdgcn_mfma_f32_16x16x32_bf16(af0, bfr, acc[0][n], 0, 0, 0);
      acc[1][n] =
          __builtin_amdgcn_mfma_f32_16x16x32_bf16(af1, bfr, acc[1][n], 0, 0, 0);
    }
  }

  // ---- softmax ----
  const float NEG = -3.0e38f;
  float mx[2][4];
#pragma unroll
  for (int m = 0; m < 2; ++m)
#pragma unroll
    for (int q = 0; q < 4; ++q) {
      int rr = m * 16 + kg * 4 + q;
      float vmax = NEG;
#pragma unroll
      for (int n = 0; n < 4; ++n) {
        int col = (w * 4 + n) * 16 + lcol;
        int ck = col & 31;
        bool ok = (col < nm) && (ck - rr <= 3) && (rr - ck <= 3);
        float v = ok ? acc[m][n][q] : NEG;
        acc[m][n][q] = v;
        vmax = fmaxf(vmax, v);
      }
      vmax = fmaxf(vmax, __shfl_xor(vmax, 1));
      vmax = fmaxf(vmax, __shfl_xor(vmax, 2));
      vmax = fmaxf(vmax, __shfl_xor(vmax, 4));
      vmax = fmaxf(vmax, __shfl_xor(vmax, 8));
      mx[m][q] = vmax;
    }
  if (lcol == 0) {
#pragma unroll
    for (int m = 0; m < 2; ++m)
#pragma unroll
      for (int q = 0; q < 4; ++q) st_mx[m * 16 + kg * 4 + q][w] = mx[m][q];
  }
  __syncthreads();
  float sm[2][4];
#pragma unroll
  for (int m = 0; m < 2; ++m)
#pragma unroll
    for (int q = 0; q < 4; ++q) {
      int rr = m * 16 + kg * 4 + q;
      float4 v4 = *reinterpret_cast<const float4*>(&st_mx[rr][0]);
      float g = fmaxf(fmaxf(v4.x, v4.y), fmaxf(v4.z, v4.w));
      float ss = 0.f;
#pragma unroll
      for (int n = 0; n < 4; ++n) {
        float v = acc[m][n][q];
        float pv = (v > -1.0e30f) ? exp2f((v - g) * 1.4426950408889634f) : 0.f;
        acc[m][n][q] = pv;
        ss += pv;
      }
      ss += __shfl_xor(ss, 1);
      ss += __shfl_xor(ss, 2);
      ss += __shfl_xor(ss, 4);
      ss += __shfl_xor(ss, 8);
      sm[m][q] = ss;
    }
  if (lcol == 0) {
#pragma unroll
    for (int m = 0; m < 2; ++m)
#pragma unroll
      for (int q = 0; q < 4; ++q) st_sm[m * 16 + kg * 4 + q][w] = sm[m][q];
  }
  __syncthreads();
#pragma unroll
  for (int m = 0; m < 2; ++m)
#pragma unroll
    for (int q = 0; q < 4; ++q) {
      int rr = m * 16 + kg * 4 + q;
      float4 v4 = *reinterpret_cast<const float4*>(&st_sm[rr][0]);
      float rinv = 1.0f / (v4.x + v4.y + v4.z + v4.w);
#pragma unroll
      for (int n = 0; n < 4; ++n) {
        P_s[rr][(w * 4 + n) * 16 + lcol] = f2bf(acc[m][n][q] * rinv);
      }
    }
  __syncthreads();

  // ---- PV ----
  floatx4 oacc[2][4];
#pragma unroll
  for (int m = 0; m < 2; ++m)
#pragma unroll
    for (int n = 0; n < 4; ++n) oacc[m][n] = (floatx4){0.f, 0.f, 0.f, 0.f};

  for (int kb = 0; kb < nkr; ++kb) {
    short8 ap0 = *reinterpret_cast<const short8*>(&P_s[lcol][kb * 32 + kg * 8]);
    short8 ap1 =
        *reinterpret_cast<const short8*>(&P_s[16 + lcol][kb * 32 + kg * 8]);
    int tokb = (r0 + kb) * 32;
#pragma unroll
    for (int n = 0; n < 4; ++n) {
      int ch = w * 64 + n * 16 + lcol;
      short8 bv = *reinterpret_cast<const short8*>(
          &ktvb[(long)ch * NTOK + tokb + kg * 8]);
      oacc[0][n] =
          __builtin_amdgcn_mfma_f32_16x16x32_bf16(ap0, bv, oacc[0][n], 0, 0, 0);
      oacc[1][n] =
          __builtin_amdgcn_mfma_f32_16x16x32_bf16(ap1, bv, oacc[1][n], 0, 0, 0);
    }
  }
  // ---- write O (bf16) ----
#pragma unroll
  for (int m = 0; m < 2; ++m)
#pragma unroll
    for (int n = 0; n < 4; ++n) {
      int ch = w * 64 + n * 16 + lcol;
#pragma unroll
      for (int q = 0; q < 4; ++q) {
        int rr = m * 16 + kg * 4 + q;
        o[((long)b * NTOK + r * 32 + rr) * (KMEM * HID) + k * HID + ch] =
            f2bf(oacc[m][n][q]);
      }
    }
}

// ---------------------------------------------------------------------------
// x = LayerNorm(x + res) * g + b  -> fp32 out AND bf16 out16
// ---------------------------------------------------------------------------
__global__ __launch_bounds__(256) void add_ln_kernel(
    const float* __restrict__ x, const float* __restrict__ res,
    const float* __restrict__ g, const float* __restrict__ bta,
    float* __restrict__ out, short* __restrict__ out16) {
  long row = blockIdx.x;
  int j = threadIdx.x;
  float v = x[row * HID + j] + res[row * HID + j];
  float s = v, s2 = v * v;
#pragma unroll
  for (int off = 32; off > 0; off >>= 1) {
    s += __shfl_xor(s, off);
    s2 += __shfl_xor(s2, off);
  }
  __shared__ float ss[4], ss2[4];
  int wave = j >> 6, lane = j & 63;
  if (lane == 0) {
    ss[wave] = s;
    ss2[wave] = s2;
  }
  __syncthreads();
  s = ss[0] + ss[1] + ss[2] + ss[3];
  s2 = ss2[0] + ss2[1] + ss2[2] + ss2[3];
  float mean = s * (1.f / 256.f);
  float var = s2 * (1.f / 256.f) - mean * mean;
  float inv = rsqrtf(var + LN_EPS);
  float r = (v - mean) * inv * g[j] + bta[j];
  out[row * HID + j] = r;
  out16[row * HID + j] = f2bf(r);
}

// ---------------------------------------------------------------------------
// recon_tokens (b,t,272) -> recon (b,272,32,32) + pred_sq
// ---------------------------------------------------------------------------
__global__ __launch_bounds__(256) void recon_out_kernel(
    const float* __restrict__ rt, const float* __restrict__ qf,
    float* __restrict__ recon, float* __restrict__ pred_sq) {
  int b = blockIdx.y;
  int t0 = blockIdx.x * 32;
  __shared__ float tile[32][33];
  int lx = threadIdx.x & 31;
  int ly = threadIdx.x >> 5;
  float sq = 0.f;
  for (int c0 = 0; c0 < DIN; c0 += 32) {
    __syncthreads();
#pragma unroll
    for (int i = 0; i < 4; i++) {
      int tt = ly + i * 8;
      int c = c0 + lx;
      tile[tt][lx] = (c < DIN) ? rt[((long)b * NTOK + t0 + tt) * DIN + c] : 0.f;
    }
    __syncthreads();
#pragma unroll
    for (int i = 0; i < 4; i++) {
      int c = c0 + ly + i * 8;
      if (c < DIN) {
        float v = tile[lx][ly + i * 8];
        long gaddr = ((long)b * DIN + c) * NTOK + t0 + lx;
        float q = qf[gaddr];
        recon[gaddr] = v;
        float d = v - q;
        sq = fmaf(d, d, sq);
      }
    }
  }
  __shared__ float red[8][33];
  red[ly][lx] = sq;
  __syncthreads();
  if (ly == 0) {
    float s = 0.f;
#pragma unroll
    for (int u = 0; u < 8; u++) s += red[u][lx];
    pred_sq[b * NTOK + t0 + lx] = s;
  }
}

__global__ __launch_bounds__(256) void minmax_kernel(
    const float* __restrict__ pred_sq, float* __restrict__ mnmx) {
  int tid = threadIdx.x;
  float mn = INFINITY, mx = -INFINITY;
  for (int i = tid; i < BATCH * NTOK; i += 256) {
    float v = sqrtf(pred_sq[i]);
    mn = fminf(mn, v);
    mx = fmaxf(mx, v);
  }
#pragma unroll
  for (int off = 32; off > 0; off >>= 1) {
    mn = fminf(mn, __shfl_xor(mn, off));
    mx = fmaxf(mx, __shfl_xor(mx, off));
  }
  __shared__ float smn[4], smx[4];
  int wave = tid >> 6, lane = tid & 63;
  if (lane == 0) {
    smn[wave] = mn;
    smx[wave] = mx;
  }
  __syncthreads();
  if (tid == 0) {
    mn = fminf(fminf(smn[0], smn[1]), fminf(smn[2], smn[3]));
    mx = fmaxf(fmaxf(smx[0], smx[1]), fmaxf(smx[2], smx[3]));
    mnmx[0] = mn;
    mnmx[1] = mx;
  }
}

__global__ __launch_bounds__(256) void resize_kernel(
    const float* __restrict__ pred_sq, const float* __restrict__ mnmx,
    float* __restrict__ out) {
  long idx = (long)blockIdx.x * 256 + threadIdx.x;
  if (idx >= (long)BATCH * 256 * 256) return;
  int b = (int)(idx >> 16);
  int oy = (int)((idx >> 8) & 255), ox = (int)(idx & 255);
  float mn = mnmx[0], mx = mnmx[1];
  float inv = 1.0f / (mx - mn);
  float ys = oy * (31.0f / 255.0f);
  int y0 = (int)floorf(ys);
  int y1 = min(y0 + 1, 31);
  float fy = ys - (float)y0;
  float xs = ox * (31.0f / 255.0f);
  int x0 = (int)floorf(xs);
  int x1 = min(x0 + 1, 31);
  float fx = xs - (float)x0;
  const float* p = pred_sq + b * NTOK;
  float v00 = sqrtf(p[y0 * 32 + x0]), v01 = sqrtf(p[y0 * 32 + x1]);
  float v10 = sqrtf(p[y1 * 32 + x0]), v11 = sqrtf(p[y1 * 32 + x1]);
  float cA = v00 * (1.f - fy) + v10 * fy;
  float cB = v01 * (1.f - fy) + v11 * fy;
  float v = cA * (1.f - fx) + cB * fx;
  out[idx] = (v - mn) * inv;
}

// ---------------------------------------------------------------------------
extern "C" void kernel_launch(void* const* d_in, const int* in_sizes, int n_in,
                              void* d_out, int out_size, void* d_ws,
                              size_t ws_size, hipStream_t stream) {
  const float* qf = (const float*)d_in[0];
  const float* mf = (const float*)d_in[1];
  const float* qW = (const float*)d_in[2];
  const float* qb = (const float*)d_in[3];
  const float* kvW = (const float*)d_in[4];
  const float* kvb = (const float*)d_in[5];
  const float* row_e = (const float*)d_in[6];
  const float* col_e = (const float*)d_in[7];
  const float* aggW = (const float*)d_in[8];
  const float* aggb = (const float*)d_in[9];
  const float* n1g = (const float*)d_in[10];
  const float* n1b = (const float*)d_in[11];
  const float* l1W = (const float*)d_in[12];
  const float* l1b = (const float*)d_in[13];
  const float* l2W = (const float*)d_in[14];
  const float* l2b = (const float*)d_in[15];
  const float* n2g = (const float*)d_in[16];
  const float* n2b = (const float*)d_in[17];
  const float* outW = (const float*)d_in[18];
  const float* outb = (const float*)d_in[19];

  float* out = (float*)d_out;
  float* recon = out;                            // 16*272*1024
  float* pred = out + (long)BATCH * DIN * NTOK;  // 16*256*256

  // bf16 transposed weights stashed in d_out recon region,
  // fully consumed before recon_out_kernel overwrites it at the end.
  short* wt = (short*)d_out;
  short* wt_agg0 = wt;                  // [256][1024]
  short* wt_agg1 = wt_agg0 + 262144;    // [256][1024]
  short* wt_l1_0 = wt_agg1 + 262144;    // [1024][256]
  short* wt_l1_1 = wt_l1_0 + 262144;    // [1024][256]
  short* wt_l2_0 = wt_l1_1 + 262144;    // [256][1024]
  short* wt_l2_1 = wt_l2_0 + 262144;    // [256][1024]
  short* wt_out = wt_l2_1 + 262144;     // [272][256]
  short* wt_q = wt_out + 69632;         // [256][288]
  short* wt_kv = wt_q + 73728;          // [256][288]

  // workspace layout
  float* ws = (float*)d_ws;
  float* pos = ws;                              // 262144 f   (1MB)
  float* x = pos + 262144;                      // 4194304 f  (16MB)
  short* x16 = (short*)(x + 4194304);           // 4194304 s  (8MB)
  short* ktp = x16 + 4194304;                   // 16777216 s (32MB)
  short* ktv = ktp + 16777216;                  // 16777216 s (32MB)
  short* buf16 = ktv + 16777216;                // 16777216 s (32MB)
  float* tmp256 = (float*)(buf16 + 16777216);   // 4194304 f  (16MB)
  float* rtbuf = tmp256 + 4194304;              // 4456448 f  (17.8MB)
  float* pred_sq = rtbuf + 4456448;             // 16384 f
  float* mnmx = pred_sq + 16384;                // 2 f
  // transient aliases (consumed before their hosts are first written):
  short* qf_t = ktp;            // [16384][288] bf16 (9.4MB <= 32MB; consumed
                                //   by qproj before kvproj writes ktp)
  short* mf_t = buf16;          // [65536][288] bf16 (37.7MB <= buf16+tmp256
                                //   48MB; consumed before attn/agg write them)

  pos_kernel<<<NTOK, 256, 0, stream>>>(row_e, col_e, pos);

  wt_cvt_kernel<<<dim3(8, 32), 256, 0, stream>>>(aggW, wt_agg0, 1024, 1024, 256);
  wt_cvt_kernel<<<dim3(8, 32), 256, 0, stream>>>(aggW + 262144, wt_agg1, 1024, 1024, 256);
  wt_cvt_kernel<<<dim3(32, 8), 256, 0, stream>>>(l1W, wt_l1_0, 256, 256, 1024);
  wt_cvt_kernel<<<dim3(32, 8), 256, 0, stream>>>(l1W + 262144, wt_l1_1, 256, 256, 1024);
  wt_cvt_kernel<<<dim3(8, 32), 256, 0, stream>>>(l2W, wt_l2_0, 1024, 1024, 256);
  wt_cvt_kernel<<<dim3(8, 32), 256, 0, stream>>>(l2W + 262144, wt_l2_1, 1024, 1024, 256);
  wt_cvt_kernel<<<dim3(9, 8), 256, 0, stream>>>(outW, wt_out, 256, 256, 272);
  wt_cvt_kernel<<<dim3(8, 9), 256, 0, stream>>>(qW, wt_q, 272, 288, 256);
  wt_cvt_kernel<<<dim3(8, 9), 256, 0, stream>>>(kvW, wt_kv, 272, 288, 256);

  // q path first (qf_t aliases ktp; consumed before kvproj writes ktp)
  tcvt_kernel<<<dim3(512, 9), 256, 0, stream>>>(qf, qf_t);
  gemm2_kernel<0><<<512, 256, 0, stream>>>(qf_t, wt_q, qb, x, nullptr,
                                           BATCH * NTOK, HID, DINP, 2, nullptr,
                                           nullptr, nullptr);
  // kv path
  tcvt_kernel<<<dim3(2048, 9), 256, 0, stream>>>(mf, mf_t);
  gemm2_kernel<2><<<2048, 256, 0, stream>>>(mf_t, wt_kv, kvb, nullptr, nullptr,
                                            KMEM * BATCH * NTOK, HID, DINP, 2,
                                            ktp, ktv, pos);

  for (int l = 0; l < 2; l++) {
    attn_kernel<<<2048, 256, 0, stream>>>(x, ktp, ktv, pos, buf16);
    // agg: buf16[16384][1024] @ wt_agg -> tmp256 fp32
    gemm2_kernel<0><<<512, 256, 0, stream>>>(
        buf16, l ? wt_agg1 : wt_agg0, aggb + l * 256, tmp256, nullptr,
        BATCH * NTOK, HID, KMEM * HID, 2, nullptr, nullptr, nullptr);
    add_ln_kernel<<<BATCH * NTOK, 256, 0, stream>>>(
        x, tmp256, n1g + l * 256, n1b + l * 256, x, x16);
    // ff1: x16[16384][256] @ wt_l1 -> relu bf16 buf16
    gemm2_kernel<1><<<2048, 256, 0, stream>>>(
        x16, l ? wt_l1_1 : wt_l1_0, l1b + l * 1024, nullptr, buf16,
        BATCH * NTOK, DFF, HID, 8, nullptr, nullptr, nullptr);
    // ff2: buf16[16384][1024] @ wt_l2 -> tmp256 fp32
    gemm2_kernel<0><<<512, 256, 0, stream>>>(
        buf16, l ? wt_l2_1 : wt_l2_0, l2b + l * 256, tmp256, nullptr,
        BATCH * NTOK, HID, DFF, 2, nullptr, nullptr, nullptr);
    add_ln_kernel<<<BATCH * NTOK, 256, 0, stream>>>(
        x, tmp256, n2g + l * 256, n2b + l * 256, x, x16);
  }

  // out projection: x16 @ wt_out -> rtbuf fp32 (N=272 guarded)
  gemm2_kernel<0><<<768, 256, 0, stream>>>(x16, wt_out, outb, rtbuf, nullptr,
                                           BATCH * NTOK, DIN, HID, 3, nullptr,
                                           nullptr, nullptr);
  {
    dim3 grid(NTOK / 32, BATCH);
    recon_out_kernel<<<grid, 256, 0, stream>>>(rtbuf, qf, recon, pred_sq);
  }
  minmax_kernel<<<1, 256, 0, stream>>>(pred_sq, mnmx);
  resize_kernel<<<(BATCH * 256 * 256) / 256, 256, 0, stream>>>(pred_sq, mnmx,
                                                               pred);
}

// Round 7
// 444.334 us; speedup vs baseline: 5.5309x; 1.1336x over previous
//
#include <hip/hip_runtime.h>
#include <hip/hip_bf16.h>
#include <math.h>

// Problem constants
#define BATCH 16
#define NTOK 1024      // 32*32
#define HID 256
#define KMEM 4
#define DIN 272
#define DINP 288       // DIN zero-padded to /32
#define DFF 1024
#define LN_EPS 1e-5f

using short8 = __attribute__((ext_vector_type(8))) short;
using short4v = __attribute__((ext_vector_type(4))) short;
using floatx4 = __attribute__((ext_vector_type(4))) float;

__device__ inline short f2bf(float f) {
  unsigned u = __builtin_bit_cast(unsigned, f);
  u += 0x7fff + ((u >> 16) & 1);  // RNE
  return (short)(u >> 16);
}
__device__ inline float bf2f(short s) {
  unsigned u = ((unsigned)(unsigned short)s) << 16;
  return __builtin_bit_cast(float, u);
}

// ---------------------------------------------------------------------------
// pos embed: pos[t][j] = j<128 ? col_embed[t%32][j] : row_embed[t/32][j-128]
// ---------------------------------------------------------------------------
__global__ __launch_bounds__(256) void pos_kernel(
    const float* __restrict__ row_e, const float* __restrict__ col_e,
    float* __restrict__ pos) {
  int t = blockIdx.x;
  int j = threadIdx.x;
  float v = (j < 128) ? col_e[(t & 31) * 128 + j]
                      : row_e[(t >> 5) * 128 + (j - 128)];
  pos[t * 256 + j] = v;
}

// ---------------------------------------------------------------------------
// Activation transpose+cvt: src fp32 [slices][272][1024] -> dst bf16
// [slices*1024][288], channels 272..287 zeroed.
// ---------------------------------------------------------------------------
__global__ __launch_bounds__(256) void tcvt_kernel(
    const float* __restrict__ src, short* __restrict__ dst) {
  __shared__ short tile[32][33];
  int slice = blockIdx.x >> 5;
  int t0 = (blockIdx.x & 31) * 32;
  int c0 = blockIdx.y * 32;
  int tx = threadIdx.x & 31, ty = threadIdx.x >> 5;
  const float* s = src + (long)slice * DIN * NTOK;
#pragma unroll
  for (int i = 0; i < 4; i++) {
    int c = c0 + ty + i * 8;
    float v = (c < DIN) ? s[(long)c * NTOK + t0 + tx] : 0.f;
    tile[ty + i * 8][tx] = f2bf(v);
  }
  __syncthreads();
  short* d = dst + ((long)slice * NTOK + t0) * DINP + c0;
#pragma unroll
  for (int i = 0; i < 4; i++) {
    int tl = ty + i * 8;
    d[(long)tl * DINP + tx] = tile[tx][tl];
  }
}

// ---------------------------------------------------------------------------
// All weight transposes+cvt in ONE dispatch.  W[K][N] fp32 -> Wt[N][Kd] bf16.
// ---------------------------------------------------------------------------
struct WtJob {
  const float* src;
  short* dst;
  int K, Kd, N, ntx, start;
};
struct WtJobs {
  WtJob j[9];
};

__global__ __launch_bounds__(256) void wt_cvt_all_kernel(WtJobs jobs) {
  __shared__ short tile[32][33];
  int bid = blockIdx.x;
  int ji = 0;
#pragma unroll
  for (int i = 1; i < 9; ++i)
    if (bid >= jobs.j[i].start) ji = i;
  const float* W = jobs.j[ji].src;
  short* Wt = jobs.j[ji].dst;
  int K = jobs.j[ji].K, Kd = jobs.j[ji].Kd, N = jobs.j[ji].N;
  int local = bid - jobs.j[ji].start;
  int n0 = (local % jobs.j[ji].ntx) * 32;
  int k0 = (local / jobs.j[ji].ntx) * 32;
  int tx = threadIdx.x & 31, ty8 = threadIdx.x >> 5;
#pragma unroll
  for (int i = 0; i < 4; i++) {
    int k = k0 + ty8 + i * 8;
    int n = n0 + tx;
    float v = (k < K && n < N) ? W[(long)k * N + n] : 0.f;
    tile[ty8 + i * 8][tx] = f2bf(v);
  }
  __syncthreads();
#pragma unroll
  for (int i = 0; i < 4; i++) {
    int n = n0 + ty8 + i * 8;
    int k = k0 + tx;
    if (n < N && k < Kd) Wt[(long)n * Kd + k] = tile[tx][ty8 + i * 8];
  }
}

// ---------------------------------------------------------------------------
// Unified MFMA bf16 GEMM with 2-phase prefetch pipeline.
// A bf16 [M][K], Wt bf16 [N][K].  Tile 64x128, BK=32, 4 waves.
// OUTMODE 0: Cf fp32.  OUTMODE 1: Cs bf16 relu.  OUTMODE 3: Cf fp32 + Cs bf16.
// OUTMODE 2: kv projection (N==256): ktp = bf16(val+pos); ktv = V^T bf16.
// ---------------------------------------------------------------------------
template <int OUTMODE>
__global__ __launch_bounds__(256) void gemm2_kernel(
    const short* __restrict__ A, const short* __restrict__ Wt,
    const float* __restrict__ bias, float* __restrict__ Cf,
    short* __restrict__ Cs, int M, int N, int K, int gxn,
    short* __restrict__ ktp, short* __restrict__ ktv,
    const float* __restrict__ pos) {
  __shared__ short As[2][64][40];
  __shared__ short Bs[2][128][40];
  int nwg = gridDim.x;
  int cpx = nwg >> 3;
  int bid = blockIdx.x;
  int h = (bid & 7) * cpx + (bid >> 3);
  int cx = h % gxn;
  int ry = h / gxn;
  int row0 = ry * 64, col0 = cx * 128;
  int tid = threadIdx.x;
  int w = tid >> 6, lane = tid & 63;
  int wrow = (w >> 1) * 32, wcol = (w & 1) * 64;
  int lcol = lane & 15, kg = lane >> 4;

  int arow = tid >> 2, ak = (tid & 3) * 8;
  int brow = tid >> 2, bk = (tid & 3) * 8;
  const short* Ab = A + (long)row0 * K;
  const short* Bb = Wt + (long)col0 * K;
  bool bv0 = (col0 + brow) < N;
  bool bv1 = (col0 + brow + 64) < N;

  const short8 z8 = (short8){0, 0, 0, 0, 0, 0, 0, 0};
  short8 ra, rb0, rb1;
  ra = *reinterpret_cast<const short8*>(&Ab[(long)arow * K + ak]);
  rb0 = bv0 ? *reinterpret_cast<const short8*>(&Bb[(long)brow * K + bk]) : z8;
  rb1 = bv1 ? *reinterpret_cast<const short8*>(&Bb[(long)(brow + 64) * K + bk])
            : z8;
  *reinterpret_cast<short8*>(&As[0][arow][ak]) = ra;
  *reinterpret_cast<short8*>(&Bs[0][brow][bk]) = rb0;
  *reinterpret_cast<short8*>(&Bs[0][brow + 64][bk]) = rb1;
  __syncthreads();

  floatx4 acc[2][4];
#pragma unroll
  for (int m = 0; m < 2; ++m)
#pragma unroll
    for (int n = 0; n < 4; ++n) acc[m][n] = (floatx4){0.f, 0.f, 0.f, 0.f};

  int NT = K >> 5;
  for (int t = 0; t < NT; ++t) {
    int cur = t & 1;
    if (t + 1 < NT) {
      int ko = (t + 1) << 5;
      ra = *reinterpret_cast<const short8*>(&Ab[(long)arow * K + ko + ak]);
      rb0 = bv0 ? *reinterpret_cast<const short8*>(&Bb[(long)brow * K + ko + bk])
                : z8;
      rb1 = bv1 ? *reinterpret_cast<const short8*>(
                      &Bb[(long)(brow + 64) * K + ko + bk])
                : z8;
    }
    short8 af[2], bf[4];
#pragma unroll
    for (int m = 0; m < 2; ++m)
      af[m] = *reinterpret_cast<const short8*>(
          &As[cur][wrow + m * 16 + lcol][kg * 8]);
#pragma unroll
    for (int n = 0; n < 4; ++n)
      bf[n] = *reinterpret_cast<const short8*>(
          &Bs[cur][wcol + n * 16 + lcol][kg * 8]);
#pragma unroll
    for (int m = 0; m < 2; ++m)
#pragma unroll
      for (int n = 0; n < 4; ++n)
        acc[m][n] = __builtin_amdgcn_mfma_f32_16x16x32_bf16(af[m], bf[n],
                                                            acc[m][n], 0, 0, 0);
    if (t + 1 < NT) {
      int nxt = cur ^ 1;
      *reinterpret_cast<short8*>(&As[nxt][arow][ak]) = ra;
      *reinterpret_cast<short8*>(&Bs[nxt][brow][bk]) = rb0;
      *reinterpret_cast<short8*>(&Bs[nxt][brow + 64][bk]) = rb1;
    }
    __syncthreads();
  }

#pragma unroll
  for (int n = 0; n < 4; ++n) {
    int c = col0 + wcol + n * 16 + lcol;
    if (c >= N) continue;
    float bv = bias[c];
#pragma unroll
    for (int m = 0; m < 2; ++m) {
      int rbase = row0 + wrow + m * 16 + kg * 4;
      if (OUTMODE == 0) {
#pragma unroll
        for (int q = 0; q < 4; ++q)
          Cf[(long)(rbase + q) * N + c] = acc[m][n][q] + bv;
      } else if (OUTMODE == 1) {
#pragma unroll
        for (int q = 0; q < 4; ++q)
          Cs[(long)(rbase + q) * N + c] = f2bf(fmaxf(acc[m][n][q] + bv, 0.f));
      } else if (OUTMODE == 3) {
#pragma unroll
        for (int q = 0; q < 4; ++q) {
          float val = acc[m][n][q] + bv;
          Cf[(long)(rbase + q) * N + c] = val;
          Cs[(long)(rbase + q) * N + c] = f2bf(val);
        }
      } else {
        int slice = rbase >> 10, tbase = rbase & 1023;
        short4v vt;
#pragma unroll
        for (int q = 0; q < 4; ++q) {
          float val = acc[m][n][q] + bv;
          vt[q] = f2bf(val);
          ktp[(long)(rbase + q) * 256 + c] =
              f2bf(val + pos[(tbase + q) * 256 + c]);
        }
        *reinterpret_cast<short4v*>(
            &ktv[(long)slice * (256 * 1024) + (long)c * 1024 + tbase]) = vt;
      }
    }
  }
}

// ---------------------------------------------------------------------------
// MFMA GEMM + fused residual + LayerNorm epilogue.
// A bf16 [M][K] @ Wt bf16 [256][K] + bias + res(fp32) -> LN -> xout + x16out.
// Tile 32x256 (full row), BK=32, 4 waves (each wave 32 rows x 64 cols),
// 2-phase prefetch pipeline.  Grid = M/32.
// ---------------------------------------------------------------------------
__global__ __launch_bounds__(256) void gemm_ln_kernel(
    const short* __restrict__ A, const short* __restrict__ Wt,
    const float* __restrict__ bias, const float* __restrict__ res,
    const float* __restrict__ g, const float* __restrict__ bta,
    float* __restrict__ xout, short* __restrict__ x16out, int K) {
  __shared__ short As[2][32][40];
  __shared__ short Bs[2][256][40];
  __shared__ float st_s[32][4];
  __shared__ float st_s2[32][4];
  int tid = threadIdx.x;
  int row0 = blockIdx.x * 32;
  int w = tid >> 6, lane = tid & 63, lcol = lane & 15, kg = lane >> 4;
  int arow = tid >> 2, ak = (tid & 3) * 8;  // tid<128 stages A
  int brow = tid >> 2, bk = (tid & 3) * 8;  // rows brow + i*64
  const short* Ab = A + (long)row0 * K;

  short8 ra, rb[4];
  if (tid < 128) ra = *reinterpret_cast<const short8*>(&Ab[(long)arow * K + ak]);
#pragma unroll
  for (int i = 0; i < 4; ++i)
    rb[i] = *reinterpret_cast<const short8*>(&Wt[(long)(brow + i * 64) * K + bk]);
  if (tid < 128) *reinterpret_cast<short8*>(&As[0][arow][ak]) = ra;
#pragma unroll
  for (int i = 0; i < 4; ++i)
    *reinterpret_cast<short8*>(&Bs[0][brow + i * 64][bk]) = rb[i];
  __syncthreads();

  floatx4 acc[2][4];
#pragma unroll
  for (int m = 0; m < 2; ++m)
#pragma unroll
    for (int n = 0; n < 4; ++n) acc[m][n] = (floatx4){0.f, 0.f, 0.f, 0.f};

  int NT = K >> 5;
  for (int t = 0; t < NT; ++t) {
    int cur = t & 1;
    if (t + 1 < NT) {
      int ko = (t + 1) << 5;
      if (tid < 128)
        ra = *reinterpret_cast<const short8*>(&Ab[(long)arow * K + ko + ak]);
#pragma unroll
      for (int i = 0; i < 4; ++i)
        rb[i] = *reinterpret_cast<const short8*>(
            &Wt[(long)(brow + i * 64) * K + ko + bk]);
    }
    short8 af[2], bf[4];
#pragma unroll
    for (int m = 0; m < 2; ++m)
      af[m] =
          *reinterpret_cast<const short8*>(&As[cur][m * 16 + lcol][kg * 8]);
#pragma unroll
    for (int n = 0; n < 4; ++n)
      bf[n] = *reinterpret_cast<const short8*>(
          &Bs[cur][w * 64 + n * 16 + lcol][kg * 8]);
#pragma unroll
    for (int m = 0; m < 2; ++m)
#pragma unroll
      for (int n = 0; n < 4; ++n)
        acc[m][n] = __builtin_amdgcn_mfma_f32_16x16x32_bf16(af[m], bf[n],
                                                            acc[m][n], 0, 0, 0);
    if (t + 1 < NT) {
      int nxt = cur ^ 1;
      if (tid < 128) *reinterpret_cast<short8*>(&As[nxt][arow][ak]) = ra;
#pragma unroll
      for (int i = 0; i < 4; ++i)
        *reinterpret_cast<short8*>(&Bs[nxt][brow + i * 64][bk]) = rb[i];
    }
    __syncthreads();
  }

  // epilogue: val = acc + bias + residual, then LN over the 256-wide row
  float val[2][4][4];
#pragma unroll
  for (int n = 0; n < 4; ++n) {
    int c = w * 64 + n * 16 + lcol;
    float bv = bias[c];
#pragma unroll
    for (int m = 0; m < 2; ++m) {
      int rbase = row0 + m * 16 + kg * 4;
#pragma unroll
      for (int q = 0; q < 4; ++q)
        val[m][n][q] = acc[m][n][q] + bv + res[(long)(rbase + q) * 256 + c];
    }
  }
  float s[2][4], s2[2][4];
#pragma unroll
  for (int m = 0; m < 2; ++m)
#pragma unroll
    for (int q = 0; q < 4; ++q) {
      float ss = 0.f, ss2 = 0.f;
#pragma unroll
      for (int n = 0; n < 4; ++n) {
        float v = val[m][n][q];
        ss += v;
        ss2 = fmaf(v, v, ss2);
      }
      ss += __shfl_xor(ss, 1);
      ss2 += __shfl_xor(ss2, 1);
      ss += __shfl_xor(ss, 2);
      ss2 += __shfl_xor(ss2, 2);
      ss += __shfl_xor(ss, 4);
      ss2 += __shfl_xor(ss2, 4);
      ss += __shfl_xor(ss, 8);
      ss2 += __shfl_xor(ss2, 8);
      s[m][q] = ss;
      s2[m][q] = ss2;
    }
  if (lcol == 0) {
#pragma unroll
    for (int m = 0; m < 2; ++m)
#pragma unroll
      for (int q = 0; q < 4; ++q) {
        st_s[m * 16 + kg * 4 + q][w] = s[m][q];
        st_s2[m * 16 + kg * 4 + q][w] = s2[m][q];
      }
  }
  __syncthreads();
#pragma unroll
  for (int m = 0; m < 2; ++m)
#pragma unroll
    for (int q = 0; q < 4; ++q) {
      int row = m * 16 + kg * 4 + q;
      float4 a4 = *reinterpret_cast<const float4*>(&st_s[row][0]);
      float4 b4 = *reinterpret_cast<const float4*>(&st_s2[row][0]);
      float S = (a4.x + a4.y) + (a4.z + a4.w);
      float S2 = (b4.x + b4.y) + (b4.z + b4.w);
      float mean = S * (1.f / 256.f);
      float var = S2 * (1.f / 256.f) - mean * mean;
      float inv = rsqrtf(var + LN_EPS);
#pragma unroll
      for (int n = 0; n < 4; ++n) {
        int c = w * 64 + n * 16 + lcol;
        float o = (val[m][n][q] - mean) * inv * g[c] + bta[c];
        long addr = (long)(row0 + row) * 256 + c;
        xout[addr] = o;
        x16out[addr] = f2bf(o);
      }
    }
}

// ---------------------------------------------------------------------------
// MFMA windowed attention. One block per (b,k,r) (grid 2048, XCD-swizzled).
// Q from x16 (bf16) + pos.  S = Q@K'^T (K' b128 from global ktp); cross-wave
// softmax; P transposed into LDS; O = P@V (V^T b128 from ktv).  O bf16.
// ---------------------------------------------------------------------------
__global__ __launch_bounds__(256) void attn_kernel(
    const short* __restrict__ x16, const short* __restrict__ ktp,
    const short* __restrict__ ktv, const float* __restrict__ pos,
    short* __restrict__ o) {
  __shared__ short Q_s[32][264];
  __shared__ short P_s[32][264];
  __shared__ float st_mx[32][4];
  __shared__ float st_sm[32][4];
  int h = blockIdx.x;
  int xcd = h & 7, jj = h >> 3;
  int sidx = xcd * 8 + (jj >> 5);
  int r = jj & 31;
  int b = sidx & 15, k = sidx >> 4;
  int tid = threadIdx.x;
  int w = tid >> 6, lane = tid & 63, lcol = lane & 15, kg = lane >> 4;
  const float scale = 0.0625f;  // 1/sqrt(256)

  // ---- stage Q = bf16((x + pos) * scale) from x16 ----
  const short* xb = x16 + ((long)b * NTOK + r * 32) * HID;
  const float* pq = pos + (long)r * 32 * HID;
#pragma unroll
  for (int p = 0; p < 4; ++p) {
    int f = p * 256 + tid;
    int row = f >> 5, c8 = (f & 31) << 3;
    short8 xv = *reinterpret_cast<const short8*>(&xb[row * HID + c8]);
    float4 p0 = *reinterpret_cast<const float4*>(&pq[row * HID + c8]);
    float4 p1 = *reinterpret_cast<const float4*>(&pq[row * HID + c8 + 4]);
    short8 s;
    s[0] = f2bf((bf2f(xv[0]) + p0.x) * scale);
    s[1] = f2bf((bf2f(xv[1]) + p0.y) * scale);
    s[2] = f2bf((bf2f(xv[2]) + p0.z) * scale);
    s[3] = f2bf((bf2f(xv[3]) + p0.w) * scale);
    s[4] = f2bf((bf2f(xv[4]) + p1.x) * scale);
    s[5] = f2bf((bf2f(xv[5]) + p1.y) * scale);
    s[6] = f2bf((bf2f(xv[6]) + p1.z) * scale);
    s[7] = f2bf((bf2f(xv[7]) + p1.w) * scale);
    *reinterpret_cast<short8*>(&Q_s[row][c8]) = s;
  }
  __syncthreads();

  int r0 = max(r - 3, 0), r1 = min(r + 3, 31);
  int nkr = r1 - r0 + 1, nm = nkr * 32;
  const short* ktpb = ktp + ((long)(k * BATCH + b)) * NTOK * HID;
  const short* ktvb = ktv + ((long)(k * BATCH + b)) * NTOK * HID;

  // ---- S phase ----
  floatx4 acc[2][4];
#pragma unroll
  for (int m = 0; m < 2; ++m)
#pragma unroll
    for (int n = 0; n < 4; ++n) acc[m][n] = (floatx4){0.f, 0.f, 0.f, 0.f};

  int tokn[4];
#pragma unroll
  for (int n = 0; n < 4; ++n) {
    int nf = w * 4 + n;
    int krow = min(r0 + (nf >> 1), 31);
    tokn[n] = krow * 32 + ((nf & 1) << 4) + lcol;
  }
#pragma unroll
  for (int s = 0; s < 8; ++s) {
    short8 af0 = *reinterpret_cast<const short8*>(&Q_s[lcol][s * 32 + kg * 8]);
    short8 af1 =
        *reinterpret_cast<const short8*>(&Q_s[16 + lcol][s * 32 + kg * 8]);
#pragma unroll
    for (int n = 0; n < 4; ++n) {
      short8 bfr = *reinterpret_cast<const short8*>(
          &ktpb[(long)tokn[n] * HID + s * 32 + kg * 8]);
      acc[0][n] =
          __builtin_amdgcn_mfma_f32_16x16x32_bf16(af0, bfr, acc[0][n], 0, 0, 0);
      acc[1][n] =
          __builtin_amdgcn_mfma_f32_16x16x32_bf16(af1, bfr, acc[1][n], 0, 0, 0);
    }
  }

  // ---- softmax ----
  const float NEG = -3.0e38f;
  float mx[2][4];
#pragma unroll
  for (int m = 0; m < 2; ++m)
#pragma unroll
    for (int q = 0; q < 4; ++q) {
      int rr = m * 16 + kg * 4 + q;
      float vmax = NEG;
#pragma unroll
      for (int n = 0; n < 4; ++n) {
        int col = (w * 4 + n) * 16 + lcol;
        int ck = col & 31;
        bool ok = (col < nm) && (ck - rr <= 3) && (rr - ck <= 3);
        float v = ok ? acc[m][n][q] : NEG;
        acc[m][n][q] = v;
        vmax = fmaxf(vmax, v);
      }
      vmax = fmaxf(vmax, __shfl_xor(vmax, 1));
      vmax = fmaxf(vmax, __shfl_xor(vmax, 2));
      vmax = fmaxf(vmax, __shfl_xor(vmax, 4));
      vmax = fmaxf(vmax, __shfl_xor(vmax, 8));
      mx[m][q] = vmax;
    }
  if (lcol == 0) {
#pragma unroll
    for (int m = 0; m < 2; ++m)
#pragma unroll
      for (int q = 0; q < 4; ++q) st_mx[m * 16 + kg * 4 + q][w] = mx[m][q];
  }
  __syncthreads();
  float sm[2][4];
#pragma unroll
  for (int m = 0; m < 2; ++m)
#pragma unroll
    for (int q = 0; q < 4; ++q) {
      int rr = m * 16 + kg * 4 + q;
      float4 v4 = *reinterpret_cast<const float4*>(&st_mx[rr][0]);
      float g = fmaxf(fmaxf(v4.x, v4.y), fmaxf(v4.z, v4.w));
      float ss = 0.f;
#pragma unroll
      for (int n = 0; n < 4; ++n) {
        float v = acc[m][n][q];
        float pv = (v > -1.0e30f) ? exp2f((v - g) * 1.4426950408889634f) : 0.f;
        acc[m][n][q] = pv;
        ss += pv;
      }
      ss += __shfl_xor(ss, 1);
      ss += __shfl_xor(ss, 2);
      ss += __shfl_xor(ss, 4);
      ss += __shfl_xor(ss, 8);
      sm[m][q] = ss;
    }
  if (lcol == 0) {
#pragma unroll
    for (int m = 0; m < 2; ++m)
#pragma unroll
      for (int q = 0; q < 4; ++q) st_sm[m * 16 + kg * 4 + q][w] = sm[m][q];
  }
  __syncthreads();
#pragma unroll
  for (int m = 0; m < 2; ++m)
#pragma unroll
    for (int q = 0; q < 4; ++q) {
      int rr = m * 16 + kg * 4 + q;
      float4 v4 = *reinterpret_cast<const float4*>(&st_sm[rr][0]);
      float rinv = 1.0f / (v4.x + v4.y + v4.z + v4.w);
#pragma unroll
      for (int n = 0; n < 4; ++n) {
        P_s[rr][(w * 4 + n) * 16 + lcol] = f2bf(acc[m][n][q] * rinv);
      }
    }
  __syncthreads();

  // ---- PV ----
  floatx4 oacc[2][4];
#pragma unroll
  for (int m = 0; m < 2; ++m)
#pragma unroll
    for (int n = 0; n < 4; ++n) oacc[m][n] = (floatx4){0.f, 0.f, 0.f, 0.f};

  for (int kb = 0; kb < nkr; ++kb) {
    short8 ap0 = *reinterpret_cast<const short8*>(&P_s[lcol][kb * 32 + kg * 8]);
    short8 ap1 =
        *reinterpret_cast<const short8*>(&P_s[16 + lcol][kb * 32 + kg * 8]);
    int tokb = (r0 + kb) * 32;
#pragma unroll
    for (int n = 0; n < 4; ++n) {
      int ch = w * 64 + n * 16 + lcol;
      short8 bv = *reinterpret_cast<const short8*>(
          &ktvb[(long)ch * NTOK + tokb + kg * 8]);
      oacc[0][n] =
          __builtin_amdgcn_mfma_f32_16x16x32_bf16(ap0, bv, oacc[0][n], 0, 0, 0);
      oacc[1][n] =
          __builtin_amdgcn_mfma_f32_16x16x32_bf16(ap1, bv, oacc[1][n], 0, 0, 0);
    }
  }
#pragma unroll
  for (int m = 0; m < 2; ++m)
#pragma unroll
    for (int n = 0; n < 4; ++n) {
      int ch = w * 64 + n * 16 + lcol;
#pragma unroll
      for (int q = 0; q < 4; ++q) {
        int rr = m * 16 + kg * 4 + q;
        o[((long)b * NTOK + r * 32 + rr) * (KMEM * HID) + k * HID + ch] =
            f2bf(oacc[m][n][q]);
      }
    }
}

// ---------------------------------------------------------------------------
// recon_tokens (b,t,272) -> recon (b,272,32,32) + pred_sq
// ---------------------------------------------------------------------------
__global__ __launch_bounds__(256) void recon_out_kernel(
    const float* __restrict__ rt, const float* __restrict__ qf,
    float* __restrict__ recon, float* __restrict__ pred_sq) {
  int b = blockIdx.y;
  int t0 = blockIdx.x * 32;
  __shared__ float tile[32][33];
  int lx = threadIdx.x & 31;
  int ly = threadIdx.x >> 5;
  float sq = 0.f;
  for (int c0 = 0; c0 < DIN; c0 += 32) {
    __syncthreads();
#pragma unroll
    for (int i = 0; i < 4; i++) {
      int tt = ly + i * 8;
      int c = c0 + lx;
      tile[tt][lx] = (c < DIN) ? rt[((long)b * NTOK + t0 + tt) * DIN + c] : 0.f;
    }
    __syncthreads();
#pragma unroll
    for (int i = 0; i < 4; i++) {
      int c = c0 + ly + i * 8;
      if (c < DIN) {
        float v = tile[lx][ly + i * 8];
        long gaddr = ((long)b * DIN + c) * NTOK + t0 + lx;
        float q = qf[gaddr];
        recon[gaddr] = v;
        float d = v - q;
        sq = fmaf(d, d, sq);
      }
    }
  }
  __shared__ float red[8][33];
  red[ly][lx] = sq;
  __syncthreads();
  if (ly == 0) {
    float s = 0.f;
#pragma unroll
    for (int u = 0; u < 8; u++) s += red[u][lx];
    pred_sq[b * NTOK + t0 + lx] = s;
  }
}

__global__ __launch_bounds__(256) void minmax_kernel(
    const float* __restrict__ pred_sq, float* __restrict__ mnmx) {
  int tid = threadIdx.x;
  float mn = INFINITY, mx = -INFINITY;
  for (int i = tid; i < BATCH * NTOK; i += 256) {
    float v = sqrtf(pred_sq[i]);
    mn = fminf(mn, v);
    mx = fmaxf(mx, v);
  }
#pragma unroll
  for (int off = 32; off > 0; off >>= 1) {
    mn = fminf(mn, __shfl_xor(mn, off));
    mx = fmaxf(mx, __shfl_xor(mx, off));
  }
  __shared__ float smn[4], smx[4];
  int wave = tid >> 6, lane = tid & 63;
  if (lane == 0) {
    smn[wave] = mn;
    smx[wave] = mx;
  }
  __syncthreads();
  if (tid == 0) {
    mn = fminf(fminf(smn[0], smn[1]), fminf(smn[2], smn[3]));
    mx = fmaxf(fmaxf(smx[0], smx[1]), fmaxf(smx[2], smx[3]));
    mnmx[0] = mn;
    mnmx[1] = mx;
  }
}

__global__ __launch_bounds__(256) void resize_kernel(
    const float* __restrict__ pred_sq, const float* __restrict__ mnmx,
    float* __restrict__ out) {
  long idx = (long)blockIdx.x * 256 + threadIdx.x;
  if (idx >= (long)BATCH * 256 * 256) return;
  int b = (int)(idx >> 16);
  int oy = (int)((idx >> 8) & 255), ox = (int)(idx & 255);
  float mn = mnmx[0], mx = mnmx[1];
  float inv = 1.0f / (mx - mn);
  float ys = oy * (31.0f / 255.0f);
  int y0 = (int)floorf(ys);
  int y1 = min(y0 + 1, 31);
  float fy = ys - (float)y0;
  float xs = ox * (31.0f / 255.0f);
  int x0 = (int)floorf(xs);
  int x1 = min(x0 + 1, 31);
  float fx = xs - (float)x0;
  const float* p = pred_sq + b * NTOK;
  float v00 = sqrtf(p[y0 * 32 + x0]), v01 = sqrtf(p[y0 * 32 + x1]);
  float v10 = sqrtf(p[y1 * 32 + x0]), v11 = sqrtf(p[y1 * 32 + x1]);
  float cA = v00 * (1.f - fy) + v10 * fy;
  float cB = v01 * (1.f - fy) + v11 * fy;
  float v = cA * (1.f - fx) + cB * fx;
  out[idx] = (v - mn) * inv;
}

// ---------------------------------------------------------------------------
extern "C" void kernel_launch(void* const* d_in, const int* in_sizes, int n_in,
                              void* d_out, int out_size, void* d_ws,
                              size_t ws_size, hipStream_t stream) {
  const float* qf = (const float*)d_in[0];
  const float* mf = (const float*)d_in[1];
  const float* qW = (const float*)d_in[2];
  const float* qb = (const float*)d_in[3];
  const float* kvW = (const float*)d_in[4];
  const float* kvb = (const float*)d_in[5];
  const float* row_e = (const float*)d_in[6];
  const float* col_e = (const float*)d_in[7];
  const float* aggW = (const float*)d_in[8];
  const float* aggb = (const float*)d_in[9];
  const float* n1g = (const float*)d_in[10];
  const float* n1b = (const float*)d_in[11];
  const float* l1W = (const float*)d_in[12];
  const float* l1b = (const float*)d_in[13];
  const float* l2W = (const float*)d_in[14];
  const float* l2b = (const float*)d_in[15];
  const float* n2g = (const float*)d_in[16];
  const float* n2b = (const float*)d_in[17];
  const float* outW = (const float*)d_in[18];
  const float* outb = (const float*)d_in[19];

  float* out = (float*)d_out;
  float* recon = out;                            // 16*272*1024
  float* pred = out + (long)BATCH * DIN * NTOK;  // 16*256*256

  // bf16 transposed weights stashed in d_out recon region,
  // fully consumed before recon_out_kernel overwrites it at the end.
  short* wt = (short*)d_out;
  short* wt_agg0 = wt;                  // [256][1024]
  short* wt_agg1 = wt_agg0 + 262144;    // [256][1024]
  short* wt_l1_0 = wt_agg1 + 262144;    // [1024][256]
  short* wt_l1_1 = wt_l1_0 + 262144;    // [1024][256]
  short* wt_l2_0 = wt_l1_1 + 262144;    // [256][1024]
  short* wt_l2_1 = wt_l2_0 + 262144;    // [256][1024]
  short* wt_out = wt_l2_1 + 262144;     // [272][256]
  short* wt_q = wt_out + 69632;         // [256][288]
  short* wt_kv = wt_q + 73728;          // [256][288]

  // workspace layout
  float* ws = (float*)d_ws;
  float* pos = ws;                              // 262144 f   (1MB)
  float* x = pos + 262144;                      // 4194304 f  (16MB)
  short* x16 = (short*)(x + 4194304);           // 4194304 s  (8MB)
  short* ktp = x16 + 4194304;                   // 16777216 s (32MB)
  short* ktv = ktp + 16777216;                  // 16777216 s (32MB)
  short* buf16 = ktv + 16777216;                // 16777216 s (32MB)
  float* tmp256 = (float*)(buf16 + 16777216);   // 4194304 f  (16MB, spill only)
  float* rtbuf = tmp256 + 4194304;              // 4456448 f  (17.8MB)
  float* pred_sq = rtbuf + 4456448;             // 16384 f
  float* mnmx = pred_sq + 16384;                // 2 f
  // transient aliases (consumed before their hosts are first written):
  short* qf_t = ktp;    // [16384][288] bf16 (9.4MB; consumed by qproj
                        //   before kvproj writes ktp)
  short* mf_t = buf16;  // [65536][288] bf16 (37.7MB, spills into tmp256;
                        //   consumed by kvproj before attn writes buf16)

  pos_kernel<<<NTOK, 256, 0, stream>>>(row_e, col_e, pos);

  // all weight transposes in one dispatch
  {
    WtJobs jobs;
    jobs.j[0] = {aggW, wt_agg0, 1024, 1024, 256, 8, 0};
    jobs.j[1] = {aggW + 262144, wt_agg1, 1024, 1024, 256, 8, 256};
    jobs.j[2] = {l1W, wt_l1_0, 256, 256, 1024, 32, 512};
    jobs.j[3] = {l1W + 262144, wt_l1_1, 256, 256, 1024, 32, 768};
    jobs.j[4] = {l2W, wt_l2_0, 1024, 1024, 256, 8, 1024};
    jobs.j[5] = {l2W + 262144, wt_l2_1, 1024, 1024, 256, 8, 1280};
    jobs.j[6] = {outW, wt_out, 256, 256, 272, 9, 1536};
    jobs.j[7] = {qW, wt_q, 272, 288, 256, 8, 1608};
    jobs.j[8] = {kvW, wt_kv, 272, 288, 256, 8, 1680};
    wt_cvt_all_kernel<<<1752, 256, 0, stream>>>(jobs);
  }

  // q path first (qf_t aliases ktp; consumed before kvproj writes ktp)
  tcvt_kernel<<<dim3(512, 9), 256, 0, stream>>>(qf, qf_t);
  gemm2_kernel<3><<<512, 256, 0, stream>>>(qf_t, wt_q, qb, x, x16,
                                           BATCH * NTOK, HID, DINP, 2, nullptr,
                                           nullptr, nullptr);
  // kv path
  tcvt_kernel<<<dim3(2048, 9), 256, 0, stream>>>(mf, mf_t);
  gemm2_kernel<2><<<2048, 256, 0, stream>>>(mf_t, wt_kv, kvb, nullptr, nullptr,
                                            KMEM * BATCH * NTOK, HID, DINP, 2,
                                            ktp, ktv, pos);

  for (int l = 0; l < 2; l++) {
    attn_kernel<<<2048, 256, 0, stream>>>(x16, ktp, ktv, pos, buf16);
    // agg + LN1 fused: buf16 @ wt_agg + aggb + x -> LN -> x, x16
    gemm_ln_kernel<<<512, 256, 0, stream>>>(
        buf16, l ? wt_agg1 : wt_agg0, aggb + l * 256, x, n1g + l * 256,
        n1b + l * 256, x, x16, KMEM * HID);
    // ff1: x16 @ wt_l1 -> relu bf16 buf16
    gemm2_kernel<1><<<2048, 256, 0, stream>>>(
        x16, l ? wt_l1_1 : wt_l1_0, l1b + l * 1024, nullptr, buf16,
        BATCH * NTOK, DFF, HID, 8, nullptr, nullptr, nullptr);
    // ff2 + LN2 fused: buf16 @ wt_l2 + l2b + x -> LN -> x, x16
    gemm_ln_kernel<<<512, 256, 0, stream>>>(
        buf16, l ? wt_l2_1 : wt_l2_0, l2b + l * 256, x, n2g + l * 256,
        n2b + l * 256, x, x16, DFF);
  }

  // out projection: x16 @ wt_out -> rtbuf fp32 (N=272 guarded)
  gemm2_kernel<0><<<768, 256, 0, stream>>>(x16, wt_out, outb, rtbuf, nullptr,
                                           BATCH * NTOK, DIN, HID, 3, nullptr,
                                           nullptr, nullptr);
  {
    dim3 grid(NTOK / 32, BATCH);
    recon_out_kernel<<<grid, 256, 0, stream>>>(rtbuf, qf, recon, pred_sq);
  }
  minmax_kernel<<<1, 256, 0, stream>>>(pred_sq, mnmx);
  resize_kernel<<<(BATCH * 256 * 256) / 256, 256, 0, stream>>>(pred_sq, mnmx,
                                                               pred);
}

// Round 8
// 420.686 us; speedup vs baseline: 5.8418x; 1.0562x over previous
//
#include <hip/hip_runtime.h>
#include <hip/hip_bf16.h>
#include <math.h>

// Problem constants
#define BATCH 16
#define NTOK 1024      // 32*32
#define HID 256
#define KMEM 4
#define DIN 272
#define DINP 288       // DIN zero-padded to /32
#define DFF 1024
#define LN_EPS 1e-5f

using short8 = __attribute__((ext_vector_type(8))) short;
using short4v = __attribute__((ext_vector_type(4))) short;
using floatx4 = __attribute__((ext_vector_type(4))) float;

__device__ inline short f2bf(float f) {
  unsigned u = __builtin_bit_cast(unsigned, f);
  u += 0x7fff + ((u >> 16) & 1);  // RNE
  return (short)(u >> 16);
}
__device__ inline float bf2f(short s) {
  unsigned u = ((unsigned)(unsigned short)s) << 16;
  return __builtin_bit_cast(float, u);
}

// ---------------------------------------------------------------------------
// pos embed: pos[t][j] = j<128 ? col_embed[t%32][j] : row_embed[t/32][j-128]
// ---------------------------------------------------------------------------
__global__ __launch_bounds__(256) void pos_kernel(
    const float* __restrict__ row_e, const float* __restrict__ col_e,
    float* __restrict__ pos) {
  int t = blockIdx.x;
  int j = threadIdx.x;
  float v = (j < 128) ? col_e[(t & 31) * 128 + j]
                      : row_e[(t >> 5) * 128 + (j - 128)];
  pos[t * 256 + j] = v;
}

// ---------------------------------------------------------------------------
// Activation transpose+cvt for BOTH qf and mf in one dispatch.
// slices 0..15 -> qf, 16..79 -> mf.  fp32 [272][1024] -> bf16 [1024][288].
// ---------------------------------------------------------------------------
__global__ __launch_bounds__(256) void tcvt_kernel(
    const float* __restrict__ qf, const float* __restrict__ mf,
    short* __restrict__ qf_t, short* __restrict__ mf_t) {
  __shared__ short tile[32][33];
  int slice = blockIdx.x >> 5;
  int t0 = (blockIdx.x & 31) * 32;
  int c0 = blockIdx.y * 32;
  int tx = threadIdx.x & 31, ty = threadIdx.x >> 5;
  const float* s;
  short* d;
  if (slice < 16) {
    s = qf + (long)slice * DIN * NTOK;
    d = qf_t + (long)slice * NTOK * DINP;
  } else {
    s = mf + (long)(slice - 16) * DIN * NTOK;
    d = mf_t + (long)(slice - 16) * NTOK * DINP;
  }
#pragma unroll
  for (int i = 0; i < 4; i++) {
    int c = c0 + ty + i * 8;
    float v = (c < DIN) ? s[(long)c * NTOK + t0 + tx] : 0.f;
    tile[ty + i * 8][tx] = f2bf(v);
  }
  __syncthreads();
  d += (long)t0 * DINP + c0;
#pragma unroll
  for (int i = 0; i < 4; i++) {
    int tl = ty + i * 8;
    d[(long)tl * DINP + tx] = tile[tx][tl];
  }
}

// ---------------------------------------------------------------------------
// All weight transposes+cvt in ONE dispatch.  W[K][N] fp32 -> Wt[N][Kd] bf16.
// ---------------------------------------------------------------------------
struct WtJob {
  const float* src;
  short* dst;
  int K, Kd, N, ntx, start;
};
struct WtJobs {
  WtJob j[9];
};

__global__ __launch_bounds__(256) void wt_cvt_all_kernel(WtJobs jobs) {
  __shared__ short tile[32][33];
  int bid = blockIdx.x;
  int ji = 0;
#pragma unroll
  for (int i = 1; i < 9; ++i)
    if (bid >= jobs.j[i].start) ji = i;
  const float* W = jobs.j[ji].src;
  short* Wt = jobs.j[ji].dst;
  int K = jobs.j[ji].K, Kd = jobs.j[ji].Kd, N = jobs.j[ji].N;
  int local = bid - jobs.j[ji].start;
  int n0 = (local % jobs.j[ji].ntx) * 32;
  int k0 = (local / jobs.j[ji].ntx) * 32;
  int tx = threadIdx.x & 31, ty8 = threadIdx.x >> 5;
#pragma unroll
  for (int i = 0; i < 4; i++) {
    int k = k0 + ty8 + i * 8;
    int n = n0 + tx;
    float v = (k < K && n < N) ? W[(long)k * N + n] : 0.f;
    tile[ty8 + i * 8][tx] = f2bf(v);
  }
  __syncthreads();
#pragma unroll
  for (int i = 0; i < 4; i++) {
    int n = n0 + ty8 + i * 8;
    int k = k0 + tx;
    if (n < N && k < Kd) Wt[(long)n * Kd + k] = tile[tx][ty8 + i * 8];
  }
}

// ---------------------------------------------------------------------------
// Unified MFMA bf16 GEMM with 2-phase prefetch pipeline.
// A bf16 [M][K], Wt bf16 [N][K].  Tile 64x128, BK=32, 4 waves.
// OUTMODE 0: Cf fp32.  OUTMODE 1: Cs bf16 relu.  OUTMODE 3: Cf fp32 + Cs bf16.
// OUTMODE 2: kv projection (N==256): ktp = bf16(val+pos); ktv = V^T bf16.
// OUTMODE 4: out projection: write recon[b][c][t] (transposed) + per-token
//            squared-error partials vs qf (pred_part[cx][row]).
// ---------------------------------------------------------------------------
template <int OUTMODE>
__global__ __launch_bounds__(256) void gemm2_kernel(
    const short* __restrict__ A, const short* __restrict__ Wt,
    const float* __restrict__ bias, float* __restrict__ Cf,
    short* __restrict__ Cs, int M, int N, int K, int gxn,
    short* __restrict__ ktp, short* __restrict__ ktv,
    const float* __restrict__ pos, const float* __restrict__ qfp,
    float* __restrict__ ppart) {
  __shared__ short As[2][64][40];
  __shared__ short Bs[2][128][40];
  __shared__ float part_s[64][2];
  int nwg = gridDim.x;
  int cpx = nwg >> 3;
  int bid = blockIdx.x;
  int h = (bid & 7) * cpx + (bid >> 3);
  int cx = h % gxn;
  int ry = h / gxn;
  int row0 = ry * 64, col0 = cx * 128;
  int tid = threadIdx.x;
  int w = tid >> 6, lane = tid & 63;
  int wrow = (w >> 1) * 32, wcol = (w & 1) * 64;
  int lcol = lane & 15, kg = lane >> 4;

  int arow = tid >> 2, ak = (tid & 3) * 8;
  int brow = tid >> 2, bk = (tid & 3) * 8;
  const short* Ab = A + (long)row0 * K;
  const short* Bb = Wt + (long)col0 * K;
  bool bv0 = (col0 + brow) < N;
  bool bv1 = (col0 + brow + 64) < N;

  const short8 z8 = (short8){0, 0, 0, 0, 0, 0, 0, 0};
  short8 ra, rb0, rb1;
  ra = *reinterpret_cast<const short8*>(&Ab[(long)arow * K + ak]);
  rb0 = bv0 ? *reinterpret_cast<const short8*>(&Bb[(long)brow * K + bk]) : z8;
  rb1 = bv1 ? *reinterpret_cast<const short8*>(&Bb[(long)(brow + 64) * K + bk])
            : z8;
  *reinterpret_cast<short8*>(&As[0][arow][ak]) = ra;
  *reinterpret_cast<short8*>(&Bs[0][brow][bk]) = rb0;
  *reinterpret_cast<short8*>(&Bs[0][brow + 64][bk]) = rb1;
  __syncthreads();

  floatx4 acc[2][4];
#pragma unroll
  for (int m = 0; m < 2; ++m)
#pragma unroll
    for (int n = 0; n < 4; ++n) acc[m][n] = (floatx4){0.f, 0.f, 0.f, 0.f};

  int NT = K >> 5;
  for (int t = 0; t < NT; ++t) {
    int cur = t & 1;
    if (t + 1 < NT) {
      int ko = (t + 1) << 5;
      ra = *reinterpret_cast<const short8*>(&Ab[(long)arow * K + ko + ak]);
      rb0 = bv0 ? *reinterpret_cast<const short8*>(&Bb[(long)brow * K + ko + bk])
                : z8;
      rb1 = bv1 ? *reinterpret_cast<const short8*>(
                      &Bb[(long)(brow + 64) * K + ko + bk])
                : z8;
    }
    short8 af[2], bf[4];
#pragma unroll
    for (int m = 0; m < 2; ++m)
      af[m] = *reinterpret_cast<const short8*>(
          &As[cur][wrow + m * 16 + lcol][kg * 8]);
#pragma unroll
    for (int n = 0; n < 4; ++n)
      bf[n] = *reinterpret_cast<const short8*>(
          &Bs[cur][wcol + n * 16 + lcol][kg * 8]);
#pragma unroll
    for (int m = 0; m < 2; ++m)
#pragma unroll
      for (int n = 0; n < 4; ++n)
        acc[m][n] = __builtin_amdgcn_mfma_f32_16x16x32_bf16(af[m], bf[n],
                                                            acc[m][n], 0, 0, 0);
    if (t + 1 < NT) {
      int nxt = cur ^ 1;
      *reinterpret_cast<short8*>(&As[nxt][arow][ak]) = ra;
      *reinterpret_cast<short8*>(&Bs[nxt][brow][bk]) = rb0;
      *reinterpret_cast<short8*>(&Bs[nxt][brow + 64][bk]) = rb1;
    }
    __syncthreads();
  }

  if (OUTMODE == 4) {
    // transposed recon write + squared-error partials
    int bb = row0 >> 10;
    int tb0 = (row0 & 1023) + wrow;
    float sqp[2][4] = {};
#pragma unroll
    for (int n = 0; n < 4; ++n) {
      int c = col0 + wcol + n * 16 + lcol;
      if (c < N) {
        float bv = bias[c];
#pragma unroll
        for (int m = 0; m < 2; ++m) {
          int tb = tb0 + m * 16 + kg * 4;
          long addr = ((long)bb * DIN + c) * 1024 + tb;
          float4 qv = *reinterpret_cast<const float4*>(&qfp[addr]);
          float4 ov;
          float v0 = acc[m][n][0] + bv;
          float v1 = acc[m][n][1] + bv;
          float v2 = acc[m][n][2] + bv;
          float v3 = acc[m][n][3] + bv;
          ov.x = v0;
          ov.y = v1;
          ov.z = v2;
          ov.w = v3;
          float d0 = v0 - qv.x, d1 = v1 - qv.y, d2 = v2 - qv.z, d3 = v3 - qv.w;
          sqp[m][0] = fmaf(d0, d0, sqp[m][0]);
          sqp[m][1] = fmaf(d1, d1, sqp[m][1]);
          sqp[m][2] = fmaf(d2, d2, sqp[m][2]);
          sqp[m][3] = fmaf(d3, d3, sqp[m][3]);
          *reinterpret_cast<float4*>(&Cf[addr]) = ov;
        }
      }
    }
#pragma unroll
    for (int m = 0; m < 2; ++m)
#pragma unroll
      for (int q = 0; q < 4; ++q) {
        float s = sqp[m][q];
        s += __shfl_xor(s, 1);
        s += __shfl_xor(s, 2);
        s += __shfl_xor(s, 4);
        s += __shfl_xor(s, 8);
        if (lcol == 0) part_s[wrow + m * 16 + kg * 4 + q][w & 1] = s;
      }
    __syncthreads();
    if (tid < 64)
      ppart[(long)cx * 16384 + row0 + tid] = part_s[tid][0] + part_s[tid][1];
    return;
  }

#pragma unroll
  for (int n = 0; n < 4; ++n) {
    int c = col0 + wcol + n * 16 + lcol;
    if (c >= N) continue;
    float bv = bias[c];
#pragma unroll
    for (int m = 0; m < 2; ++m) {
      int rbase = row0 + wrow + m * 16 + kg * 4;
      if (OUTMODE == 0) {
#pragma unroll
        for (int q = 0; q < 4; ++q)
          Cf[(long)(rbase + q) * N + c] = acc[m][n][q] + bv;
      } else if (OUTMODE == 1) {
#pragma unroll
        for (int q = 0; q < 4; ++q)
          Cs[(long)(rbase + q) * N + c] = f2bf(fmaxf(acc[m][n][q] + bv, 0.f));
      } else if (OUTMODE == 3) {
#pragma unroll
        for (int q = 0; q < 4; ++q) {
          float val = acc[m][n][q] + bv;
          Cf[(long)(rbase + q) * N + c] = val;
          Cs[(long)(rbase + q) * N + c] = f2bf(val);
        }
      } else {
        int slice = rbase >> 10, tbase = rbase & 1023;
        short4v vt;
#pragma unroll
        for (int q = 0; q < 4; ++q) {
          float val = acc[m][n][q] + bv;
          vt[q] = f2bf(val);
          ktp[(long)(rbase + q) * 256 + c] =
              f2bf(val + pos[(tbase + q) * 256 + c]);
        }
        *reinterpret_cast<short4v*>(
            &ktv[(long)slice * (256 * 1024) + (long)c * 1024 + tbase]) = vt;
      }
    }
  }
}

// ---------------------------------------------------------------------------
// MFMA GEMM + fused residual + LayerNorm epilogue.
// A bf16 [M][K] @ Wt bf16 [256][K] + bias + res(fp32) -> LN -> xout + x16out.
// Tile 32x256 (full row), BK=32, 4 waves, 2-phase pipeline.  Grid = M/32.
// ---------------------------------------------------------------------------
__global__ __launch_bounds__(256) void gemm_ln_kernel(
    const short* __restrict__ A, const short* __restrict__ Wt,
    const float* __restrict__ bias, const float* __restrict__ res,
    const float* __restrict__ g, const float* __restrict__ bta,
    float* __restrict__ xout, short* __restrict__ x16out, int K) {
  __shared__ short As[2][32][40];
  __shared__ short Bs[2][256][40];
  __shared__ float st_s[32][4];
  __shared__ float st_s2[32][4];
  int tid = threadIdx.x;
  int row0 = blockIdx.x * 32;
  int w = tid >> 6, lane = tid & 63, lcol = lane & 15, kg = lane >> 4;
  int arow = tid >> 2, ak = (tid & 3) * 8;  // tid<128 stages A
  int brow = tid >> 2, bk = (tid & 3) * 8;  // rows brow + i*64
  const short* Ab = A + (long)row0 * K;

  short8 ra, rb[4];
  if (tid < 128) ra = *reinterpret_cast<const short8*>(&Ab[(long)arow * K + ak]);
#pragma unroll
  for (int i = 0; i < 4; ++i)
    rb[i] = *reinterpret_cast<const short8*>(&Wt[(long)(brow + i * 64) * K + bk]);
  if (tid < 128) *reinterpret_cast<short8*>(&As[0][arow][ak]) = ra;
#pragma unroll
  for (int i = 0; i < 4; ++i)
    *reinterpret_cast<short8*>(&Bs[0][brow + i * 64][bk]) = rb[i];
  __syncthreads();

  floatx4 acc[2][4];
#pragma unroll
  for (int m = 0; m < 2; ++m)
#pragma unroll
    for (int n = 0; n < 4; ++n) acc[m][n] = (floatx4){0.f, 0.f, 0.f, 0.f};

  int NT = K >> 5;
  for (int t = 0; t < NT; ++t) {
    int cur = t & 1;
    if (t + 1 < NT) {
      int ko = (t + 1) << 5;
      if (tid < 128)
        ra = *reinterpret_cast<const short8*>(&Ab[(long)arow * K + ko + ak]);
#pragma unroll
      for (int i = 0; i < 4; ++i)
        rb[i] = *reinterpret_cast<const short8*>(
            &Wt[(long)(brow + i * 64) * K + ko + bk]);
    }
    short8 af[2], bf[4];
#pragma unroll
    for (int m = 0; m < 2; ++m)
      af[m] =
          *reinterpret_cast<const short8*>(&As[cur][m * 16 + lcol][kg * 8]);
#pragma unroll
    for (int n = 0; n < 4; ++n)
      bf[n] = *reinterpret_cast<const short8*>(
          &Bs[cur][w * 64 + n * 16 + lcol][kg * 8]);
#pragma unroll
    for (int m = 0; m < 2; ++m)
#pragma unroll
      for (int n = 0; n < 4; ++n)
        acc[m][n] = __builtin_amdgcn_mfma_f32_16x16x32_bf16(af[m], bf[n],
                                                            acc[m][n], 0, 0, 0);
    if (t + 1 < NT) {
      int nxt = cur ^ 1;
      if (tid < 128) *reinterpret_cast<short8*>(&As[nxt][arow][ak]) = ra;
#pragma unroll
      for (int i = 0; i < 4; ++i)
        *reinterpret_cast<short8*>(&Bs[nxt][brow + i * 64][bk]) = rb[i];
    }
    __syncthreads();
  }

  // epilogue: val = acc + bias + residual, then LN over the 256-wide row
  float val[2][4][4];
#pragma unroll
  for (int n = 0; n < 4; ++n) {
    int c = w * 64 + n * 16 + lcol;
    float bv = bias[c];
#pragma unroll
    for (int m = 0; m < 2; ++m) {
      int rbase = row0 + m * 16 + kg * 4;
#pragma unroll
      for (int q = 0; q < 4; ++q)
        val[m][n][q] = acc[m][n][q] + bv + res[(long)(rbase + q) * 256 + c];
    }
  }
  float s[2][4], s2[2][4];
#pragma unroll
  for (int m = 0; m < 2; ++m)
#pragma unroll
    for (int q = 0; q < 4; ++q) {
      float ss = 0.f, ss2 = 0.f;
#pragma unroll
      for (int n = 0; n < 4; ++n) {
        float v = val[m][n][q];
        ss += v;
        ss2 = fmaf(v, v, ss2);
      }
      ss += __shfl_xor(ss, 1);
      ss2 += __shfl_xor(ss2, 1);
      ss += __shfl_xor(ss, 2);
      ss2 += __shfl_xor(ss2, 2);
      ss += __shfl_xor(ss, 4);
      ss2 += __shfl_xor(ss2, 4);
      ss += __shfl_xor(ss, 8);
      ss2 += __shfl_xor(ss2, 8);
      s[m][q] = ss;
      s2[m][q] = ss2;
    }
  if (lcol == 0) {
#pragma unroll
    for (int m = 0; m < 2; ++m)
#pragma unroll
      for (int q = 0; q < 4; ++q) {
        st_s[m * 16 + kg * 4 + q][w] = s[m][q];
        st_s2[m * 16 + kg * 4 + q][w] = s2[m][q];
      }
  }
  __syncthreads();
#pragma unroll
  for (int m = 0; m < 2; ++m)
#pragma unroll
    for (int q = 0; q < 4; ++q) {
      int row = m * 16 + kg * 4 + q;
      float4 a4 = *reinterpret_cast<const float4*>(&st_s[row][0]);
      float4 b4 = *reinterpret_cast<const float4*>(&st_s2[row][0]);
      float S = (a4.x + a4.y) + (a4.z + a4.w);
      float S2 = (b4.x + b4.y) + (b4.z + b4.w);
      float mean = S * (1.f / 256.f);
      float var = S2 * (1.f / 256.f) - mean * mean;
      float inv = rsqrtf(var + LN_EPS);
#pragma unroll
      for (int n = 0; n < 4; ++n) {
        int c = w * 64 + n * 16 + lcol;
        float o = (val[m][n][q] - mean) * inv * g[c] + bta[c];
        long addr = (long)(row0 + row) * 256 + c;
        xout[addr] = o;
        x16out[addr] = f2bf(o);
      }
    }
}

// ---------------------------------------------------------------------------
// MFMA windowed attention. One block per (b,k,r) (grid 2048, XCD-swizzled).
// Q from x16 (bf16) + pos.  S = Q@K'^T (K' b128 from global ktp); cross-wave
// softmax; P transposed into LDS; O = P@V (V^T b128 from ktv).  O bf16.
// Q_s and P_s ALIAS the same LDS (Q dead after S phase; 2 barriers separate
// last Q read from first P write) -> ~19 KB LDS -> 8 blocks/CU.
// ---------------------------------------------------------------------------
__global__ __launch_bounds__(256) void attn_kernel(
    const short* __restrict__ x16, const short* __restrict__ ktp,
    const short* __restrict__ ktv, const float* __restrict__ pos,
    short* __restrict__ o) {
  __shared__ short QP_s[32][264];  // Q during S phase, P during PV phase
  __shared__ float st_mx[32][4];
  __shared__ float st_sm[32][4];
  int h = blockIdx.x;
  int xcd = h & 7, jj = h >> 3;
  int sidx = xcd * 8 + (jj >> 5);
  int r = jj & 31;
  int b = sidx & 15, k = sidx >> 4;
  int tid = threadIdx.x;
  int w = tid >> 6, lane = tid & 63, lcol = lane & 15, kg = lane >> 4;
  const float scale = 0.0625f;  // 1/sqrt(256)

  // ---- stage Q = bf16((x + pos) * scale) from x16 ----
  const short* xb = x16 + ((long)b * NTOK + r * 32) * HID;
  const float* pq = pos + (long)r * 32 * HID;
#pragma unroll
  for (int p = 0; p < 4; ++p) {
    int f = p * 256 + tid;
    int row = f >> 5, c8 = (f & 31) << 3;
    short8 xv = *reinterpret_cast<const short8*>(&xb[row * HID + c8]);
    float4 p0 = *reinterpret_cast<const float4*>(&pq[row * HID + c8]);
    float4 p1 = *reinterpret_cast<const float4*>(&pq[row * HID + c8 + 4]);
    short8 s;
    s[0] = f2bf((bf2f(xv[0]) + p0.x) * scale);
    s[1] = f2bf((bf2f(xv[1]) + p0.y) * scale);
    s[2] = f2bf((bf2f(xv[2]) + p0.z) * scale);
    s[3] = f2bf((bf2f(xv[3]) + p0.w) * scale);
    s[4] = f2bf((bf2f(xv[4]) + p1.x) * scale);
    s[5] = f2bf((bf2f(xv[5]) + p1.y) * scale);
    s[6] = f2bf((bf2f(xv[6]) + p1.z) * scale);
    s[7] = f2bf((bf2f(xv[7]) + p1.w) * scale);
    *reinterpret_cast<short8*>(&QP_s[row][c8]) = s;
  }
  __syncthreads();

  int r0 = max(r - 3, 0), r1 = min(r + 3, 31);
  int nkr = r1 - r0 + 1, nm = nkr * 32;
  const short* ktpb = ktp + ((long)(k * BATCH + b)) * NTOK * HID;
  const short* ktvb = ktv + ((long)(k * BATCH + b)) * NTOK * HID;

  // ---- S phase ----
  floatx4 acc[2][4];
#pragma unroll
  for (int m = 0; m < 2; ++m)
#pragma unroll
    for (int n = 0; n < 4; ++n) acc[m][n] = (floatx4){0.f, 0.f, 0.f, 0.f};

  int tokn[4];
#pragma unroll
  for (int n = 0; n < 4; ++n) {
    int nf = w * 4 + n;
    int krow = min(r0 + (nf >> 1), 31);
    tokn[n] = krow * 32 + ((nf & 1) << 4) + lcol;
  }
#pragma unroll
  for (int s = 0; s < 8; ++s) {
    short8 af0 = *reinterpret_cast<const short8*>(&QP_s[lcol][s * 32 + kg * 8]);
    short8 af1 =
        *reinterpret_cast<const short8*>(&QP_s[16 + lcol][s * 32 + kg * 8]);
#pragma unroll
    for (int n = 0; n < 4; ++n) {
      short8 bfr = *reinterpret_cast<const short8*>(
          &ktpb[(long)tokn[n] * HID + s * 32 + kg * 8]);
      acc[0][n] =
          __builtin_amdgcn_mfma_f32_16x16x32_bf16(af0, bfr, acc[0][n], 0, 0, 0);
      acc[1][n] =
          __builtin_amdgcn_mfma_f32_16x16x32_bf16(af1, bfr, acc[1][n], 0, 0, 0);
    }
  }

  // ---- softmax ----
  const float NEG = -3.0e38f;
  float mx[2][4];
#pragma unroll
  for (int m = 0; m < 2; ++m)
#pragma unroll
    for (int q = 0; q < 4; ++q) {
      int rr = m * 16 + kg * 4 + q;
      float vmax = NEG;
#pragma unroll
      for (int n = 0; n < 4; ++n) {
        int col = (w * 4 + n) * 16 + lcol;
        int ck = col & 31;
        bool ok = (col < nm) && (ck - rr <= 3) && (rr - ck <= 3);
        float v = ok ? acc[m][n][q] : NEG;
        acc[m][n][q] = v;
        vmax = fmaxf(vmax, v);
      }
      vmax = fmaxf(vmax, __shfl_xor(vmax, 1));
      vmax = fmaxf(vmax, __shfl_xor(vmax, 2));
      vmax = fmaxf(vmax, __shfl_xor(vmax, 4));
      vmax = fmaxf(vmax, __shfl_xor(vmax, 8));
      mx[m][q] = vmax;
    }
  if (lcol == 0) {
#pragma unroll
    for (int m = 0; m < 2; ++m)
#pragma unroll
      for (int q = 0; q < 4; ++q) st_mx[m * 16 + kg * 4 + q][w] = mx[m][q];
  }
  __syncthreads();
  float sm[2][4];
#pragma unroll
  for (int m = 0; m < 2; ++m)
#pragma unroll
    for (int q = 0; q < 4; ++q) {
      int rr = m * 16 + kg * 4 + q;
      float4 v4 = *reinterpret_cast<const float4*>(&st_mx[rr][0]);
      float g = fmaxf(fmaxf(v4.x, v4.y), fmaxf(v4.z, v4.w));
      float ss = 0.f;
#pragma unroll
      for (int n = 0; n < 4; ++n) {
        float v = acc[m][n][q];
        float pv = (v > -1.0e30f) ? exp2f((v - g) * 1.4426950408889634f) : 0.f;
        acc[m][n][q] = pv;
        ss += pv;
      }
      ss += __shfl_xor(ss, 1);
      ss += __shfl_xor(ss, 2);
      ss += __shfl_xor(ss, 4);
      ss += __shfl_xor(ss, 8);
      sm[m][q] = ss;
    }
  if (lcol == 0) {
#pragma unroll
    for (int m = 0; m < 2; ++m)
#pragma unroll
      for (int q = 0; q < 4; ++q) st_sm[m * 16 + kg * 4 + q][w] = sm[m][q];
  }
  __syncthreads();
  // Q_s region now dead -> write P into the same LDS
#pragma unroll
  for (int m = 0; m < 2; ++m)
#pragma unroll
    for (int q = 0; q < 4; ++q) {
      int rr = m * 16 + kg * 4 + q;
      float4 v4 = *reinterpret_cast<const float4*>(&st_sm[rr][0]);
      float rinv = 1.0f / (v4.x + v4.y + v4.z + v4.w);
#pragma unroll
      for (int n = 0; n < 4; ++n) {
        QP_s[rr][(w * 4 + n) * 16 + lcol] = f2bf(acc[m][n][q] * rinv);
      }
    }
  __syncthreads();

  // ---- PV ----
  floatx4 oacc[2][4];
#pragma unroll
  for (int m = 0; m < 2; ++m)
#pragma unroll
    for (int n = 0; n < 4; ++n) oacc[m][n] = (floatx4){0.f, 0.f, 0.f, 0.f};

  for (int kb = 0; kb < nkr; ++kb) {
    short8 ap0 = *reinterpret_cast<const short8*>(&QP_s[lcol][kb * 32 + kg * 8]);
    short8 ap1 =
        *reinterpret_cast<const short8*>(&QP_s[16 + lcol][kb * 32 + kg * 8]);
    int tokb = (r0 + kb) * 32;
#pragma unroll
    for (int n = 0; n < 4; ++n) {
      int ch = w * 64 + n * 16 + lcol;
      short8 bv = *reinterpret_cast<const short8*>(
          &ktvb[(long)ch * NTOK + tokb + kg * 8]);
      oacc[0][n] =
          __builtin_amdgcn_mfma_f32_16x16x32_bf16(ap0, bv, oacc[0][n], 0, 0, 0);
      oacc[1][n] =
          __builtin_amdgcn_mfma_f32_16x16x32_bf16(ap1, bv, oacc[1][n], 0, 0, 0);
    }
  }
#pragma unroll
  for (int m = 0; m < 2; ++m)
#pragma unroll
    for (int n = 0; n < 4; ++n) {
      int ch = w * 64 + n * 16 + lcol;
#pragma unroll
      for (int q = 0; q < 4; ++q) {
        int rr = m * 16 + kg * 4 + q;
        o[((long)b * NTOK + r * 32 + rr) * (KMEM * HID) + k * HID + ch] =
            f2bf(oacc[m][n][q]);
      }
    }
}

// ---------------------------------------------------------------------------
// sum the 3 pred partials -> pred_sq, and global min/max of sqrt(pred_sq)
// ---------------------------------------------------------------------------
__global__ __launch_bounds__(256) void minmax_kernel(
    const float* __restrict__ ppart, float* __restrict__ pred_sq,
    float* __restrict__ mnmx) {
  int tid = threadIdx.x;
  float mn = INFINITY, mx = -INFINITY;
  for (int i = tid; i < BATCH * NTOK; i += 256) {
    float v = ppart[i] + ppart[16384 + i] + ppart[32768 + i];
    pred_sq[i] = v;
    float sv = sqrtf(v);
    mn = fminf(mn, sv);
    mx = fmaxf(mx, sv);
  }
#pragma unroll
  for (int off = 32; off > 0; off >>= 1) {
    mn = fminf(mn, __shfl_xor(mn, off));
    mx = fmaxf(mx, __shfl_xor(mx, off));
  }
  __shared__ float smn[4], smx[4];
  int wave = tid >> 6, lane = tid & 63;
  if (lane == 0) {
    smn[wave] = mn;
    smx[wave] = mx;
  }
  __syncthreads();
  if (tid == 0) {
    mn = fminf(fminf(smn[0], smn[1]), fminf(smn[2], smn[3]));
    mx = fmaxf(fmaxf(smx[0], smx[1]), fmaxf(smx[2], smx[3]));
    mnmx[0] = mn;
    mnmx[1] = mx;
  }
}

__global__ __launch_bounds__(256) void resize_kernel(
    const float* __restrict__ pred_sq, const float* __restrict__ mnmx,
    float* __restrict__ out) {
  long idx = (long)blockIdx.x * 256 + threadIdx.x;
  if (idx >= (long)BATCH * 256 * 256) return;
  int b = (int)(idx >> 16);
  int oy = (int)((idx >> 8) & 255), ox = (int)(idx & 255);
  float mn = mnmx[0], mx = mnmx[1];
  float inv = 1.0f / (mx - mn);
  float ys = oy * (31.0f / 255.0f);
  int y0 = (int)floorf(ys);
  int y1 = min(y0 + 1, 31);
  float fy = ys - (float)y0;
  float xs = ox * (31.0f / 255.0f);
  int x0 = (int)floorf(xs);
  int x1 = min(x0 + 1, 31);
  float fx = xs - (float)x0;
  const float* p = pred_sq + b * NTOK;
  float v00 = sqrtf(p[y0 * 32 + x0]), v01 = sqrtf(p[y0 * 32 + x1]);
  float v10 = sqrtf(p[y1 * 32 + x0]), v11 = sqrtf(p[y1 * 32 + x1]);
  float cA = v00 * (1.f - fy) + v10 * fy;
  float cB = v01 * (1.f - fy) + v11 * fy;
  float v = cA * (1.f - fx) + cB * fx;
  out[idx] = (v - mn) * inv;
}

// ---------------------------------------------------------------------------
extern "C" void kernel_launch(void* const* d_in, const int* in_sizes, int n_in,
                              void* d_out, int out_size, void* d_ws,
                              size_t ws_size, hipStream_t stream) {
  const float* qf = (const float*)d_in[0];
  const float* mf = (const float*)d_in[1];
  const float* qW = (const float*)d_in[2];
  const float* qb = (const float*)d_in[3];
  const float* kvW = (const float*)d_in[4];
  const float* kvb = (const float*)d_in[5];
  const float* row_e = (const float*)d_in[6];
  const float* col_e = (const float*)d_in[7];
  const float* aggW = (const float*)d_in[8];
  const float* aggb = (const float*)d_in[9];
  const float* n1g = (const float*)d_in[10];
  const float* n1b = (const float*)d_in[11];
  const float* l1W = (const float*)d_in[12];
  const float* l1b = (const float*)d_in[13];
  const float* l2W = (const float*)d_in[14];
  const float* l2b = (const float*)d_in[15];
  const float* n2g = (const float*)d_in[16];
  const float* n2b = (const float*)d_in[17];
  const float* outW = (const float*)d_in[18];
  const float* outb = (const float*)d_in[19];

  float* out = (float*)d_out;
  float* recon = out;                            // 16*272*1024
  float* pred = out + (long)BATCH * DIN * NTOK;  // 16*256*256

  // workspace layout
  float* ws = (float*)d_ws;
  float* pos = ws;                              // 262144 f   (1MB)
  float* x = pos + 262144;                      // 4194304 f  (16MB)
  short* x16 = (short*)(x + 4194304);           // 4194304 s  (8MB)
  short* ktp = x16 + 4194304;                   // 16777216 s (32MB)
  short* ktv = ktp + 16777216;                  // 16777216 s (32MB)
  short* buf16 = ktv + 16777216;                // 16777216 s (32MB)
  float* tmp256 = (float*)(buf16 + 16777216);   // 4194304 f  (16MB, mf_t spill)
  // bf16 transposed weights now live in ws (d_out must stay clean for the
  // fused out-projection which writes recon while reading wt_out).
  short* wt = (short*)(tmp256 + 4194304);
  short* wt_agg0 = wt;                  // [256][1024]
  short* wt_agg1 = wt_agg0 + 262144;    // [256][1024]
  short* wt_l1_0 = wt_agg1 + 262144;    // [1024][256]
  short* wt_l1_1 = wt_l1_0 + 262144;    // [1024][256]
  short* wt_l2_0 = wt_l1_1 + 262144;    // [256][1024]
  short* wt_l2_1 = wt_l2_0 + 262144;    // [256][1024]
  short* wt_out = wt_l2_1 + 262144;     // [272][256]
  short* wt_q = wt_out + 69632;         // [256][288]
  short* wt_kv = wt_q + 73728;          // [256][288]
  float* pred_part = (float*)(wt_kv + 73728);   // 49152 f (3 x 16384)
  float* pred_sq = pred_part + 49152;           // 16384 f
  float* mnmx = pred_sq + 16384;                // 2 f
  // transient aliases (consumed before their hosts are first written):
  short* qf_t = ktp;    // [16384][288] bf16 (9.4MB; consumed by qproj
                        //   before kvproj writes ktp)
  short* mf_t = buf16;  // [65536][288] bf16 (37.7MB, spills into tmp256;
                        //   consumed by kvproj before attn writes buf16)

  pos_kernel<<<NTOK, 256, 0, stream>>>(row_e, col_e, pos);

  // all weight transposes in one dispatch
  {
    WtJobs jobs;
    jobs.j[0] = {aggW, wt_agg0, 1024, 1024, 256, 8, 0};
    jobs.j[1] = {aggW + 262144, wt_agg1, 1024, 1024, 256, 8, 256};
    jobs.j[2] = {l1W, wt_l1_0, 256, 256, 1024, 32, 512};
    jobs.j[3] = {l1W + 262144, wt_l1_1, 256, 256, 1024, 32, 768};
    jobs.j[4] = {l2W, wt_l2_0, 1024, 1024, 256, 8, 1024};
    jobs.j[5] = {l2W + 262144, wt_l2_1, 1024, 1024, 256, 8, 1280};
    jobs.j[6] = {outW, wt_out, 256, 256, 272, 9, 1536};
    jobs.j[7] = {qW, wt_q, 272, 288, 256, 8, 1608};
    jobs.j[8] = {kvW, wt_kv, 272, 288, 256, 8, 1680};
    wt_cvt_all_kernel<<<1752, 256, 0, stream>>>(jobs);
  }

  // both activation transposes in one dispatch (qf_t aliases ktp)
  tcvt_kernel<<<dim3(2560, 9), 256, 0, stream>>>(qf, mf, qf_t, mf_t);

  // q projection (consumes qf_t before kvproj overwrites ktp)
  gemm2_kernel<3><<<512, 256, 0, stream>>>(
      qf_t, wt_q, qb, x, x16, BATCH * NTOK, HID, DINP, 2, nullptr, nullptr,
      nullptr, nullptr, nullptr);
  // kv projection
  gemm2_kernel<2><<<2048, 256, 0, stream>>>(
      mf_t, wt_kv, kvb, nullptr, nullptr, KMEM * BATCH * NTOK, HID, DINP, 2,
      ktp, ktv, pos, nullptr, nullptr);

  for (int l = 0; l < 2; l++) {
    attn_kernel<<<2048, 256, 0, stream>>>(x16, ktp, ktv, pos, buf16);
    // agg + LN1 fused: buf16 @ wt_agg + aggb + x -> LN -> x, x16
    gemm_ln_kernel<<<512, 256, 0, stream>>>(
        buf16, l ? wt_agg1 : wt_agg0, aggb + l * 256, x, n1g + l * 256,
        n1b + l * 256, x, x16, KMEM * HID);
    // ff1: x16 @ wt_l1 -> relu bf16 buf16
    gemm2_kernel<1><<<2048, 256, 0, stream>>>(
        x16, l ? wt_l1_1 : wt_l1_0, l1b + l * 1024, nullptr, buf16,
        BATCH * NTOK, DFF, HID, 8, nullptr, nullptr, nullptr, nullptr,
        nullptr);
    // ff2 + LN2 fused: buf16 @ wt_l2 + l2b + x -> LN -> x, x16
    gemm_ln_kernel<<<512, 256, 0, stream>>>(
        buf16, l ? wt_l2_1 : wt_l2_0, l2b + l * 256, x, n2g + l * 256,
        n2b + l * 256, x, x16, DFF);
  }

  // out projection fused: x16 @ wt_out -> recon (transposed) + pred partials
  gemm2_kernel<4><<<768, 256, 0, stream>>>(
      x16, wt_out, outb, recon, nullptr, BATCH * NTOK, DIN, HID, 3, nullptr,
      nullptr, nullptr, qf, pred_part);
  minmax_kernel<<<1, 256, 0, stream>>>(pred_part, pred_sq, mnmx);
  resize_kernel<<<(BATCH * 256 * 256) / 256, 256, 0, stream>>>(pred_sq, mnmx,
                                                               pred);
}